// Round 15
// baseline (165.745 us; speedup 1.0000x reference)
//
#include <hip/hip_runtime.h>
#include <hip/hip_bf16.h>
#include <math.h>

// Problem constants (B,S,D,E = 2,2048,1024,8)
#define Bq 2
#define Sq 2048
#define Dq 1024
#define Eq 8
#define Hq 2048            // 2*D
#define Aq 128             // H/16
#define Nq (Bq*Sq)         // 4096 tokens

typedef __attribute__((ext_vector_type(4))) float f32x4;
typedef __attribute__((ext_vector_type(8))) short bfrag;   // 8 bf16 in 4 VGPRs

__device__ __forceinline__ float silu_f(float x) {
    return x / (1.0f + expf(-x));
}
__device__ __forceinline__ unsigned short f2bf(float x) {  // RNE fp32->bf16
    unsigned u = __float_as_uint(x);
    u += 0x7fffu + ((u >> 16) & 1u);
    return (unsigned short)(u >> 16);
}
__device__ __forceinline__ float bf2f(unsigned short h) {
    return __uint_as_float(((unsigned)h) << 16);
}
__device__ __forceinline__ void gl16(const unsigned short* g, unsigned short* l) {
    __builtin_amdgcn_global_load_lds(
        (const __attribute__((address_space(1))) void*)g,
        (__attribute__((address_space(3))) void*)(void*)l, 16, 0, 0);
}

// Counted-vmcnt wait-then-barrier (T4). vmcnt retires IN ORDER.
#define WAITV_BAR(N)                                            \
    asm volatile("s_waitcnt vmcnt(" #N ")" ::: "memory");       \
    __builtin_amdgcn_s_barrier();                               \
    asm volatile("" ::: "memory")
#define END_BAR()                                               \
    asm volatile("" ::: "memory");                              \
    __builtin_amdgcn_s_barrier();                               \
    asm volatile("" ::: "memory")

__global__ __launch_bounds__(256)
void convert_all(const float* __restrict__ x,  const float* __restrict__ gw,
                 const float* __restrict__ uw, const float* __restrict__ dw,
                 const float* __restrict__ pw, const float* __restrict__ ow,
                 const float* __restrict__ opw, const float* __restrict__ aw,
                 unsigned short* xh,  unsigned short* gwh, unsigned short* uwh,
                 unsigned short* dwh, unsigned short* pwh, unsigned short* powh,
                 unsigned short* oph, unsigned short* adw)
{
    const int T = 3276800;
    for (int i = blockIdx.x * 256 + threadIdx.x; i < T; i += gridDim.x * 256) {
        const float* in; unsigned short* hi; int j = i;
        if (j < 1048576)                 { in = x;   hi = xh;  }
        else if ((j -= 1048576) < 524288){ in = gw;  hi = gwh; }
        else if ((j -= 524288) < 524288) { in = uw;  hi = uwh; }
        else if ((j -= 524288) < 524288) { in = dw;  hi = dwh; }
        else if ((j -= 524288) < 32768)  { in = pw;  hi = pwh; }
        else if ((j -= 32768) < 65536)   { in = ow;  hi = powh; }
        else if ((j -= 65536) < 524288)  { in = opw; hi = oph; }
        else { j -= 524288;                in = aw;  hi = adw; }
        float4 v = ((const float4*)in)[j];
        ((ushort4*)hi)[j] = make_ushort4(f2bf(v.x), f2bf(v.y), f2bf(v.z), f2bf(v.w));
    }
}

// Transpose [R][C] -> bf16 [C][R], batched by blockIdx.z.
template<typename TIN>
__global__ __launch_bounds__(256)
void transb(const TIN* __restrict__ in, unsigned short* __restrict__ out, int R, int C)
{
    __shared__ float t[32][33];
    in  += (size_t)blockIdx.z * R * C;
    out += (size_t)blockIdx.z * R * C;
    int tx = threadIdx.x & 31, ty = threadIdx.x >> 5;
    int r0 = blockIdx.y * 32, c0 = blockIdx.x * 32;
#pragma unroll
    for (int j = 0; j < 4; j++) {
        TIN v = in[(size_t)(r0 + ty + j * 8) * C + c0 + tx];
        float f;
        if (sizeof(TIN) == 2) f = bf2f(*(const unsigned short*)&v);
        else                  f = *(const float*)&v;
        t[ty + j * 8][tx] = f;
    }
    __syncthreads();
#pragma unroll
    for (int j = 0; j < 4; j++)
        out[(size_t)(c0 + ty + j * 8) * R + r0 + tx] = f2bf(t[tx][ty + j * 8]);
}

// ---------------------------------------------------------------------------
// 1-term bf16 MFMA GEMM, BK=64, 8 waves (2Mx4N, wave tile 64x32), 2-buf +
// counted-vmcnt. 64 KB LDS. (Unchanged from round 12 — proven.)
// EPI: 0 = fp32 store (+bz*zC+kz*pz); 1 = bf16 silu-clip store (+bz*zC).
// ---------------------------------------------------------------------------
template<int EPI>
__global__ __launch_bounds__(512)
void mg(const unsigned short* __restrict__ Ah, const unsigned short* __restrict__ Bh,
        void* __restrict__ Cv, int N, int K, int kchunks,
        long zA, long zB, long zC, long pz)
{
    __shared__ __align__(16) unsigned short lds[32768];  // 2 bufs x (A 8192 | B 8192)

    const int tid = threadIdx.x;
    const int l   = tid & 63;
    const int w   = tid >> 6;                  // 0..7
    const int wr  = w >> 2, wc = w & 3;
    const int bm0 = blockIdx.y * 128, bn0 = blockIdx.x * 128;
    const int bz  = blockIdx.z / kchunks;
    const int kz  = blockIdx.z - bz * kchunks;
    const int kcnt = K / kchunks;
    const int kbeg = kz * kcnt;
    const int kend = kbeg + kcnt;

    const unsigned short* A0 = Ah + (size_t)bz * zA;
    const unsigned short* B0 = Bh + (size_t)bz * zB;

    const int srow = tid >> 3;                 // 0..63 (+64 round 1)
    const int sq   = (tid & 7) ^ (srow & 7);
    const size_t aoff = (size_t)(bm0 + srow) * K + sq * 8;
    const size_t boff = (size_t)(bn0 + srow) * K + sq * 8;
    const size_t r64  = (size_t)64 * K;

    auto stage = [&](int b, int kt) {          // 4 gl16
        unsigned short* d = &lds[b * 16384 + (w << 9)];
        gl16(A0 + aoff + kt,       d + 0);
        gl16(A0 + aoff + kt + r64, d + 4096);
        gl16(B0 + boff + kt,       d + 8192);
        gl16(B0 + boff + kt + r64, d + 12288);
    };

    const int rowa = (wr * 64 + (l & 15)) * 64;
    const int rowb = (wc * 32 + (l & 15)) * 64;
    const int q0 = (((l >> 4)    ) ^ (l & 7)) << 3;
    const int q1 = (((l >> 4) + 4) ^ (l & 7)) << 3;

    f32x4 acc[4][2];
#pragma unroll
    for (int i = 0; i < 4; i++)
#pragma unroll
        for (int j = 0; j < 2; j++) acc[i][j] = (f32x4){0.f, 0.f, 0.f, 0.f};

    stage(0, kbeg);
    int cur = 0;
    for (int kt = kbeg; kt < kend; kt += 64) {
        if (kt + 64 < kend) {
            stage(cur ^ 1, kt + 64);
            WAITV_BAR(4);
        } else {
            WAITV_BAR(0);
        }
        const int cb = cur * 16384;
#pragma unroll
        for (int ks = 0; ks < 2; ks++) {
            const int qo = ks ? q1 : q0;
            bfrag a4[4], b4[2];
#pragma unroll
            for (int f = 0; f < 4; f++)
                a4[f] = *(const bfrag*)&lds[cb + rowa + f * 1024 + qo];
#pragma unroll
            for (int f = 0; f < 2; f++)
                b4[f] = *(const bfrag*)&lds[cb + 8192 + rowb + f * 1024 + qo];
#pragma unroll
            for (int i = 0; i < 4; i++)
#pragma unroll
                for (int j = 0; j < 2; j++)
                    acc[i][j] = __builtin_amdgcn_mfma_f32_16x16x32_bf16(a4[i], b4[j], acc[i][j], 0, 0, 0);
        }
        END_BAR();
        cur ^= 1;
    }

    const int crow0 = bm0 + wr * 64 + (l >> 4) * 4;
    const int ccol0 = bn0 + wc * 32 + (l & 15);
#pragma unroll
    for (int i = 0; i < 4; i++)
#pragma unroll
        for (int j = 0; j < 2; j++)
#pragma unroll
            for (int r = 0; r < 4; r++) {
                size_t idx = (size_t)(crow0 + i * 16 + r) * N + (ccol0 + j * 16);
                float v = acc[i][j][r];
                if (EPI == 0)
                    ((float*)Cv + (size_t)bz * zC + (size_t)kz * pz)[idx] = v;
                else
                    ((unsigned short*)Cv + (size_t)bz * zC)[idx] =
                        f2bf(silu_f(fminf(fmaxf(v, -5.f), 5.f)));
            }
}

// ---------------------------------------------------------------------------
// Fused gate+up GEMM, tile 128x128, BK=32, 8 waves (2Mx4N, wave tile 64x32),
// 2-buf + counted-vmcnt(3). LDS 48 KB -> grid 512 = 2 blocks/CU = 4 waves/SIMD
// (r13 diag: not L2-BW-bound (25 GB/s/CU); 2 waves/SIMD left dep-chains
// exposed — double the TLP at identical LDS/MFMA volume).
// 4-slot swizzle: stage sq=(tid&3)^(srow&3); read qo=((l>>4)^(l&3))*8;
// frag rows +(l&15) keep row&3==l&3 -> same XOR recovers G. 2D XCD chunk.
//   hh[n,h] = bf16( silu(x@gw^T) * (x@uw^T) )      K=1024, 32 K-steps.
// ---------------------------------------------------------------------------
__global__ __launch_bounds__(512)
void gup(const unsigned short* __restrict__ xh, const unsigned short* __restrict__ gwh,
         const unsigned short* __restrict__ uwh, unsigned short* __restrict__ hh)
{
    __shared__ __align__(16) unsigned short lds[24576];  // 2 bufs x (x|gw|uw 4096 each)
    const int tid = threadIdx.x;
    const int l   = tid & 63;
    const int w   = tid >> 6;
    const int wr  = w >> 2, wc = w & 3;        // 2 row-waves x 4 col-waves

    // grid (16,32): 2D XCD chunk (r8-proven): xcd owns 8bx x 8by
    int id  = blockIdx.y * gridDim.x + blockIdx.x;
    int xcd = id & 7, j = id >> 3;             // j in 0..63
    int bx  = (xcd & 1) * 8 + (j & 7);         // 0..15
    int by  = (xcd >> 1) * 8 + (j >> 3);       // 0..31
    const int bm0 = by * 128, bn0 = bx * 128;

    const int srow = tid >> 2;                 // 0..127
    const int sq   = (tid & 3) ^ (srow & 3);
    const size_t aoff = (size_t)(bm0 + srow) * Dq + sq * 8;
    const size_t boff = (size_t)(bn0 + srow) * Dq + sq * 8;

    const int rowa = (wr * 64 + (l & 15)) * 32;   // row stride 32 (BK=32)
    const int rowb = (wc * 32 + (l & 15)) * 32;
    const int q0 = (((l >> 4)) ^ (l & 3)) << 3;   // single ks (K=32)

    auto stage = [&](int b, int kt) {          // 3 gl16 (x, gw, uw: 8 KB each)
        unsigned short* d = &lds[b * 12288 + (w << 9)];
        gl16(xh  + aoff + kt, d + 0);
        gl16(gwh + boff + kt, d + 4096);
        gl16(uwh + boff + kt, d + 8192);
    };

    f32x4 accg[4][2], accu[4][2];
#pragma unroll
    for (int i = 0; i < 4; i++)
#pragma unroll
        for (int jj = 0; jj < 2; jj++) {
            accg[i][jj] = (f32x4){0.f, 0.f, 0.f, 0.f};
            accu[i][jj] = (f32x4){0.f, 0.f, 0.f, 0.f};
        }

    stage(0, 0);
    int cur = 0;
    for (int kt = 0; kt < Dq; kt += 32) {
        if (kt + 32 < Dq) {
            stage(cur ^ 1, kt + 32);       // 3 new in flight across the barrier
            WAITV_BAR(3);                  // drain only CUR's 3 (in-order retire)
        } else {
            WAITV_BAR(0);
        }
        const int cb = cur * 12288;
        bfrag a4[4], g4[2], u4[2];
#pragma unroll
        for (int f = 0; f < 4; f++)
            a4[f] = *(const bfrag*)&lds[cb + rowa + f * 512 + q0];
#pragma unroll
        for (int f = 0; f < 2; f++) {
            g4[f] = *(const bfrag*)&lds[cb + 4096 + rowb + f * 512 + q0];
            u4[f] = *(const bfrag*)&lds[cb + 8192 + rowb + f * 512 + q0];
        }
#pragma unroll
        for (int i = 0; i < 4; i++)
#pragma unroll
            for (int jj = 0; jj < 2; jj++) {
                accg[i][jj] = __builtin_amdgcn_mfma_f32_16x16x32_bf16(a4[i], g4[jj], accg[i][jj], 0, 0, 0);
                accu[i][jj] = __builtin_amdgcn_mfma_f32_16x16x32_bf16(a4[i], u4[jj], accu[i][jj], 0, 0, 0);
            }
        END_BAR();
        cur ^= 1;
    }

    const int crow0 = bm0 + wr * 64 + (l >> 4) * 4;
    const int ccol0 = bn0 + wc * 32 + (l & 15);
#pragma unroll
    for (int i = 0; i < 4; i++)
#pragma unroll
        for (int jj = 0; jj < 2; jj++)
#pragma unroll
            for (int r = 0; r < 4; r++) {
                size_t idx = (size_t)(crow0 + i * 16 + r) * Hq + (ccol0 + jj * 16);
                hh[idx] = f2bf(silu_f(accg[i][jj][r]) * accu[i][jj][r]);
            }
}

// ---------------------------------------------------------------------------
// Final fused GEMM, BK=64, 8 waves (2Mx4N), 3-deep ring (96 KB LDS):
//   out[4096][1024] = hh@dwh^T (K=2048) + acat@kcat^T (K=256)
// ---------------------------------------------------------------------------
__global__ __launch_bounds__(512)
void gfinal(const unsigned short* __restrict__ hh, const unsigned short* __restrict__ dwh,
            const unsigned short* __restrict__ acat, const unsigned short* __restrict__ kcat,
            float* __restrict__ out)
{
    __shared__ __align__(16) unsigned short lds[49152];  // 3 bufs x 16384
    const int tid = threadIdx.x;
    const int l   = tid & 63;
    const int w   = tid >> 6;
    const int wr  = w >> 2, wc = w & 3;

    int nb  = gridDim.x * gridDim.y;                      // 256
    int id  = blockIdx.y * gridDim.x + blockIdx.x;
    int id2 = (id & 7) * (nb >> 3) + (id >> 3);
    int bx  = id2 % gridDim.x, by = id2 / gridDim.x;
    const int bm0 = by * 128, bn0 = bx * 128;

    const int srow = tid >> 3;
    const int sq   = (tid & 7) ^ (srow & 7);
    const int rowa = (wr * 64 + (l & 15)) * 64;
    const int rowb = (wc * 32 + (l & 15)) * 64;
    const int q0 = (((l >> 4)    ) ^ (l & 7)) << 3;
    const int q1 = (((l >> 4) + 4) ^ (l & 7)) << 3;

    f32x4 acc[4][2];
#pragma unroll
    for (int i = 0; i < 4; i++)
#pragma unroll
        for (int j = 0; j < 2; j++) acc[i][j] = (f32x4){0.f, 0.f, 0.f, 0.f};

    // ---- main: K=2048, 3-deep ----
    {
        const size_t aoff = (size_t)(bm0 + srow) * Hq + sq * 8;
        const size_t boff = (size_t)(bn0 + srow) * Hq + sq * 8;
        const size_t r64  = (size_t)64 * Hq;
        auto stage = [&](int b, int kt) {      // 4 gl16
            unsigned short* d = &lds[b * 16384 + (w << 9)];
            gl16(hh  + aoff + kt,       d + 0);
            gl16(hh  + aoff + kt + r64, d + 4096);
            gl16(dwh + boff + kt,       d + 8192);
            gl16(dwh + boff + kt + r64, d + 12288);
        };
        stage(0, 0);
        stage(1, 64);
        int cur = 0;
        for (int kt = 0; kt < Hq; kt += 64) {
            if (kt + 64 < Hq) { WAITV_BAR(4); } else { WAITV_BAR(0); }
            if (kt + 128 < Hq) {
                int nb3 = (cur + 2 >= 3) ? cur - 1 : cur + 2;
                stage(nb3, kt + 128);
            }
            const int cb = cur * 16384;
#pragma unroll
            for (int ks = 0; ks < 2; ks++) {
                const int qo = ks ? q1 : q0;
                bfrag a4[4], b4[2];
#pragma unroll
                for (int f = 0; f < 4; f++)
                    a4[f] = *(const bfrag*)&lds[cb + rowa + f * 1024 + qo];
#pragma unroll
                for (int f = 0; f < 2; f++)
                    b4[f] = *(const bfrag*)&lds[cb + 8192 + rowb + f * 1024 + qo];
#pragma unroll
                for (int i = 0; i < 4; i++)
#pragma unroll
                    for (int j = 0; j < 2; j++)
                        acc[i][j] = __builtin_amdgcn_mfma_f32_16x16x32_bf16(a4[i], b4[j], acc[i][j], 0, 0, 0);
            }
            cur = (cur == 2) ? 0 : cur + 1;
        }
    }
    END_BAR();   // all waves done with main's last compute before tail staging
    // ---- tail: K=256 over [acat | kcat], 3-deep (4 iters) ----
    {
        const size_t aoff = (size_t)(bm0 + srow) * 256 + sq * 8;
        const size_t boff = (size_t)(bn0 + srow) * 256 + sq * 8;
        const size_t r64  = (size_t)64 * 256;
        auto stage2 = [&](int b, int kt) {
            unsigned short* d = &lds[b * 16384 + (w << 9)];
            gl16(acat + aoff + kt,       d + 0);
            gl16(acat + aoff + kt + r64, d + 4096);
            gl16(kcat + boff + kt,       d + 8192);
            gl16(kcat + boff + kt + r64, d + 12288);
        };
        stage2(0, 0);
        stage2(1, 64);
        int cur = 0;
        for (int kt = 0; kt < 256; kt += 64) {
            if (kt + 64 < 256) { WAITV_BAR(4); } else { WAITV_BAR(0); }
            if (kt + 128 < 256) {
                int nb3 = (cur + 2 >= 3) ? cur - 1 : cur + 2;
                stage2(nb3, kt + 128);
            }
            const int cb = cur * 16384;
#pragma unroll
            for (int ks = 0; ks < 2; ks++) {
                const int qo = ks ? q1 : q0;
                bfrag a4[4], b4[2];
#pragma unroll
                for (int f = 0; f < 4; f++)
                    a4[f] = *(const bfrag*)&lds[cb + rowa + f * 1024 + qo];
#pragma unroll
                for (int f = 0; f < 2; f++)
                    b4[f] = *(const bfrag*)&lds[cb + 8192 + rowb + f * 1024 + qo];
#pragma unroll
                for (int i = 0; i < 4; i++)
#pragma unroll
                    for (int j = 0; j < 2; j++)
                        acc[i][j] = __builtin_amdgcn_mfma_f32_16x16x32_bf16(a4[i], b4[j], acc[i][j], 0, 0, 0);
            }
            cur = (cur == 2) ? 0 : cur + 1;
        }
    }

    const int crow0 = bm0 + wr * 64 + (l >> 4) * 4;
    const int ccol0 = bn0 + wc * 32 + (l & 15);
#pragma unroll
    for (int i = 0; i < 4; i++)
#pragma unroll
        for (int j = 0; j < 2; j++)
#pragma unroll
            for (int r = 0; r < 4; r++)
                out[(size_t)(crow0 + i * 16 + r) * Dq + ccol0 + j * 16] = acc[i][j][r];
}

// Reduce NZ split-K partials + LayerNorm over A=128 -> bf16.
template<int NZ>
__global__ __launch_bounds__(256)
void rln(const float* __restrict__ p, unsigned short* __restrict__ oh,
         const float* __restrict__ g, const float* __restrict__ b, long pstride)
{
    int row  = blockIdx.x * 4 + (threadIdx.x >> 6);
    int lane = threadIdx.x & 63;
    long base = (long)row * Aq;
    float x0 = 0.f, x1 = 0.f;
#pragma unroll
    for (int z = 0; z < NZ; z++) {
        x0 += p[base + z * pstride + lane];
        x1 += p[base + z * pstride + lane + 64];
    }
    float s  = x0 + x1;
    float ss = x0 * x0 + x1 * x1;
#pragma unroll
    for (int off = 32; off > 0; off >>= 1) {
        s  += __shfl_xor(s, off);
        ss += __shfl_xor(ss, off);
    }
    float m  = s * (1.0f / Aq);
    float v  = ss * (1.0f / Aq) - m * m;
    float rs = rsqrtf(v + 1e-5f);
    oh[base + lane]      = f2bf((x0 - m) * rs * g[lane]      + b[lane]);
    oh[base + lane + 64] = f2bf((x1 - m) * rs * g[lane + 64] + b[lane + 64]);
}

// Reduce NZ split-K partials [bz][NZ][rowsPerB][A] -> scaled bf16.
// Output col = ocol + bz*ocolStep (lets one launch fill both kcat halves).
template<int NZ>
__global__ __launch_bounds__(256)
void rbf(const float* __restrict__ p, unsigned short* __restrict__ o,
         int rowsPerB, float scale, int total, int ostride, int ocol, int ocolStep)
{
    int i = blockIdx.x * 256 + threadIdx.x;
    if (i >= total) return;
    int n = i >> 7, a = i & 127;
    int bz = n / rowsPerB, s = n - bz * rowsPerB;
    long base = ((long)bz * NZ) * rowsPerB * Aq + (long)s * Aq + a;
    float acc = 0.f;
#pragma unroll
    for (int z = 0; z < NZ; z++) acc += p[base + (long)z * rowsPerB * Aq];
    o[(long)s * ostride + (ocol + bz * ocolStep) + a +
      (ocolStep ? 0 : (long)bz * rowsPerB * ostride)] = f2bf(acc * scale);
}

// mixed[n,:] = sum_e ew[n,e] * LN_e(h[e,n,:])  -> bf16 into acat col 128.
__global__ __launch_bounds__(256)
void mix_ln(const float* __restrict__ h, const float* __restrict__ ew,
            const float* __restrict__ g, const float* __restrict__ bb,
            unsigned short* __restrict__ acat)
{
    int n    = blockIdx.x * 4 + (threadIdx.x >> 6);
    int lane = threadIdx.x & 63;
    float a0 = 0.0f, a1 = 0.0f;
#pragma unroll
    for (int e = 0; e < Eq; e++) {
        const float* r = h + ((long)e * Nq + n) * Aq;
        float x0 = r[lane], x1 = r[lane + 64];
        float s  = x0 + x1;
        float ss = x0 * x0 + x1 * x1;
#pragma unroll
        for (int off = 32; off > 0; off >>= 1) {
            s  += __shfl_xor(s, off);
            ss += __shfl_xor(ss, off);
        }
        float m  = s * (1.0f / Aq);
        float v  = ss * (1.0f / Aq) - m * m;
        float rs = rsqrtf(v + 1e-5f);
        float wv = ew[(long)n * Eq + e];
        a0 += wv * ((x0 - m) * rs * g[e * Aq + lane]      + bb[e * Aq + lane]);
        a1 += wv * ((x1 - m) * rs * g[e * Aq + lane + 64] + bb[e * Aq + lane + 64]);
    }
    acat[(long)n * 256 + 128 + lane]      = f2bf(a0);
    acat[(long)n * 256 + 128 + lane + 64] = f2bf(a1);
}

extern "C" void kernel_launch(void* const* d_in, const int* in_sizes, int n_in,
                              void* d_out, int out_size, void* d_ws, size_t ws_size,
                              hipStream_t stream)
{
    const float* x             = (const float*)d_in[0];
    const float* ew            = (const float*)d_in[1];
    const float* up_w          = (const float*)d_in[2];
    const float* gate_w        = (const float*)d_in[3];
    const float* down_w        = (const float*)d_in[4];
    const float* pre_w         = (const float*)d_in[5];
    const float* post_w        = (const float*)d_in[6];
    const float* an_g          = (const float*)d_in[7];
    const float* an_b          = (const float*)d_in[8];
    const float* adapt_proj_w  = (const float*)d_in[9];
    const float* adapter_w     = (const float*)d_in[10];
    const float* adapter_g     = (const float*)d_in[11];
    const float* adapter_b     = (const float*)d_in[12];
    const float* expert_proj_w = (const float*)d_in[13];
    const float* output_proj_w = (const float*)d_in[14];
    float* out = (float*)d_out;

    // ---- workspace (KB offsets; peak ~81 MB) ----
#define OFF(kb) ((char*)d_ws + (size_t)(kb) * 1024)
    float* kdp  = (float*)OFF(0);        // [16][D][A] 8MB   (phase 1, bz=0)
    float* wfp  = (float*)OFF(8192);     // 8MB              (phase 1, bz=1)
    float* p1   = (float*)OFF(16384);    // [8][N][A] 16MB   (phase 1)
    float* p2   = (float*)OFF(0);        // [8][N][A] 16MB   (phase 3)
    unsigned short* wmat = (unsigned short*)OFF(16384);  // [B][S][S] bf16 16MB (ph 3-4)
    float* p3   = (float*)OFF(0);        // [2][8][S][A] 16MB (phase 4)
    float* h_e  = (float*)OFF(0);        // [E][N][A] 16MB    (phase 5, after p3 dead)
    unsigned short* hh   = (unsigned short*)OFF(32768);  // [N,H] 16MB
    unsigned short* xh   = (unsigned short*)OFF(49152);  // 8MB
    unsigned short* gwh  = (unsigned short*)OFF(57344);  // 4MB
    unsigned short* uwh  = (unsigned short*)OFF(61440);  // 4MB
    unsigned short* dwh  = (unsigned short*)OFF(65536);  // 4MB   } contiguous pair
    unsigned short* oph  = (unsigned short*)OFF(69632);  // 4MB   } for batched kcat
    unsigned short* pwh  = (unsigned short*)OFF(73728);  // .25MB
    unsigned short* powh = (unsigned short*)OFF(73984);  // .5MB
    unsigned short* apT  = (unsigned short*)OFF(74496);  // .5MB  } contiguous pair
    unsigned short* epT  = (unsigned short*)OFF(75008);  // .5MB  }
    unsigned short* ainh = (unsigned short*)OFF(75520);  // 1MB
    unsigned short* ainT = (unsigned short*)OFF(76544);  // [B][A][S] 1MB
    unsigned short* aouth= (unsigned short*)OFF(77568);  // 1MB
    unsigned short* adw  = (unsigned short*)OFF(78592);  // .25MB
    unsigned short* kcat = (unsigned short*)OFF(78848);  // [D][256] .5MB
    unsigned short* acat = (unsigned short*)OFF(79360);  // [N][256] 2MB -> 81408
#undef OFF

    dim3 blk(256), blk512(512);
    const long NA = (long)Nq * Aq;
    const long SA = (long)Sq * Aq;
    const long SS = (long)Sq * Sq;

    // 1. conversions + transposes
    convert_all<<<dim3(2048), blk, 0, stream>>>(x, gate_w, up_w, down_w, pre_w, post_w,
        output_proj_w, adapter_w, xh, gwh, uwh, dwh, pwh, powh, oph, adw);
    transb<float><<<dim3(4, 64, 1), blk, 0, stream>>>(adapt_proj_w,  apT, Hq, Aq);
    transb<float><<<dim3(4, 64, 1), blk, 0, stream>>>(expert_proj_w, epT, Hq, Aq);

    // 2. weight fusions (batched bz=2): bz0 = dwh@apT -> kdp, bz1 = oph@epT -> wfp
    mg<0><<<dim3(1, 8, 32), blk512, 0, stream>>>(dwh, apT, kdp, Aq, Hq, 16,
        (long)Dq * Hq, (long)Aq * Hq, (long)16 * Dq * Aq, (long)Dq * Aq);
    rbf<16><<<dim3(1024), blk, 0, stream>>>(kdp, kcat, Dq, 1.0f, 2 * Dq * Aq, 256, 0, 128);

    // 3. ain = LN(x @ pre_w^T)  (split-K 8)
    mg<0><<<dim3(1, 32, 8), blk512, 0, stream>>>(xh, pwh, p1, Aq, Dq, 8, 0, 0, 0, NA);
    rln<8><<<dim3(1024), blk, 0, stream>>>(p1, ainh, an_g, an_b, NA);
    transb<unsigned short><<<dim3(4, 64, 2), blk, 0, stream>>>(ainh, ainT, Sq, Aq);

    // 4. fused SwiGLU: hh = bf16(silu(x@gw^T) * (x@uw^T))  tile 128x128, BK=32
    gup<<<dim3(16, 32), blk512, 0, stream>>>(xh, gwh, uwh, hh);

    // 5. aout = LN(hidden @ post_w^T)  (split-K 8)
    mg<0><<<dim3(1, 32, 8), blk512, 0, stream>>>(hh, powh, p2, Aq, Hq, 8, 0, 0, 0, NA);
    rln<8><<<dim3(1024), blk, 0, stream>>>(p2, aouth, an_g, an_b, NA);

    // 6. wmat = bf16(silu(clip(ain @ aout^T)))  per batch
    mg<1><<<dim3(16, 16, 2), blk512, 0, stream>>>(ainh, aouth, wmat, Sq, Aq, 1,
        SA, SA, SS, 0);

    // 7. acat[:,0:128] = 0.1 * (wmat @ ain)  (split-K 8, batched)
    mg<0><<<dim3(1, 16, 16), blk512, 0, stream>>>(wmat, ainT, p3, Aq, Sq, 8,
        SS, SA, 8 * SA, SA);
    rbf<8><<<dim3(2048), blk, 0, stream>>>(p3, acat, Sq, 0.1f, Nq * Aq, 256, 0, 0);

    // 8. expert path: h_e, then acat[:,128:256] = mixed
    mg<0><<<dim3(1, 32, 8), blk512, 0, stream>>>(ainh, adw, h_e, Aq, Aq, 1,
        0, (long)Aq * Aq, NA, 0);
    mix_ln<<<dim3(1024), blk, 0, stream>>>(h_e, ew, adapter_g, adapter_b, acat);

    // 9. out = hh@dwh^T + acat@kcat^T
    gfinal<<<dim3(8, 32), blk512, 0, stream>>>(hh, dwh, acat, kcat, out);
}

// Round 16
// 165.022 us; speedup vs baseline: 1.0044x; 1.0044x over previous
//
#include <hip/hip_runtime.h>
#include <hip/hip_bf16.h>
#include <math.h>

// Problem constants (B,S,D,E = 2,2048,1024,8)
#define Bq 2
#define Sq 2048
#define Dq 1024
#define Eq 8
#define Hq 2048            // 2*D
#define Aq 128             // H/16
#define Nq (Bq*Sq)         // 4096 tokens

typedef __attribute__((ext_vector_type(4))) float f32x4;
typedef __attribute__((ext_vector_type(8))) short bfrag;   // 8 bf16 in 4 VGPRs

__device__ __forceinline__ float silu_f(float x) {
    return x / (1.0f + expf(-x));
}
__device__ __forceinline__ unsigned short f2bf(float x) {  // RNE fp32->bf16
    unsigned u = __float_as_uint(x);
    u += 0x7fffu + ((u >> 16) & 1u);
    return (unsigned short)(u >> 16);
}
__device__ __forceinline__ float bf2f(unsigned short h) {
    return __uint_as_float(((unsigned)h) << 16);
}
__device__ __forceinline__ void gl16(const unsigned short* g, unsigned short* l) {
    __builtin_amdgcn_global_load_lds(
        (const __attribute__((address_space(1))) void*)g,
        (__attribute__((address_space(3))) void*)(void*)l, 16, 0, 0);
}

// Counted-vmcnt wait-then-barrier (T4). vmcnt retires IN ORDER.
#define WAITV_BAR(N)                                            \
    asm volatile("s_waitcnt vmcnt(" #N ")" ::: "memory");       \
    __builtin_amdgcn_s_barrier();                               \
    asm volatile("" ::: "memory")
#define END_BAR()                                               \
    asm volatile("" ::: "memory");                              \
    __builtin_amdgcn_s_barrier();                               \
    asm volatile("" ::: "memory")

__global__ __launch_bounds__(256)
void convert_all(const float* __restrict__ x,  const float* __restrict__ gw,
                 const float* __restrict__ uw, const float* __restrict__ dw,
                 const float* __restrict__ pw, const float* __restrict__ ow,
                 const float* __restrict__ opw, const float* __restrict__ aw,
                 unsigned short* xh,  unsigned short* gwh, unsigned short* uwh,
                 unsigned short* dwh, unsigned short* pwh, unsigned short* powh,
                 unsigned short* oph, unsigned short* adw)
{
    const int T = 3276800;
    for (int i = blockIdx.x * 256 + threadIdx.x; i < T; i += gridDim.x * 256) {
        const float* in; unsigned short* hi; int j = i;
        if (j < 1048576)                 { in = x;   hi = xh;  }
        else if ((j -= 1048576) < 524288){ in = gw;  hi = gwh; }
        else if ((j -= 524288) < 524288) { in = uw;  hi = uwh; }
        else if ((j -= 524288) < 524288) { in = dw;  hi = dwh; }
        else if ((j -= 524288) < 32768)  { in = pw;  hi = pwh; }
        else if ((j -= 32768) < 65536)   { in = ow;  hi = powh; }
        else if ((j -= 65536) < 524288)  { in = opw; hi = oph; }
        else { j -= 524288;                in = aw;  hi = adw; }
        float4 v = ((const float4*)in)[j];
        ((ushort4*)hi)[j] = make_ushort4(f2bf(v.x), f2bf(v.y), f2bf(v.z), f2bf(v.w));
    }
}

// Transpose [R][C] -> bf16 [C][R], batched by blockIdx.z.
template<typename TIN>
__global__ __launch_bounds__(256)
void transb(const TIN* __restrict__ in, unsigned short* __restrict__ out, int R, int C)
{
    __shared__ float t[32][33];
    in  += (size_t)blockIdx.z * R * C;
    out += (size_t)blockIdx.z * R * C;
    int tx = threadIdx.x & 31, ty = threadIdx.x >> 5;
    int r0 = blockIdx.y * 32, c0 = blockIdx.x * 32;
#pragma unroll
    for (int j = 0; j < 4; j++) {
        TIN v = in[(size_t)(r0 + ty + j * 8) * C + c0 + tx];
        float f;
        if (sizeof(TIN) == 2) f = bf2f(*(const unsigned short*)&v);
        else                  f = *(const float*)&v;
        t[ty + j * 8][tx] = f;
    }
    __syncthreads();
#pragma unroll
    for (int j = 0; j < 4; j++)
        out[(size_t)(c0 + ty + j * 8) * R + r0 + tx] = f2bf(t[tx][ty + j * 8]);
}

// ---------------------------------------------------------------------------
// 1-term bf16 MFMA GEMM, BK=64, 8 waves (2Mx4N, wave tile 64x32), 2-buf +
// counted-vmcnt. 64 KB LDS. (Unchanged — proven.)
// EPI: 0 = fp32 store (+bz*zC+kz*pz); 1 = bf16 silu-clip store (+bz*zC).
// ---------------------------------------------------------------------------
template<int EPI>
__global__ __launch_bounds__(512)
void mg(const unsigned short* __restrict__ Ah, const unsigned short* __restrict__ Bh,
        void* __restrict__ Cv, int N, int K, int kchunks,
        long zA, long zB, long zC, long pz)
{
    __shared__ __align__(16) unsigned short lds[32768];  // 2 bufs x (A 8192 | B 8192)

    const int tid = threadIdx.x;
    const int l   = tid & 63;
    const int w   = tid >> 6;                  // 0..7
    const int wr  = w >> 2, wc = w & 3;
    const int bm0 = blockIdx.y * 128, bn0 = blockIdx.x * 128;
    const int bz  = blockIdx.z / kchunks;
    const int kz  = blockIdx.z - bz * kchunks;
    const int kcnt = K / kchunks;
    const int kbeg = kz * kcnt;
    const int kend = kbeg + kcnt;

    const unsigned short* A0 = Ah + (size_t)bz * zA;
    const unsigned short* B0 = Bh + (size_t)bz * zB;

    const int srow = tid >> 3;                 // 0..63 (+64 round 1)
    const int sq   = (tid & 7) ^ (srow & 7);
    const size_t aoff = (size_t)(bm0 + srow) * K + sq * 8;
    const size_t boff = (size_t)(bn0 + srow) * K + sq * 8;
    const size_t r64  = (size_t)64 * K;

    auto stage = [&](int b, int kt) {          // 4 gl16
        unsigned short* d = &lds[b * 16384 + (w << 9)];
        gl16(A0 + aoff + kt,       d + 0);
        gl16(A0 + aoff + kt + r64, d + 4096);
        gl16(B0 + boff + kt,       d + 8192);
        gl16(B0 + boff + kt + r64, d + 12288);
    };

    const int rowa = (wr * 64 + (l & 15)) * 64;
    const int rowb = (wc * 32 + (l & 15)) * 64;
    const int q0 = (((l >> 4)    ) ^ (l & 7)) << 3;
    const int q1 = (((l >> 4) + 4) ^ (l & 7)) << 3;

    f32x4 acc[4][2];
#pragma unroll
    for (int i = 0; i < 4; i++)
#pragma unroll
        for (int j = 0; j < 2; j++) acc[i][j] = (f32x4){0.f, 0.f, 0.f, 0.f};

    stage(0, kbeg);
    int cur = 0;
    for (int kt = kbeg; kt < kend; kt += 64) {
        if (kt + 64 < kend) {
            stage(cur ^ 1, kt + 64);
            WAITV_BAR(4);
        } else {
            WAITV_BAR(0);
        }
        const int cb = cur * 16384;
#pragma unroll
        for (int ks = 0; ks < 2; ks++) {
            const int qo = ks ? q1 : q0;
            bfrag a4[4], b4[2];
#pragma unroll
            for (int f = 0; f < 4; f++)
                a4[f] = *(const bfrag*)&lds[cb + rowa + f * 1024 + qo];
#pragma unroll
            for (int f = 0; f < 2; f++)
                b4[f] = *(const bfrag*)&lds[cb + 8192 + rowb + f * 1024 + qo];
#pragma unroll
            for (int i = 0; i < 4; i++)
#pragma unroll
                for (int j = 0; j < 2; j++)
                    acc[i][j] = __builtin_amdgcn_mfma_f32_16x16x32_bf16(a4[i], b4[j], acc[i][j], 0, 0, 0);
        }
        END_BAR();
        cur ^= 1;
    }

    const int crow0 = bm0 + wr * 64 + (l >> 4) * 4;
    const int ccol0 = bn0 + wc * 32 + (l & 15);
#pragma unroll
    for (int i = 0; i < 4; i++)
#pragma unroll
        for (int j = 0; j < 2; j++)
#pragma unroll
            for (int r = 0; r < 4; r++) {
                size_t idx = (size_t)(crow0 + i * 16 + r) * N + (ccol0 + j * 16);
                float v = acc[i][j][r];
                if (EPI == 0)
                    ((float*)Cv + (size_t)bz * zC + (size_t)kz * pz)[idx] = v;
                else
                    ((unsigned short*)Cv + (size_t)bz * zC)[idx] =
                        f2bf(silu_f(fminf(fmaxf(v, -5.f), 5.f)));
            }
}

// ---------------------------------------------------------------------------
// Fused gate+up GEMM, tile 128x128, BK=32, 8 waves (2Mx4N, wave tile 64x32),
// 2-buf + counted-vmcnt(3). 48 KB LDS -> 2 blocks/CU = 4 waves/SIMD.
// SWIZZLE FIX (r15 post-mortem): BK=32 row stride = 64 B (16 banks), so the
// XOR must use (row>>1)&3, not row&3 — bank position in the 128B cycle is
// ((row&1), q), and q = c^((row>>1)&3) makes 16 rows exactly 2-way (free).
// r15's row&3 variant collapsed to 4 slots -> 4-way conflict (4.19M measured).
// Stage: sq=(tid&3)^((srow>>1)&3); read: qo=((l>>4)^(((l&15)>>1)&3))*8.
//   hh[n,h] = bf16( silu(x@gw^T) * (x@uw^T) )      K=1024, 32 K-steps.
// ---------------------------------------------------------------------------
__global__ __launch_bounds__(512)
void gup(const unsigned short* __restrict__ xh, const unsigned short* __restrict__ gwh,
         const unsigned short* __restrict__ uwh, unsigned short* __restrict__ hh)
{
    __shared__ __align__(16) unsigned short lds[24576];  // 2 bufs x (x|gw|uw 4096 each)
    const int tid = threadIdx.x;
    const int l   = tid & 63;
    const int w   = tid >> 6;
    const int wr  = w >> 2, wc = w & 3;        // 2 row-waves x 4 col-waves

    // grid (16,32): 2D XCD chunk (r8-proven): xcd owns 8bx x 8by
    int id  = blockIdx.y * gridDim.x + blockIdx.x;
    int xcd = id & 7, j = id >> 3;             // j in 0..63
    int bx  = (xcd & 1) * 8 + (j & 7);         // 0..15
    int by  = (xcd >> 1) * 8 + (j >> 3);       // 0..31
    const int bm0 = by * 128, bn0 = bx * 128;

    const int srow = tid >> 2;                 // 0..127
    const int sq   = (tid & 3) ^ ((srow >> 1) & 3);      // FIXED swizzle
    const size_t aoff = (size_t)(bm0 + srow) * Dq + sq * 8;
    const size_t boff = (size_t)(bn0 + srow) * Dq + sq * 8;

    const int rowa = (wr * 64 + (l & 15)) * 32;   // row stride 32 ushorts (BK=32)
    const int rowb = (wc * 32 + (l & 15)) * 32;
    const int q0 = (((l >> 4)) ^ (((l & 15) >> 1) & 3)) << 3;   // FIXED swizzle

    auto stage = [&](int b, int kt) {          // 3 gl16 (x, gw, uw: 8 KB each)
        unsigned short* d = &lds[b * 12288 + (w << 9)];
        gl16(xh  + aoff + kt, d + 0);
        gl16(gwh + boff + kt, d + 4096);
        gl16(uwh + boff + kt, d + 8192);
    };

    f32x4 accg[4][2], accu[4][2];
#pragma unroll
    for (int i = 0; i < 4; i++)
#pragma unroll
        for (int jj = 0; jj < 2; jj++) {
            accg[i][jj] = (f32x4){0.f, 0.f, 0.f, 0.f};
            accu[i][jj] = (f32x4){0.f, 0.f, 0.f, 0.f};
        }

    stage(0, 0);
    int cur = 0;
    for (int kt = 0; kt < Dq; kt += 32) {
        if (kt + 32 < Dq) {
            stage(cur ^ 1, kt + 32);       // 3 new in flight across the barrier
            WAITV_BAR(3);                  // drain only CUR's 3 (in-order retire)
        } else {
            WAITV_BAR(0);
        }
        const int cb = cur * 12288;
        bfrag a4[4], g4[2], u4[2];
#pragma unroll
        for (int f = 0; f < 4; f++)
            a4[f] = *(const bfrag*)&lds[cb + rowa + f * 512 + q0];
#pragma unroll
        for (int f = 0; f < 2; f++) {
            g4[f] = *(const bfrag*)&lds[cb + 4096 + rowb + f * 512 + q0];
            u4[f] = *(const bfrag*)&lds[cb + 8192 + rowb + f * 512 + q0];
        }
#pragma unroll
        for (int i = 0; i < 4; i++)
#pragma unroll
            for (int jj = 0; jj < 2; jj++) {
                accg[i][jj] = __builtin_amdgcn_mfma_f32_16x16x32_bf16(a4[i], g4[jj], accg[i][jj], 0, 0, 0);
                accu[i][jj] = __builtin_amdgcn_mfma_f32_16x16x32_bf16(a4[i], u4[jj], accu[i][jj], 0, 0, 0);
            }
        END_BAR();
        cur ^= 1;
    }

    const int crow0 = bm0 + wr * 64 + (l >> 4) * 4;
    const int ccol0 = bn0 + wc * 32 + (l & 15);
#pragma unroll
    for (int i = 0; i < 4; i++)
#pragma unroll
        for (int jj = 0; jj < 2; jj++)
#pragma unroll
            for (int r = 0; r < 4; r++) {
                size_t idx = (size_t)(crow0 + i * 16 + r) * Hq + (ccol0 + jj * 16);
                hh[idx] = f2bf(silu_f(accg[i][jj][r]) * accu[i][jj][r]);
            }
}

// ---------------------------------------------------------------------------
// Final fused GEMM, BK=64, 8 waves (2Mx4N), 3-deep ring (96 KB LDS):
//   out[4096][1024] = hh@dwh^T (K=2048) + acat@kcat^T (K=256)
// ---------------------------------------------------------------------------
__global__ __launch_bounds__(512)
void gfinal(const unsigned short* __restrict__ hh, const unsigned short* __restrict__ dwh,
            const unsigned short* __restrict__ acat, const unsigned short* __restrict__ kcat,
            float* __restrict__ out)
{
    __shared__ __align__(16) unsigned short lds[49152];  // 3 bufs x 16384
    const int tid = threadIdx.x;
    const int l   = tid & 63;
    const int w   = tid >> 6;
    const int wr  = w >> 2, wc = w & 3;

    int nb  = gridDim.x * gridDim.y;                      // 256
    int id  = blockIdx.y * gridDim.x + blockIdx.x;
    int id2 = (id & 7) * (nb >> 3) + (id >> 3);
    int bx  = id2 % gridDim.x, by = id2 / gridDim.x;
    const int bm0 = by * 128, bn0 = bx * 128;

    const int srow = tid >> 3;
    const int sq   = (tid & 7) ^ (srow & 7);
    const int rowa = (wr * 64 + (l & 15)) * 64;
    const int rowb = (wc * 32 + (l & 15)) * 64;
    const int q0 = (((l >> 4)    ) ^ (l & 7)) << 3;
    const int q1 = (((l >> 4) + 4) ^ (l & 7)) << 3;

    f32x4 acc[4][2];
#pragma unroll
    for (int i = 0; i < 4; i++)
#pragma unroll
        for (int j = 0; j < 2; j++) acc[i][j] = (f32x4){0.f, 0.f, 0.f, 0.f};

    // ---- main: K=2048, 3-deep ----
    {
        const size_t aoff = (size_t)(bm0 + srow) * Hq + sq * 8;
        const size_t boff = (size_t)(bn0 + srow) * Hq + sq * 8;
        const size_t r64  = (size_t)64 * Hq;
        auto stage = [&](int b, int kt) {      // 4 gl16
            unsigned short* d = &lds[b * 16384 + (w << 9)];
            gl16(hh  + aoff + kt,       d + 0);
            gl16(hh  + aoff + kt + r64, d + 4096);
            gl16(dwh + boff + kt,       d + 8192);
            gl16(dwh + boff + kt + r64, d + 12288);
        };
        stage(0, 0);
        stage(1, 64);
        int cur = 0;
        for (int kt = 0; kt < Hq; kt += 64) {
            if (kt + 64 < Hq) { WAITV_BAR(4); } else { WAITV_BAR(0); }
            if (kt + 128 < Hq) {
                int nb3 = (cur + 2 >= 3) ? cur - 1 : cur + 2;
                stage(nb3, kt + 128);
            }
            const int cb = cur * 16384;
#pragma unroll
            for (int ks = 0; ks < 2; ks++) {
                const int qo = ks ? q1 : q0;
                bfrag a4[4], b4[2];
#pragma unroll
                for (int f = 0; f < 4; f++)
                    a4[f] = *(const bfrag*)&lds[cb + rowa + f * 1024 + qo];
#pragma unroll
                for (int f = 0; f < 2; f++)
                    b4[f] = *(const bfrag*)&lds[cb + 8192 + rowb + f * 1024 + qo];
#pragma unroll
                for (int i = 0; i < 4; i++)
#pragma unroll
                    for (int j = 0; j < 2; j++)
                        acc[i][j] = __builtin_amdgcn_mfma_f32_16x16x32_bf16(a4[i], b4[j], acc[i][j], 0, 0, 0);
            }
            cur = (cur == 2) ? 0 : cur + 1;
        }
    }
    END_BAR();   // all waves done with main's last compute before tail staging
    // ---- tail: K=256 over [acat | kcat], 3-deep (4 iters) ----
    {
        const size_t aoff = (size_t)(bm0 + srow) * 256 + sq * 8;
        const size_t boff = (size_t)(bn0 + srow) * 256 + sq * 8;
        const size_t r64  = (size_t)64 * 256;
        auto stage2 = [&](int b, int kt) {
            unsigned short* d = &lds[b * 16384 + (w << 9)];
            gl16(acat + aoff + kt,       d + 0);
            gl16(acat + aoff + kt + r64, d + 4096);
            gl16(kcat + boff + kt,       d + 8192);
            gl16(kcat + boff + kt + r64, d + 12288);
        };
        stage2(0, 0);
        stage2(1, 64);
        int cur = 0;
        for (int kt = 0; kt < 256; kt += 64) {
            if (kt + 64 < 256) { WAITV_BAR(4); } else { WAITV_BAR(0); }
            if (kt + 128 < 256) {
                int nb3 = (cur + 2 >= 3) ? cur - 1 : cur + 2;
                stage2(nb3, kt + 128);
            }
            const int cb = cur * 16384;
#pragma unroll
            for (int ks = 0; ks < 2; ks++) {
                const int qo = ks ? q1 : q0;
                bfrag a4[4], b4[2];
#pragma unroll
                for (int f = 0; f < 4; f++)
                    a4[f] = *(const bfrag*)&lds[cb + rowa + f * 1024 + qo];
#pragma unroll
                for (int f = 0; f < 2; f++)
                    b4[f] = *(const bfrag*)&lds[cb + 8192 + rowb + f * 1024 + qo];
#pragma unroll
                for (int i = 0; i < 4; i++)
#pragma unroll
                    for (int j = 0; j < 2; j++)
                        acc[i][j] = __builtin_amdgcn_mfma_f32_16x16x32_bf16(a4[i], b4[j], acc[i][j], 0, 0, 0);
            }
            cur = (cur == 2) ? 0 : cur + 1;
        }
    }

    const int crow0 = bm0 + wr * 64 + (l >> 4) * 4;
    const int ccol0 = bn0 + wc * 32 + (l & 15);
#pragma unroll
    for (int i = 0; i < 4; i++)
#pragma unroll
        for (int j = 0; j < 2; j++)
#pragma unroll
            for (int r = 0; r < 4; r++)
                out[(size_t)(crow0 + i * 16 + r) * Dq + ccol0 + j * 16] = acc[i][j][r];
}

// Reduce NZ split-K partials + LayerNorm over A=128 -> bf16.
template<int NZ>
__global__ __launch_bounds__(256)
void rln(const float* __restrict__ p, unsigned short* __restrict__ oh,
         const float* __restrict__ g, const float* __restrict__ b, long pstride)
{
    int row  = blockIdx.x * 4 + (threadIdx.x >> 6);
    int lane = threadIdx.x & 63;
    long base = (long)row * Aq;
    float x0 = 0.f, x1 = 0.f;
#pragma unroll
    for (int z = 0; z < NZ; z++) {
        x0 += p[base + z * pstride + lane];
        x1 += p[base + z * pstride + lane + 64];
    }
    float s  = x0 + x1;
    float ss = x0 * x0 + x1 * x1;
#pragma unroll
    for (int off = 32; off > 0; off >>= 1) {
        s  += __shfl_xor(s, off);
        ss += __shfl_xor(ss, off);
    }
    float m  = s * (1.0f / Aq);
    float v  = ss * (1.0f / Aq) - m * m;
    float rs = rsqrtf(v + 1e-5f);
    oh[base + lane]      = f2bf((x0 - m) * rs * g[lane]      + b[lane]);
    oh[base + lane + 64] = f2bf((x1 - m) * rs * g[lane + 64] + b[lane + 64]);
}

// Reduce NZ split-K partials [bz][NZ][rowsPerB][A] -> scaled bf16.
// Output col = ocol + bz*ocolStep (lets one launch fill both kcat halves).
template<int NZ>
__global__ __launch_bounds__(256)
void rbf(const float* __restrict__ p, unsigned short* __restrict__ o,
         int rowsPerB, float scale, int total, int ostride, int ocol, int ocolStep)
{
    int i = blockIdx.x * 256 + threadIdx.x;
    if (i >= total) return;
    int n = i >> 7, a = i & 127;
    int bz = n / rowsPerB, s = n - bz * rowsPerB;
    long base = ((long)bz * NZ) * rowsPerB * Aq + (long)s * Aq + a;
    float acc = 0.f;
#pragma unroll
    for (int z = 0; z < NZ; z++) acc += p[base + (long)z * rowsPerB * Aq];
    o[(long)s * ostride + (ocol + bz * ocolStep) + a +
      (ocolStep ? 0 : (long)bz * rowsPerB * ostride)] = f2bf(acc * scale);
}

// mixed[n,:] = sum_e ew[n,e] * LN_e(h[e,n,:])  -> bf16 into acat col 128.
__global__ __launch_bounds__(256)
void mix_ln(const float* __restrict__ h, const float* __restrict__ ew,
            const float* __restrict__ g, const float* __restrict__ bb,
            unsigned short* __restrict__ acat)
{
    int n    = blockIdx.x * 4 + (threadIdx.x >> 6);
    int lane = threadIdx.x & 63;
    float a0 = 0.0f, a1 = 0.0f;
#pragma unroll
    for (int e = 0; e < Eq; e++) {
        const float* r = h + ((long)e * Nq + n) * Aq;
        float x0 = r[lane], x1 = r[lane + 64];
        float s  = x0 + x1;
        float ss = x0 * x0 + x1 * x1;
#pragma unroll
        for (int off = 32; off > 0; off >>= 1) {
            s  += __shfl_xor(s, off);
            ss += __shfl_xor(ss, off);
        }
        float m  = s * (1.0f / Aq);
        float v  = ss * (1.0f / Aq) - m * m;
        float rs = rsqrtf(v + 1e-5f);
        float wv = ew[(long)n * Eq + e];
        a0 += wv * ((x0 - m) * rs * g[e * Aq + lane]      + bb[e * Aq + lane]);
        a1 += wv * ((x1 - m) * rs * g[e * Aq + lane + 64] + bb[e * Aq + lane + 64]);
    }
    acat[(long)n * 256 + 128 + lane]      = f2bf(a0);
    acat[(long)n * 256 + 128 + lane + 64] = f2bf(a1);
}

extern "C" void kernel_launch(void* const* d_in, const int* in_sizes, int n_in,
                              void* d_out, int out_size, void* d_ws, size_t ws_size,
                              hipStream_t stream)
{
    const float* x             = (const float*)d_in[0];
    const float* ew            = (const float*)d_in[1];
    const float* up_w          = (const float*)d_in[2];
    const float* gate_w        = (const float*)d_in[3];
    const float* down_w        = (const float*)d_in[4];
    const float* pre_w         = (const float*)d_in[5];
    const float* post_w        = (const float*)d_in[6];
    const float* an_g          = (const float*)d_in[7];
    const float* an_b          = (const float*)d_in[8];
    const float* adapt_proj_w  = (const float*)d_in[9];
    const float* adapter_w     = (const float*)d_in[10];
    const float* adapter_g     = (const float*)d_in[11];
    const float* adapter_b     = (const float*)d_in[12];
    const float* expert_proj_w = (const float*)d_in[13];
    const float* output_proj_w = (const float*)d_in[14];
    float* out = (float*)d_out;

    // ---- workspace (KB offsets; peak ~81 MB) ----
#define OFF(kb) ((char*)d_ws + (size_t)(kb) * 1024)
    float* kdp  = (float*)OFF(0);        // [16][D][A] 8MB   (phase 1, bz=0)
    float* wfp  = (float*)OFF(8192);     // 8MB              (phase 1, bz=1)
    float* p1   = (float*)OFF(16384);    // [8][N][A] 16MB   (phase 1)
    float* p2   = (float*)OFF(0);        // [8][N][A] 16MB   (phase 3)
    unsigned short* wmat = (unsigned short*)OFF(16384);  // [B][S][S] bf16 16MB (ph 3-4)
    float* p3   = (float*)OFF(0);        // [2][8][S][A] 16MB (phase 4)
    float* h_e  = (float*)OFF(0);        // [E][N][A] 16MB    (phase 5, after p3 dead)
    unsigned short* hh   = (unsigned short*)OFF(32768);  // [N,H] 16MB
    unsigned short* xh   = (unsigned short*)OFF(49152);  // 8MB
    unsigned short* gwh  = (unsigned short*)OFF(57344);  // 4MB
    unsigned short* uwh  = (unsigned short*)OFF(61440);  // 4MB
    unsigned short* dwh  = (unsigned short*)OFF(65536);  // 4MB   } contiguous pair
    unsigned short* oph  = (unsigned short*)OFF(69632);  // 4MB   } for batched kcat
    unsigned short* pwh  = (unsigned short*)OFF(73728);  // .25MB
    unsigned short* powh = (unsigned short*)OFF(73984);  // .5MB
    unsigned short* apT  = (unsigned short*)OFF(74496);  // .5MB  } contiguous pair
    unsigned short* epT  = (unsigned short*)OFF(75008);  // .5MB  }
    unsigned short* ainh = (unsigned short*)OFF(75520);  // 1MB
    unsigned short* ainT = (unsigned short*)OFF(76544);  // [B][A][S] 1MB
    unsigned short* aouth= (unsigned short*)OFF(77568);  // 1MB
    unsigned short* adw  = (unsigned short*)OFF(78592);  // .25MB
    unsigned short* kcat = (unsigned short*)OFF(78848);  // [D][256] .5MB
    unsigned short* acat = (unsigned short*)OFF(79360);  // [N][256] 2MB -> 81408
#undef OFF

    dim3 blk(256), blk512(512);
    const long NA = (long)Nq * Aq;
    const long SA = (long)Sq * Aq;
    const long SS = (long)Sq * Sq;

    // 1. conversions + transposes
    convert_all<<<dim3(2048), blk, 0, stream>>>(x, gate_w, up_w, down_w, pre_w, post_w,
        output_proj_w, adapter_w, xh, gwh, uwh, dwh, pwh, powh, oph, adw);
    transb<float><<<dim3(4, 64, 1), blk, 0, stream>>>(adapt_proj_w,  apT, Hq, Aq);
    transb<float><<<dim3(4, 64, 1), blk, 0, stream>>>(expert_proj_w, epT, Hq, Aq);

    // 2. weight fusions (batched bz=2): bz0 = dwh@apT -> kdp, bz1 = oph@epT -> wfp
    mg<0><<<dim3(1, 8, 32), blk512, 0, stream>>>(dwh, apT, kdp, Aq, Hq, 16,
        (long)Dq * Hq, (long)Aq * Hq, (long)16 * Dq * Aq, (long)Dq * Aq);
    rbf<16><<<dim3(1024), blk, 0, stream>>>(kdp, kcat, Dq, 1.0f, 2 * Dq * Aq, 256, 0, 128);

    // 3. ain = LN(x @ pre_w^T)  (split-K 8)
    mg<0><<<dim3(1, 32, 8), blk512, 0, stream>>>(xh, pwh, p1, Aq, Dq, 8, 0, 0, 0, NA);
    rln<8><<<dim3(1024), blk, 0, stream>>>(p1, ainh, an_g, an_b, NA);
    transb<unsigned short><<<dim3(4, 64, 2), blk, 0, stream>>>(ainh, ainT, Sq, Aq);

    // 4. fused SwiGLU: hh = bf16(silu(x@gw^T) * (x@uw^T))  tile 128x128, BK=32
    gup<<<dim3(16, 32), blk512, 0, stream>>>(xh, gwh, uwh, hh);

    // 5. aout = LN(hidden @ post_w^T)  (split-K 8)
    mg<0><<<dim3(1, 32, 8), blk512, 0, stream>>>(hh, powh, p2, Aq, Hq, 8, 0, 0, 0, NA);
    rln<8><<<dim3(1024), blk, 0, stream>>>(p2, aouth, an_g, an_b, NA);

    // 6. wmat = bf16(silu(clip(ain @ aout^T)))  per batch
    mg<1><<<dim3(16, 16, 2), blk512, 0, stream>>>(ainh, aouth, wmat, Sq, Aq, 1,
        SA, SA, SS, 0);

    // 7. acat[:,0:128] = 0.1 * (wmat @ ain)  (split-K 8, batched)
    mg<0><<<dim3(1, 16, 16), blk512, 0, stream>>>(wmat, ainT, p3, Aq, Sq, 8,
        SS, SA, 8 * SA, SA);
    rbf<8><<<dim3(2048), blk, 0, stream>>>(p3, acat, Sq, 0.1f, Nq * Aq, 256, 0, 0);

    // 8. expert path: h_e, then acat[:,128:256] = mixed
    mg<0><<<dim3(1, 32, 8), blk512, 0, stream>>>(ainh, adw, h_e, Aq, Aq, 1,
        0, (long)Aq * Aq, NA, 0);
    mix_ln<<<dim3(1024), blk, 0, stream>>>(h_e, ew, adapter_g, adapter_b, acat);

    // 9. out = hh@dwh^T + acat@kcat^T
    gfinal<<<dim3(8, 32), blk512, 0, stream>>>(hh, dwh, acat, kcat, out);
}

// Round 17
// 164.605 us; speedup vs baseline: 1.0069x; 1.0025x over previous
//
#include <hip/hip_runtime.h>
#include <hip/hip_bf16.h>
#include <math.h>

// Problem constants (B,S,D,E = 2,2048,1024,8)
#define Bq 2
#define Sq 2048
#define Dq 1024
#define Eq 8
#define Hq 2048            // 2*D
#define Aq 128             // H/16
#define Nq (Bq*Sq)         // 4096 tokens

typedef __attribute__((ext_vector_type(4))) float f32x4;
typedef __attribute__((ext_vector_type(8))) short bfrag;   // 8 bf16 in 4 VGPRs

__device__ __forceinline__ float silu_f(float x) {
    return x / (1.0f + expf(-x));
}
__device__ __forceinline__ unsigned short f2bf(float x) {  // RNE fp32->bf16
    unsigned u = __float_as_uint(x);
    u += 0x7fffu + ((u >> 16) & 1u);
    return (unsigned short)(u >> 16);
}
__device__ __forceinline__ float bf2f(unsigned short h) {
    return __uint_as_float(((unsigned)h) << 16);
}
__device__ __forceinline__ void gl16(const unsigned short* g, unsigned short* l) {
    __builtin_amdgcn_global_load_lds(
        (const __attribute__((address_space(1))) void*)g,
        (__attribute__((address_space(3))) void*)(void*)l, 16, 0, 0);
}

// Counted-vmcnt wait-then-barrier (T4). vmcnt retires IN ORDER.
#define WAITV_BAR(N)                                            \
    asm volatile("s_waitcnt vmcnt(" #N ")" ::: "memory");       \
    __builtin_amdgcn_s_barrier();                               \
    asm volatile("" ::: "memory")
#define END_BAR()                                               \
    asm volatile("" ::: "memory");                              \
    __builtin_amdgcn_s_barrier();                               \
    asm volatile("" ::: "memory")

__global__ __launch_bounds__(256)
void convert_all(const float* __restrict__ x,  const float* __restrict__ gw,
                 const float* __restrict__ uw, const float* __restrict__ dw,
                 const float* __restrict__ pw, const float* __restrict__ ow,
                 const float* __restrict__ opw, const float* __restrict__ aw,
                 unsigned short* xh,  unsigned short* gwh, unsigned short* uwh,
                 unsigned short* dwh, unsigned short* pwh, unsigned short* powh,
                 unsigned short* oph, unsigned short* adw)
{
    const int T = 3276800;
    for (int i = blockIdx.x * 256 + threadIdx.x; i < T; i += gridDim.x * 256) {
        const float* in; unsigned short* hi; int j = i;
        if (j < 1048576)                 { in = x;   hi = xh;  }
        else if ((j -= 1048576) < 524288){ in = gw;  hi = gwh; }
        else if ((j -= 524288) < 524288) { in = uw;  hi = uwh; }
        else if ((j -= 524288) < 524288) { in = dw;  hi = dwh; }
        else if ((j -= 524288) < 32768)  { in = pw;  hi = pwh; }
        else if ((j -= 32768) < 65536)   { in = ow;  hi = powh; }
        else if ((j -= 65536) < 524288)  { in = opw; hi = oph; }
        else { j -= 524288;                in = aw;  hi = adw; }
        float4 v = ((const float4*)in)[j];
        ((ushort4*)hi)[j] = make_ushort4(f2bf(v.x), f2bf(v.y), f2bf(v.z), f2bf(v.w));
    }
}

// Transpose [R][C] -> bf16 [C][R]; z selects (in0,out) / (in1,out+R*C).
template<typename TIN>
__global__ __launch_bounds__(256)
void transb(const TIN* __restrict__ in0, const TIN* __restrict__ in1,
            unsigned short* __restrict__ out, int R, int C)
{
    __shared__ float t[32][33];
    const TIN* in = blockIdx.z ? in1 : in0;
    if (!in1) in = in0 + (size_t)blockIdx.z * R * C;   // batched single-src mode
    out += (size_t)blockIdx.z * R * C;
    int tx = threadIdx.x & 31, ty = threadIdx.x >> 5;
    int r0 = blockIdx.y * 32, c0 = blockIdx.x * 32;
#pragma unroll
    for (int j = 0; j < 4; j++) {
        TIN v = in[(size_t)(r0 + ty + j * 8) * C + c0 + tx];
        float f;
        if (sizeof(TIN) == 2) f = bf2f(*(const unsigned short*)&v);
        else                  f = *(const float*)&v;
        t[ty + j * 8][tx] = f;
    }
    __syncthreads();
#pragma unroll
    for (int j = 0; j < 4; j++)
        out[(size_t)(c0 + ty + j * 8) * R + r0 + tx] = f2bf(t[tx][ty + j * 8]);
}

// ---------------------------------------------------------------------------
// 1-term bf16 MFMA GEMM, BK=64, 8 waves (2Mx4N, wave tile 64x32), 2-buf +
// counted-vmcnt. 64 KB LDS. (Unchanged — proven.)
// EPI: 0 = fp32 store (+bz*zC+kz*pz); 1 = bf16 silu-clip store (+bz*zC).
// ---------------------------------------------------------------------------
template<int EPI>
__global__ __launch_bounds__(512)
void mg(const unsigned short* __restrict__ Ah, const unsigned short* __restrict__ Bh,
        void* __restrict__ Cv, int N, int K, int kchunks,
        long zA, long zB, long zC, long pz)
{
    __shared__ __align__(16) unsigned short lds[32768];  // 2 bufs x (A 8192 | B 8192)

    const int tid = threadIdx.x;
    const int l   = tid & 63;
    const int w   = tid >> 6;                  // 0..7
    const int wr  = w >> 2, wc = w & 3;
    const int bm0 = blockIdx.y * 128, bn0 = blockIdx.x * 128;
    const int bz  = blockIdx.z / kchunks;
    const int kz  = blockIdx.z - bz * kchunks;
    const int kcnt = K / kchunks;
    const int kbeg = kz * kcnt;
    const int kend = kbeg + kcnt;

    const unsigned short* A0 = Ah + (size_t)bz * zA;
    const unsigned short* B0 = Bh + (size_t)bz * zB;

    const int srow = tid >> 3;                 // 0..63 (+64 round 1)
    const int sq   = (tid & 7) ^ (srow & 7);
    const size_t aoff = (size_t)(bm0 + srow) * K + sq * 8;
    const size_t boff = (size_t)(bn0 + srow) * K + sq * 8;
    const size_t r64  = (size_t)64 * K;

    auto stage = [&](int b, int kt) {          // 4 gl16
        unsigned short* d = &lds[b * 16384 + (w << 9)];
        gl16(A0 + aoff + kt,       d + 0);
        gl16(A0 + aoff + kt + r64, d + 4096);
        gl16(B0 + boff + kt,       d + 8192);
        gl16(B0 + boff + kt + r64, d + 12288);
    };

    const int rowa = (wr * 64 + (l & 15)) * 64;
    const int rowb = (wc * 32 + (l & 15)) * 64;
    const int q0 = (((l >> 4)    ) ^ (l & 7)) << 3;
    const int q1 = (((l >> 4) + 4) ^ (l & 7)) << 3;

    f32x4 acc[4][2];
#pragma unroll
    for (int i = 0; i < 4; i++)
#pragma unroll
        for (int j = 0; j < 2; j++) acc[i][j] = (f32x4){0.f, 0.f, 0.f, 0.f};

    stage(0, kbeg);
    int cur = 0;
    for (int kt = kbeg; kt < kend; kt += 64) {
        if (kt + 64 < kend) {
            stage(cur ^ 1, kt + 64);
            WAITV_BAR(4);
        } else {
            WAITV_BAR(0);
        }
        const int cb = cur * 16384;
#pragma unroll
        for (int ks = 0; ks < 2; ks++) {
            const int qo = ks ? q1 : q0;
            bfrag a4[4], b4[2];
#pragma unroll
            for (int f = 0; f < 4; f++)
                a4[f] = *(const bfrag*)&lds[cb + rowa + f * 1024 + qo];
#pragma unroll
            for (int f = 0; f < 2; f++)
                b4[f] = *(const bfrag*)&lds[cb + 8192 + rowb + f * 1024 + qo];
#pragma unroll
            for (int i = 0; i < 4; i++)
#pragma unroll
                for (int j = 0; j < 2; j++)
                    acc[i][j] = __builtin_amdgcn_mfma_f32_16x16x32_bf16(a4[i], b4[j], acc[i][j], 0, 0, 0);
        }
        END_BAR();
        cur ^= 1;
    }

    const int crow0 = bm0 + wr * 64 + (l >> 4) * 4;
    const int ccol0 = bn0 + wc * 32 + (l & 15);
#pragma unroll
    for (int i = 0; i < 4; i++)
#pragma unroll
        for (int j = 0; j < 2; j++)
#pragma unroll
            for (int r = 0; r < 4; r++) {
                size_t idx = (size_t)(crow0 + i * 16 + r) * N + (ccol0 + j * 16);
                float v = acc[i][j][r];
                if (EPI == 0)
                    ((float*)Cv + (size_t)bz * zC + (size_t)kz * pz)[idx] = v;
                else
                    ((unsigned short*)Cv + (size_t)bz * zC)[idx] =
                        f2bf(silu_f(fminf(fmaxf(v, -5.f), 5.f)));
            }
}

// ---------------------------------------------------------------------------
// Fused score-combine kernel (replaces steps 6+7 / the wmat materialization):
//   For batch b, row-block i (128 rows), t-chunk tz (2 of 16 column-tiles):
//     P      = bf16( silu(clip( ain_i @ aout_t^T )) )     [128x128], in LDS
//     partial = sum_t P @ ainT_t                          [128x128] fp32
//   p3[b][tz][row][a] = partial  (reduced by rbf<8> with scale 0.1).
// Numerics identical to the old path (same bf16 quantization of P).
// 16-slot swizzle (K=128 rows, 256B stride): store G(row, q^(row&15));
// read slot = (ks*4 + (l>>4)) ^ (l&15). Bank = f(slot&7) only -> uniform.
// 8 waves (2Mx4N): wave tile 64x32. LDS: ainI|aoutB|ainTB|P = 4 x 32 KB.
// ---------------------------------------------------------------------------
__global__ __launch_bounds__(512)
void gsc(const unsigned short* __restrict__ ainh, const unsigned short* __restrict__ aouth,
         const unsigned short* __restrict__ ainT, float* __restrict__ p3)
{
    __shared__ __align__(16) unsigned short lds[65536];  // 128 KB
    const int AIN = 0, AOUT = 16384, AINT = 32768, PB = 49152;

    const int tid = threadIdx.x;
    const int l   = tid & 63;
    const int w   = tid >> 6;
    const int wr  = w >> 2, wc = w & 3;
    const int tz  = blockIdx.x;        // 0..7
    const int ib  = blockIdx.y;        // 0..15
    const int b   = blockIdx.z;        // 0..1
    const long SA = (long)Sq * Aq;

    // stage a [128 x 128] bf16 tile (4 gl16 rounds), 16-slot swizzle.
    auto stage32 = [&](int base, const unsigned short* src, size_t kstride) {
#pragma unroll
        for (int rd = 0; rd < 4; rd++) {
            int grow = rd * 32 + (w << 2) + (l >> 4);
            int slot = (l & 15) ^ (grow & 15);
            gl16(src + (size_t)grow * kstride + slot * 8,
                 &lds[base + rd * 4096 + (w << 9)]);
        }
    };

    const unsigned short* ainI_src = ainh + (size_t)b * SA + (size_t)(ib * 128) * Aq;
    f32x4 acc2[4][2];
#pragma unroll
    for (int i = 0; i < 4; i++)
#pragma unroll
        for (int j = 0; j < 2; j++) acc2[i][j] = (f32x4){0.f, 0.f, 0.f, 0.f};

    // prologue: ainI + first t's operands
    {
        int tglob = tz * 2;
        stage32(AIN,  ainI_src, Aq);
        stage32(AOUT, aouth + (size_t)b * SA + (size_t)(tglob * 128) * Aq, Aq);
        stage32(AINT, ainT  + (size_t)b * SA + (size_t)(tglob * 128), Sq);
        WAITV_BAR(0);
    }

    const int rowa = (wr * 64 + (l & 15)) * 128;   // A rows (ainI / P)
    const int rowb = (wc * 32 + (l & 15)) * 128;   // B rows (aoutB / ainTB)

#pragma unroll 1
    for (int t = 0; t < 2; t++) {
        if (t == 1) {
            int tglob = tz * 2 + 1;
            stage32(AOUT, aouth + (size_t)b * SA + (size_t)(tglob * 128) * Aq, Aq);
            stage32(AINT, ainT  + (size_t)b * SA + (size_t)(tglob * 128), Sq);
            WAITV_BAR(0);
        }
        // ---- MFMA1: P = ainI @ aoutB^T  (K=128, 4 k-steps) ----
        f32x4 acc1[4][2];
#pragma unroll
        for (int i = 0; i < 4; i++)
#pragma unroll
            for (int j = 0; j < 2; j++) acc1[i][j] = (f32x4){0.f, 0.f, 0.f, 0.f};
#pragma unroll
        for (int ks = 0; ks < 4; ks++) {
            const int qo = ((ks * 4 + (l >> 4)) ^ (l & 15)) << 3;
            bfrag a4[4], b4[2];
#pragma unroll
            for (int f = 0; f < 4; f++)
                a4[f] = *(const bfrag*)&lds[AIN + rowa + f * 2048 + qo];
#pragma unroll
            for (int f = 0; f < 2; f++)
                b4[f] = *(const bfrag*)&lds[AOUT + rowb + f * 2048 + qo];
#pragma unroll
            for (int i = 0; i < 4; i++)
#pragma unroll
                for (int j = 0; j < 2; j++)
                    acc1[i][j] = __builtin_amdgcn_mfma_f32_16x16x32_bf16(a4[i], b4[j], acc1[i][j], 0, 0, 0);
        }
        // ---- epilogue1: P = bf16(silu(clip(acc1))) -> LDS (swizzled) ----
        {
            const int prow0 = wr * 64 + (l >> 4) * 4;
            const int pcol0 = wc * 32 + (l & 15);
#pragma unroll
            for (int i = 0; i < 4; i++)
#pragma unroll
                for (int j = 0; j < 2; j++)
#pragma unroll
                    for (int r = 0; r < 4; r++) {
                        int pr = prow0 + i * 16 + r;
                        int pc = pcol0 + j * 16;
                        float v = silu_f(fminf(fmaxf(acc1[i][j][r], -5.f), 5.f));
                        lds[PB + pr * 128 + (((pc >> 3) ^ (pr & 15)) << 3) + (pc & 7)] = f2bf(v);
                    }
        }
        __syncthreads();   // P visible to all waves
        // ---- MFMA2: acc2 += P @ ainTB^T  (K=128) ----
#pragma unroll
        for (int ks = 0; ks < 4; ks++) {
            const int qo = ((ks * 4 + (l >> 4)) ^ (l & 15)) << 3;
            bfrag a4[4], b4[2];
#pragma unroll
            for (int f = 0; f < 4; f++)
                a4[f] = *(const bfrag*)&lds[PB + rowa + f * 2048 + qo];
#pragma unroll
            for (int f = 0; f < 2; f++)
                b4[f] = *(const bfrag*)&lds[AINT + rowb + f * 2048 + qo];
#pragma unroll
            for (int i = 0; i < 4; i++)
#pragma unroll
                for (int j = 0; j < 2; j++)
                    acc2[i][j] = __builtin_amdgcn_mfma_f32_16x16x32_bf16(a4[i], b4[j], acc2[i][j], 0, 0, 0);
        }
        __syncthreads();   // all reads done before next t overwrites buffers
    }

    // ---- store partial: p3[b][tz][ib*128 + prow][a] ----
    const int crow0 = wr * 64 + (l >> 4) * 4;
    const int ccol0 = wc * 32 + (l & 15);
    float* dst = p3 + ((size_t)(b * 8 + tz) * Sq + ib * 128) * Aq;
#pragma unroll
    for (int i = 0; i < 4; i++)
#pragma unroll
        for (int j = 0; j < 2; j++)
#pragma unroll
            for (int r = 0; r < 4; r++)
                dst[(size_t)(crow0 + i * 16 + r) * Aq + ccol0 + j * 16] = acc2[i][j][r];
}

// ---------------------------------------------------------------------------
// Fused gate+up GEMM, tile 128x128, BK=32, 8 waves, 2-buf + counted-vmcnt(3).
// 48 KB LDS -> 2 blocks/CU. Conflict-free (row>>1)&3 swizzle (r16: verified 0).
// ---------------------------------------------------------------------------
__global__ __launch_bounds__(512)
void gup(const unsigned short* __restrict__ xh, const unsigned short* __restrict__ gwh,
         const unsigned short* __restrict__ uwh, unsigned short* __restrict__ hh)
{
    __shared__ __align__(16) unsigned short lds[24576];  // 2 bufs x (x|gw|uw 4096 each)
    const int tid = threadIdx.x;
    const int l   = tid & 63;
    const int w   = tid >> 6;
    const int wr  = w >> 2, wc = w & 3;        // 2 row-waves x 4 col-waves

    int id  = blockIdx.y * gridDim.x + blockIdx.x;
    int xcd = id & 7, j = id >> 3;             // j in 0..63
    int bx  = (xcd & 1) * 8 + (j & 7);         // 0..15
    int by  = (xcd >> 1) * 8 + (j >> 3);       // 0..31
    const int bm0 = by * 128, bn0 = bx * 128;

    const int srow = tid >> 2;                 // 0..127
    const int sq   = (tid & 3) ^ ((srow >> 1) & 3);
    const size_t aoff = (size_t)(bm0 + srow) * Dq + sq * 8;
    const size_t boff = (size_t)(bn0 + srow) * Dq + sq * 8;

    const int rowa = (wr * 64 + (l & 15)) * 32;
    const int rowb = (wc * 32 + (l & 15)) * 32;
    const int q0 = (((l >> 4)) ^ (((l & 15) >> 1) & 3)) << 3;

    auto stage = [&](int b, int kt) {          // 3 gl16 (x, gw, uw: 8 KB each)
        unsigned short* d = &lds[b * 12288 + (w << 9)];
        gl16(xh  + aoff + kt, d + 0);
        gl16(gwh + boff + kt, d + 4096);
        gl16(uwh + boff + kt, d + 8192);
    };

    f32x4 accg[4][2], accu[4][2];
#pragma unroll
    for (int i = 0; i < 4; i++)
#pragma unroll
        for (int jj = 0; jj < 2; jj++) {
            accg[i][jj] = (f32x4){0.f, 0.f, 0.f, 0.f};
            accu[i][jj] = (f32x4){0.f, 0.f, 0.f, 0.f};
        }

    stage(0, 0);
    int cur = 0;
    for (int kt = 0; kt < Dq; kt += 32) {
        if (kt + 32 < Dq) {
            stage(cur ^ 1, kt + 32);
            WAITV_BAR(3);
        } else {
            WAITV_BAR(0);
        }
        const int cb = cur * 12288;
        bfrag a4[4], g4[2], u4[2];
#pragma unroll
        for (int f = 0; f < 4; f++)
            a4[f] = *(const bfrag*)&lds[cb + rowa + f * 512 + q0];
#pragma unroll
        for (int f = 0; f < 2; f++) {
            g4[f] = *(const bfrag*)&lds[cb + 4096 + rowb + f * 512 + q0];
            u4[f] = *(const bfrag*)&lds[cb + 8192 + rowb + f * 512 + q0];
        }
#pragma unroll
        for (int i = 0; i < 4; i++)
#pragma unroll
            for (int jj = 0; jj < 2; jj++) {
                accg[i][jj] = __builtin_amdgcn_mfma_f32_16x16x32_bf16(a4[i], g4[jj], accg[i][jj], 0, 0, 0);
                accu[i][jj] = __builtin_amdgcn_mfma_f32_16x16x32_bf16(a4[i], u4[jj], accu[i][jj], 0, 0, 0);
            }
        END_BAR();
        cur ^= 1;
    }

    const int crow0 = bm0 + wr * 64 + (l >> 4) * 4;
    const int ccol0 = bn0 + wc * 32 + (l & 15);
#pragma unroll
    for (int i = 0; i < 4; i++)
#pragma unroll
        for (int jj = 0; jj < 2; jj++)
#pragma unroll
            for (int r = 0; r < 4; r++) {
                size_t idx = (size_t)(crow0 + i * 16 + r) * Hq + (ccol0 + jj * 16);
                hh[idx] = f2bf(silu_f(accg[i][jj][r]) * accu[i][jj][r]);
            }
}

// ---------------------------------------------------------------------------
// Final fused GEMM, BK=64, 8 waves (2Mx4N), 3-deep ring (96 KB LDS):
//   out[4096][1024] = hh@dwh^T (K=2048) + acat@kcat^T (K=256)
// ---------------------------------------------------------------------------
__global__ __launch_bounds__(512)
void gfinal(const unsigned short* __restrict__ hh, const unsigned short* __restrict__ dwh,
            const unsigned short* __restrict__ acat, const unsigned short* __restrict__ kcat,
            float* __restrict__ out)
{
    __shared__ __align__(16) unsigned short lds[49152];  // 3 bufs x 16384
    const int tid = threadIdx.x;
    const int l   = tid & 63;
    const int w   = tid >> 6;
    const int wr  = w >> 2, wc = w & 3;

    int nb  = gridDim.x * gridDim.y;                      // 256
    int id  = blockIdx.y * gridDim.x + blockIdx.x;
    int id2 = (id & 7) * (nb >> 3) + (id >> 3);
    int bx  = id2 % gridDim.x, by = id2 / gridDim.x;
    const int bm0 = by * 128, bn0 = bx * 128;

    const int srow = tid >> 3;
    const int sq   = (tid & 7) ^ (srow & 7);
    const int rowa = (wr * 64 + (l & 15)) * 64;
    const int rowb = (wc * 32 + (l & 15)) * 64;
    const int q0 = (((l >> 4)    ) ^ (l & 7)) << 3;
    const int q1 = (((l >> 4) + 4) ^ (l & 7)) << 3;

    f32x4 acc[4][2];
#pragma unroll
    for (int i = 0; i < 4; i++)
#pragma unroll
        for (int j = 0; j < 2; j++) acc[i][j] = (f32x4){0.f, 0.f, 0.f, 0.f};

    // ---- main: K=2048, 3-deep ----
    {
        const size_t aoff = (size_t)(bm0 + srow) * Hq + sq * 8;
        const size_t boff = (size_t)(bn0 + srow) * Hq + sq * 8;
        const size_t r64  = (size_t)64 * Hq;
        auto stage = [&](int b, int kt) {      // 4 gl16
            unsigned short* d = &lds[b * 16384 + (w << 9)];
            gl16(hh  + aoff + kt,       d + 0);
            gl16(hh  + aoff + kt + r64, d + 4096);
            gl16(dwh + boff + kt,       d + 8192);
            gl16(dwh + boff + kt + r64, d + 12288);
        };
        stage(0, 0);
        stage(1, 64);
        int cur = 0;
        for (int kt = 0; kt < Hq; kt += 64) {
            if (kt + 64 < Hq) { WAITV_BAR(4); } else { WAITV_BAR(0); }
            if (kt + 128 < Hq) {
                int nb3 = (cur + 2 >= 3) ? cur - 1 : cur + 2;
                stage(nb3, kt + 128);
            }
            const int cb = cur * 16384;
#pragma unroll
            for (int ks = 0; ks < 2; ks++) {
                const int qo = ks ? q1 : q0;
                bfrag a4[4], b4[2];
#pragma unroll
                for (int f = 0; f < 4; f++)
                    a4[f] = *(const bfrag*)&lds[cb + rowa + f * 1024 + qo];
#pragma unroll
                for (int f = 0; f < 2; f++)
                    b4[f] = *(const bfrag*)&lds[cb + 8192 + rowb + f * 1024 + qo];
#pragma unroll
                for (int i = 0; i < 4; i++)
#pragma unroll
                    for (int j = 0; j < 2; j++)
                        acc[i][j] = __builtin_amdgcn_mfma_f32_16x16x32_bf16(a4[i], b4[j], acc[i][j], 0, 0, 0);
            }
            cur = (cur == 2) ? 0 : cur + 1;
        }
    }
    END_BAR();   // all waves done with main's last compute before tail staging
    // ---- tail: K=256 over [acat | kcat], 3-deep (4 iters) ----
    {
        const size_t aoff = (size_t)(bm0 + srow) * 256 + sq * 8;
        const size_t boff = (size_t)(bn0 + srow) * 256 + sq * 8;
        const size_t r64  = (size_t)64 * 256;
        auto stage2 = [&](int b, int kt) {
            unsigned short* d = &lds[b * 16384 + (w << 9)];
            gl16(acat + aoff + kt,       d + 0);
            gl16(acat + aoff + kt + r64, d + 4096);
            gl16(kcat + boff + kt,       d + 8192);
            gl16(kcat + boff + kt + r64, d + 12288);
        };
        stage2(0, 0);
        stage2(1, 64);
        int cur = 0;
        for (int kt = 0; kt < 256; kt += 64) {
            if (kt + 64 < 256) { WAITV_BAR(4); } else { WAITV_BAR(0); }
            if (kt + 128 < 256) {
                int nb3 = (cur + 2 >= 3) ? cur - 1 : cur + 2;
                stage2(nb3, kt + 128);
            }
            const int cb = cur * 16384;
#pragma unroll
            for (int ks = 0; ks < 2; ks++) {
                const int qo = ks ? q1 : q0;
                bfrag a4[4], b4[2];
#pragma unroll
                for (int f = 0; f < 4; f++)
                    a4[f] = *(const bfrag*)&lds[cb + rowa + f * 1024 + qo];
#pragma unroll
                for (int f = 0; f < 2; f++)
                    b4[f] = *(const bfrag*)&lds[cb + 8192 + rowb + f * 1024 + qo];
#pragma unroll
                for (int i = 0; i < 4; i++)
#pragma unroll
                    for (int j = 0; j < 2; j++)
                        acc[i][j] = __builtin_amdgcn_mfma_f32_16x16x32_bf16(a4[i], b4[j], acc[i][j], 0, 0, 0);
            }
            cur = (cur == 2) ? 0 : cur + 1;
        }
    }

    const int crow0 = bm0 + wr * 64 + (l >> 4) * 4;
    const int ccol0 = bn0 + wc * 32 + (l & 15);
#pragma unroll
    for (int i = 0; i < 4; i++)
#pragma unroll
        for (int j = 0; j < 2; j++)
#pragma unroll
            for (int r = 0; r < 4; r++)
                out[(size_t)(crow0 + i * 16 + r) * Dq + ccol0 + j * 16] = acc[i][j][r];
}

// Reduce NZ split-K partials + LayerNorm over A=128 -> bf16.
template<int NZ>
__global__ __launch_bounds__(256)
void rln(const float* __restrict__ p, unsigned short* __restrict__ oh,
         const float* __restrict__ g, const float* __restrict__ b, long pstride)
{
    int row  = blockIdx.x * 4 + (threadIdx.x >> 6);
    int lane = threadIdx.x & 63;
    long base = (long)row * Aq;
    float x0 = 0.f, x1 = 0.f;
#pragma unroll
    for (int z = 0; z < NZ; z++) {
        x0 += p[base + z * pstride + lane];
        x1 += p[base + z * pstride + lane + 64];
    }
    float s  = x0 + x1;
    float ss = x0 * x0 + x1 * x1;
#pragma unroll
    for (int off = 32; off > 0; off >>= 1) {
        s  += __shfl_xor(s, off);
        ss += __shfl_xor(ss, off);
    }
    float m  = s * (1.0f / Aq);
    float v  = ss * (1.0f / Aq) - m * m;
    float rs = rsqrtf(v + 1e-5f);
    oh[base + lane]      = f2bf((x0 - m) * rs * g[lane]      + b[lane]);
    oh[base + lane + 64] = f2bf((x1 - m) * rs * g[lane + 64] + b[lane + 64]);
}

// Reduce NZ split-K partials [bz][NZ][rowsPerB][A] -> scaled bf16.
// Output col = ocol + bz*ocolStep (lets one launch fill both kcat halves).
template<int NZ>
__global__ __launch_bounds__(256)
void rbf(const float* __restrict__ p, unsigned short* __restrict__ o,
         int rowsPerB, float scale, int total, int ostride, int ocol, int ocolStep)
{
    int i = blockIdx.x * 256 + threadIdx.x;
    if (i >= total) return;
    int n = i >> 7, a = i & 127;
    int bz = n / rowsPerB, s = n - bz * rowsPerB;
    long base = ((long)bz * NZ) * rowsPerB * Aq + (long)s * Aq + a;
    float acc = 0.f;
#pragma unroll
    for (int z = 0; z < NZ; z++) acc += p[base + (long)z * rowsPerB * Aq];
    o[(long)s * ostride + (ocol + bz * ocolStep) + a +
      (ocolStep ? 0 : (long)bz * rowsPerB * ostride)] = f2bf(acc * scale);
}

// mixed[n,:] = sum_e ew[n,e] * LN_e(h[e,n,:])  -> bf16 into acat col 128.
__global__ __launch_bounds__(256)
void mix_ln(const float* __restrict__ h, const float* __restrict__ ew,
            const float* __restrict__ g, const float* __restrict__ bb,
            unsigned short* __restrict__ acat)
{
    int n    = blockIdx.x * 4 + (threadIdx.x >> 6);
    int lane = threadIdx.x & 63;
    float a0 = 0.0f, a1 = 0.0f;
#pragma unroll
    for (int e = 0; e < Eq; e++) {
        const float* r = h + ((long)e * Nq + n) * Aq;
        float x0 = r[lane], x1 = r[lane + 64];
        float s  = x0 + x1;
        float ss = x0 * x0 + x1 * x1;
#pragma unroll
        for (int off = 32; off > 0; off >>= 1) {
            s  += __shfl_xor(s, off);
            ss += __shfl_xor(ss, off);
        }
        float m  = s * (1.0f / Aq);
        float v  = ss * (1.0f / Aq) - m * m;
        float rs = rsqrtf(v + 1e-5f);
        float wv = ew[(long)n * Eq + e];
        a0 += wv * ((x0 - m) * rs * g[e * Aq + lane]      + bb[e * Aq + lane]);
        a1 += wv * ((x1 - m) * rs * g[e * Aq + lane + 64] + bb[e * Aq + lane + 64]);
    }
    acat[(long)n * 256 + 128 + lane]      = f2bf(a0);
    acat[(long)n * 256 + 128 + lane + 64] = f2bf(a1);
}

extern "C" void kernel_launch(void* const* d_in, const int* in_sizes, int n_in,
                              void* d_out, int out_size, void* d_ws, size_t ws_size,
                              hipStream_t stream)
{
    const float* x             = (const float*)d_in[0];
    const float* ew            = (const float*)d_in[1];
    const float* up_w          = (const float*)d_in[2];
    const float* gate_w        = (const float*)d_in[3];
    const float* down_w        = (const float*)d_in[4];
    const float* pre_w         = (const float*)d_in[5];
    const float* post_w        = (const float*)d_in[6];
    const float* an_g          = (const float*)d_in[7];
    const float* an_b          = (const float*)d_in[8];
    const float* adapt_proj_w  = (const float*)d_in[9];
    const float* adapter_w     = (const float*)d_in[10];
    const float* adapter_g     = (const float*)d_in[11];
    const float* adapter_b     = (const float*)d_in[12];
    const float* expert_proj_w = (const float*)d_in[13];
    const float* output_proj_w = (const float*)d_in[14];
    float* out = (float*)d_out;

    // ---- workspace (KB offsets; peak ~81 MB) ----
#define OFF(kb) ((char*)d_ws + (size_t)(kb) * 1024)
    float* kdp  = (float*)OFF(0);        // [16][D][A] 8MB   (phase 1, bz=0)
    float* wfp  = (float*)OFF(8192);     // 8MB              (phase 1, bz=1)
    float* p1   = (float*)OFF(16384);    // [8][N][A] 16MB   (phase 1)
    float* p2   = (float*)OFF(0);        // [8][N][A] 16MB   (phase 3)
    float* p3   = (float*)OFF(0);        // [2][8][S][A] 16MB (phase 4, after p2 dead)
    float* h_e  = (float*)OFF(0);        // [E][N][A] 16MB    (phase 5, after p3 dead)
    unsigned short* hh   = (unsigned short*)OFF(32768);  // [N,H] 16MB
    unsigned short* xh   = (unsigned short*)OFF(49152);  // 8MB
    unsigned short* gwh  = (unsigned short*)OFF(57344);  // 4MB
    unsigned short* uwh  = (unsigned short*)OFF(61440);  // 4MB
    unsigned short* dwh  = (unsigned short*)OFF(65536);  // 4MB   } contiguous pair
    unsigned short* oph  = (unsigned short*)OFF(69632);  // 4MB   } for batched kcat
    unsigned short* pwh  = (unsigned short*)OFF(73728);  // .25MB
    unsigned short* powh = (unsigned short*)OFF(73984);  // .5MB
    unsigned short* apT  = (unsigned short*)OFF(74496);  // .5MB  } contiguous pair
    unsigned short* epT  = (unsigned short*)OFF(75008);  // .5MB  }
    unsigned short* ainh = (unsigned short*)OFF(75520);  // 1MB
    unsigned short* ainT = (unsigned short*)OFF(76544);  // [B][A][S] 1MB
    unsigned short* aouth= (unsigned short*)OFF(77568);  // 1MB
    unsigned short* adw  = (unsigned short*)OFF(78592);  // .25MB
    unsigned short* kcat = (unsigned short*)OFF(78848);  // [D][256] .5MB
    unsigned short* acat = (unsigned short*)OFF(79360);  // [N][256] 2MB -> 81408
#undef OFF

    dim3 blk(256), blk512(512);
    const long NA = (long)Nq * Aq;
    const long SA = (long)Sq * Aq;
    const long SS = (long)Sq * Sq;

    // 1. conversions + transposes (both fp32 transposes in ONE launch, z=2)
    convert_all<<<dim3(2048), blk, 0, stream>>>(x, gate_w, up_w, down_w, pre_w, post_w,
        output_proj_w, adapter_w, xh, gwh, uwh, dwh, pwh, powh, oph, adw);
    transb<float><<<dim3(4, 64, 2), blk, 0, stream>>>(adapt_proj_w, expert_proj_w,
        apT, Hq, Aq);

    // 2. weight fusions (batched bz=2): bz0 = dwh@apT -> kdp, bz1 = oph@epT -> wfp
    mg<0><<<dim3(1, 8, 32), blk512, 0, stream>>>(dwh, apT, kdp, Aq, Hq, 16,
        (long)Dq * Hq, (long)Aq * Hq, (long)16 * Dq * Aq, (long)Dq * Aq);
    rbf<16><<<dim3(1024), blk, 0, stream>>>(kdp, kcat, Dq, 1.0f, 2 * Dq * Aq, 256, 0, 128);

    // 3. ain = LN(x @ pre_w^T)  (split-K 8)
    mg<0><<<dim3(1, 32, 8), blk512, 0, stream>>>(xh, pwh, p1, Aq, Dq, 8, 0, 0, 0, NA);
    rln<8><<<dim3(1024), blk, 0, stream>>>(p1, ainh, an_g, an_b, NA);
    transb<unsigned short><<<dim3(4, 64, 2), blk, 0, stream>>>(ainh, nullptr,
        ainT, Sq, Aq);

    // 4. fused SwiGLU: hh = bf16(silu(x@gw^T) * (x@uw^T))
    gup<<<dim3(16, 32), blk512, 0, stream>>>(xh, gwh, uwh, hh);

    // 5. aout = LN(hidden @ post_w^T)  (split-K 8)
    mg<0><<<dim3(1, 32, 8), blk512, 0, stream>>>(hh, powh, p2, Aq, Hq, 8, 0, 0, 0, NA);
    rln<8><<<dim3(1024), blk, 0, stream>>>(p2, aouth, an_g, an_b, NA);

    // 6+7. FUSED: p3[b][tz] = partial( silu(clip(ain@aout^T)) @ ain ), no wmat
    gsc<<<dim3(8, 16, 2), blk512, 0, stream>>>(ainh, aouth, ainT, p3);
    rbf<8><<<dim3(2048), blk, 0, stream>>>(p3, acat, Sq, 0.1f, Nq * Aq, 256, 0, 0);

    // 8. expert path: h_e, then acat[:,128:256] = mixed
    mg<0><<<dim3(1, 32, 8), blk512, 0, stream>>>(ainh, adw, h_e, Aq, Aq, 1,
        0, (long)Aq * Aq, NA, 0);
    mix_ln<<<dim3(1024), blk, 0, stream>>>(h_e, ew, adapter_g, adapter_b, acat);

    // 9. out = hh@dwh^T + acat@kcat^T
    gfinal<<<dim3(8, 32), blk512, 0, stream>>>(hh, dwh, acat, kcat, out);
}

// Round 18
// 163.016 us; speedup vs baseline: 1.0167x; 1.0097x over previous
//
#include <hip/hip_runtime.h>
#include <hip/hip_bf16.h>
#include <math.h>

// Problem constants (B,S,D,E = 2,2048,1024,8)
#define Bq 2
#define Sq 2048
#define Dq 1024
#define Eq 8
#define Hq 2048            // 2*D
#define Aq 128             // H/16
#define Nq (Bq*Sq)         // 4096 tokens

typedef __attribute__((ext_vector_type(4))) float f32x4;
typedef __attribute__((ext_vector_type(8))) short bfrag;   // 8 bf16 in 4 VGPRs

__device__ __forceinline__ float silu_f(float x) {
    return x / (1.0f + expf(-x));
}
__device__ __forceinline__ unsigned short f2bf(float x) {  // RNE fp32->bf16
    unsigned u = __float_as_uint(x);
    u += 0x7fffu + ((u >> 16) & 1u);
    return (unsigned short)(u >> 16);
}
__device__ __forceinline__ float bf2f(unsigned short h) {
    return __uint_as_float(((unsigned)h) << 16);
}
__device__ __forceinline__ void gl16(const unsigned short* g, unsigned short* l) {
    __builtin_amdgcn_global_load_lds(
        (const __attribute__((address_space(1))) void*)g,
        (__attribute__((address_space(3))) void*)(void*)l, 16, 0, 0);
}

// Counted-vmcnt wait-then-barrier (T4). vmcnt retires IN ORDER.
#define WAITV_BAR(N)                                            \
    asm volatile("s_waitcnt vmcnt(" #N ")" ::: "memory");       \
    __builtin_amdgcn_s_barrier();                               \
    asm volatile("" ::: "memory")
#define END_BAR()                                               \
    asm volatile("" ::: "memory");                              \
    __builtin_amdgcn_s_barrier();                               \
    asm volatile("" ::: "memory")

// ---------------------------------------------------------------------------
// convert_all: fp32 -> bf16 for all inputs (blocks 0..2047, grid-stride)
// PLUS the two fp32 transposes (blocks 2048..2559): adapt_proj/expert_proj
// [H][A] -> bf16 [A][H] at apT + z*H*A.   (r18: one dispatch fewer)
// ---------------------------------------------------------------------------
__global__ __launch_bounds__(256)
void convert_all(const float* __restrict__ x,  const float* __restrict__ gw,
                 const float* __restrict__ uw, const float* __restrict__ dw,
                 const float* __restrict__ pw, const float* __restrict__ ow,
                 const float* __restrict__ opw, const float* __restrict__ aw,
                 const float* __restrict__ apw, const float* __restrict__ epw,
                 unsigned short* xh,  unsigned short* gwh, unsigned short* uwh,
                 unsigned short* dwh, unsigned short* pwh, unsigned short* powh,
                 unsigned short* oph, unsigned short* adw, unsigned short* apT)
{
    __shared__ float t[32][33];
    if (blockIdx.x >= 2048) {
        // transpose path: 512 blocks = 2 z x (4 bx x 64 by)
        int bid = blockIdx.x - 2048;
        int z   = bid >> 8;
        int rem = bid & 255;
        int bx  = rem & 3, by = rem >> 2;
        const float* in = z ? epw : apw;
        unsigned short* out = apT + (size_t)z * Hq * Aq;
        int tx = threadIdx.x & 31, ty = threadIdx.x >> 5;
        int r0 = by * 32, c0 = bx * 32;
#pragma unroll
        for (int j = 0; j < 4; j++)
            t[ty + j * 8][tx] = in[(size_t)(r0 + ty + j * 8) * Aq + c0 + tx];
        __syncthreads();
#pragma unroll
        for (int j = 0; j < 4; j++)
            out[(size_t)(c0 + ty + j * 8) * Hq + r0 + tx] = f2bf(t[tx][ty + j * 8]);
        return;
    }
    const int T = 3276800;
    for (int i = blockIdx.x * 256 + threadIdx.x; i < T; i += 2048 * 256) {
        const float* in; unsigned short* hi; int j = i;
        if (j < 1048576)                 { in = x;   hi = xh;  }
        else if ((j -= 1048576) < 524288){ in = gw;  hi = gwh; }
        else if ((j -= 524288) < 524288) { in = uw;  hi = uwh; }
        else if ((j -= 524288) < 524288) { in = dw;  hi = dwh; }
        else if ((j -= 524288) < 32768)  { in = pw;  hi = pwh; }
        else if ((j -= 32768) < 65536)   { in = ow;  hi = powh; }
        else if ((j -= 65536) < 524288)  { in = opw; hi = oph; }
        else { j -= 524288;                in = aw;  hi = adw; }
        float4 v = ((const float4*)in)[j];
        ((ushort4*)hi)[j] = make_ushort4(f2bf(v.x), f2bf(v.y), f2bf(v.z), f2bf(v.w));
    }
}

// ---------------------------------------------------------------------------
// 1-term bf16 MFMA GEMM, BK=64, 8 waves (2Mx4N, wave tile 64x32), 2-buf +
// counted-vmcnt. 64 KB LDS. (Proven.)
// EPI: 0 = fp32 store (+bz*zC+kz*pz); 1 = bf16 silu-clip (+bz*zC);
//      2 = bf16 plain store (+bz*zC).
// ---------------------------------------------------------------------------
template<int EPI>
__global__ __launch_bounds__(512)
void mg(const unsigned short* __restrict__ Ah, const unsigned short* __restrict__ Bh,
        void* __restrict__ Cv, int N, int K, int kchunks,
        long zA, long zB, long zC, long pz)
{
    __shared__ __align__(16) unsigned short lds[32768];  // 2 bufs x (A 8192 | B 8192)

    const int tid = threadIdx.x;
    const int l   = tid & 63;
    const int w   = tid >> 6;                  // 0..7
    const int wr  = w >> 2, wc = w & 3;
    const int bm0 = blockIdx.y * 128, bn0 = blockIdx.x * 128;
    const int bz  = blockIdx.z / kchunks;
    const int kz  = blockIdx.z - bz * kchunks;
    const int kcnt = K / kchunks;
    const int kbeg = kz * kcnt;
    const int kend = kbeg + kcnt;

    const unsigned short* A0 = Ah + (size_t)bz * zA;
    const unsigned short* B0 = Bh + (size_t)bz * zB;

    const int srow = tid >> 3;                 // 0..63 (+64 round 1)
    const int sq   = (tid & 7) ^ (srow & 7);
    const size_t aoff = (size_t)(bm0 + srow) * K + sq * 8;
    const size_t boff = (size_t)(bn0 + srow) * K + sq * 8;
    const size_t r64  = (size_t)64 * K;

    auto stage = [&](int b, int kt) {          // 4 gl16
        unsigned short* d = &lds[b * 16384 + (w << 9)];
        gl16(A0 + aoff + kt,       d + 0);
        gl16(A0 + aoff + kt + r64, d + 4096);
        gl16(B0 + boff + kt,       d + 8192);
        gl16(B0 + boff + kt + r64, d + 12288);
    };

    const int rowa = (wr * 64 + (l & 15)) * 64;
    const int rowb = (wc * 32 + (l & 15)) * 64;
    const int q0 = (((l >> 4)    ) ^ (l & 7)) << 3;
    const int q1 = (((l >> 4) + 4) ^ (l & 7)) << 3;

    f32x4 acc[4][2];
#pragma unroll
    for (int i = 0; i < 4; i++)
#pragma unroll
        for (int j = 0; j < 2; j++) acc[i][j] = (f32x4){0.f, 0.f, 0.f, 0.f};

    stage(0, kbeg);
    int cur = 0;
    for (int kt = kbeg; kt < kend; kt += 64) {
        if (kt + 64 < kend) {
            stage(cur ^ 1, kt + 64);
            WAITV_BAR(4);
        } else {
            WAITV_BAR(0);
        }
        const int cb = cur * 16384;
#pragma unroll
        for (int ks = 0; ks < 2; ks++) {
            const int qo = ks ? q1 : q0;
            bfrag a4[4], b4[2];
#pragma unroll
            for (int f = 0; f < 4; f++)
                a4[f] = *(const bfrag*)&lds[cb + rowa + f * 1024 + qo];
#pragma unroll
            for (int f = 0; f < 2; f++)
                b4[f] = *(const bfrag*)&lds[cb + 8192 + rowb + f * 1024 + qo];
#pragma unroll
            for (int i = 0; i < 4; i++)
#pragma unroll
                for (int j = 0; j < 2; j++)
                    acc[i][j] = __builtin_amdgcn_mfma_f32_16x16x32_bf16(a4[i], b4[j], acc[i][j], 0, 0, 0);
        }
        END_BAR();
        cur ^= 1;
    }

    const int crow0 = bm0 + wr * 64 + (l >> 4) * 4;
    const int ccol0 = bn0 + wc * 32 + (l & 15);
#pragma unroll
    for (int i = 0; i < 4; i++)
#pragma unroll
        for (int j = 0; j < 2; j++)
#pragma unroll
            for (int r = 0; r < 4; r++) {
                size_t idx = (size_t)(crow0 + i * 16 + r) * N + (ccol0 + j * 16);
                float v = acc[i][j][r];
                if (EPI == 0)
                    ((float*)Cv + (size_t)bz * zC + (size_t)kz * pz)[idx] = v;
                else if (EPI == 1)
                    ((unsigned short*)Cv + (size_t)bz * zC)[idx] =
                        f2bf(silu_f(fminf(fmaxf(v, -5.f), 5.f)));
                else
                    ((unsigned short*)Cv + (size_t)bz * zC)[idx] = f2bf(v);
            }
}

// ---------------------------------------------------------------------------
// Fused score-combine (steps 6+7, no wmat): per (b, ib, tz):
//   P = bf16(silu(clip(ain_i @ aout_t^T))) in LDS; partial += P @ ainT_t.
// (Proven r17; numerics identical to the materialized path.)
// ---------------------------------------------------------------------------
__global__ __launch_bounds__(512)
void gsc(const unsigned short* __restrict__ ainh, const unsigned short* __restrict__ aouth,
         const unsigned short* __restrict__ ainT, float* __restrict__ p3)
{
    __shared__ __align__(16) unsigned short lds[65536];  // 128 KB
    const int AIN = 0, AOUT = 16384, AINT = 32768, PB = 49152;

    const int tid = threadIdx.x;
    const int l   = tid & 63;
    const int w   = tid >> 6;
    const int wr  = w >> 2, wc = w & 3;
    const int tz  = blockIdx.x;        // 0..7
    const int ib  = blockIdx.y;        // 0..15
    const int b   = blockIdx.z;        // 0..1
    const long SA = (long)Sq * Aq;

    auto stage32 = [&](int base, const unsigned short* src, size_t kstride) {
#pragma unroll
        for (int rd = 0; rd < 4; rd++) {
            int grow = rd * 32 + (w << 2) + (l >> 4);
            int slot = (l & 15) ^ (grow & 15);
            gl16(src + (size_t)grow * kstride + slot * 8,
                 &lds[base + rd * 4096 + (w << 9)]);
        }
    };

    const unsigned short* ainI_src = ainh + (size_t)b * SA + (size_t)(ib * 128) * Aq;
    f32x4 acc2[4][2];
#pragma unroll
    for (int i = 0; i < 4; i++)
#pragma unroll
        for (int j = 0; j < 2; j++) acc2[i][j] = (f32x4){0.f, 0.f, 0.f, 0.f};

    {
        int tglob = tz * 2;
        stage32(AIN,  ainI_src, Aq);
        stage32(AOUT, aouth + (size_t)b * SA + (size_t)(tglob * 128) * Aq, Aq);
        stage32(AINT, ainT  + (size_t)b * SA + (size_t)(tglob * 128), Sq);
        WAITV_BAR(0);
    }

    const int rowa = (wr * 64 + (l & 15)) * 128;
    const int rowb = (wc * 32 + (l & 15)) * 128;

#pragma unroll 1
    for (int t = 0; t < 2; t++) {
        if (t == 1) {
            int tglob = tz * 2 + 1;
            stage32(AOUT, aouth + (size_t)b * SA + (size_t)(tglob * 128) * Aq, Aq);
            stage32(AINT, ainT  + (size_t)b * SA + (size_t)(tglob * 128), Sq);
            WAITV_BAR(0);
        }
        f32x4 acc1[4][2];
#pragma unroll
        for (int i = 0; i < 4; i++)
#pragma unroll
            for (int j = 0; j < 2; j++) acc1[i][j] = (f32x4){0.f, 0.f, 0.f, 0.f};
#pragma unroll
        for (int ks = 0; ks < 4; ks++) {
            const int qo = ((ks * 4 + (l >> 4)) ^ (l & 15)) << 3;
            bfrag a4[4], b4[2];
#pragma unroll
            for (int f = 0; f < 4; f++)
                a4[f] = *(const bfrag*)&lds[AIN + rowa + f * 2048 + qo];
#pragma unroll
            for (int f = 0; f < 2; f++)
                b4[f] = *(const bfrag*)&lds[AOUT + rowb + f * 2048 + qo];
#pragma unroll
            for (int i = 0; i < 4; i++)
#pragma unroll
                for (int j = 0; j < 2; j++)
                    acc1[i][j] = __builtin_amdgcn_mfma_f32_16x16x32_bf16(a4[i], b4[j], acc1[i][j], 0, 0, 0);
        }
        {
            const int prow0 = wr * 64 + (l >> 4) * 4;
            const int pcol0 = wc * 32 + (l & 15);
#pragma unroll
            for (int i = 0; i < 4; i++)
#pragma unroll
                for (int j = 0; j < 2; j++)
#pragma unroll
                    for (int r = 0; r < 4; r++) {
                        int pr = prow0 + i * 16 + r;
                        int pc = pcol0 + j * 16;
                        float v = silu_f(fminf(fmaxf(acc1[i][j][r], -5.f), 5.f));
                        lds[PB + pr * 128 + (((pc >> 3) ^ (pr & 15)) << 3) + (pc & 7)] = f2bf(v);
                    }
        }
        __syncthreads();
#pragma unroll
        for (int ks = 0; ks < 4; ks++) {
            const int qo = ((ks * 4 + (l >> 4)) ^ (l & 15)) << 3;
            bfrag a4[4], b4[2];
#pragma unroll
            for (int f = 0; f < 4; f++)
                a4[f] = *(const bfrag*)&lds[PB + rowa + f * 2048 + qo];
#pragma unroll
            for (int f = 0; f < 2; f++)
                b4[f] = *(const bfrag*)&lds[AINT + rowb + f * 2048 + qo];
#pragma unroll
            for (int i = 0; i < 4; i++)
#pragma unroll
                for (int j = 0; j < 2; j++)
                    acc2[i][j] = __builtin_amdgcn_mfma_f32_16x16x32_bf16(a4[i], b4[j], acc2[i][j], 0, 0, 0);
        }
        __syncthreads();
    }

    const int crow0 = wr * 64 + (l >> 4) * 4;
    const int ccol0 = wc * 32 + (l & 15);
    float* dst = p3 + ((size_t)(b * 8 + tz) * Sq + ib * 128) * Aq;
#pragma unroll
    for (int i = 0; i < 4; i++)
#pragma unroll
        for (int j = 0; j < 2; j++)
#pragma unroll
            for (int r = 0; r < 4; r++)
                dst[(size_t)(crow0 + i * 16 + r) * Aq + ccol0 + j * 16] = acc2[i][j][r];
}

// ---------------------------------------------------------------------------
// Fused gate+up GEMM, tile 128x128, BK=32, 8 waves, 2-buf + counted-vmcnt(3).
// 48 KB LDS -> 2 blocks/CU. Conflict-free (row>>1)&3 swizzle (r16: verified 0).
// ---------------------------------------------------------------------------
__global__ __launch_bounds__(512)
void gup(const unsigned short* __restrict__ xh, const unsigned short* __restrict__ gwh,
         const unsigned short* __restrict__ uwh, unsigned short* __restrict__ hh)
{
    __shared__ __align__(16) unsigned short lds[24576];
    const int tid = threadIdx.x;
    const int l   = tid & 63;
    const int w   = tid >> 6;
    const int wr  = w >> 2, wc = w & 3;

    int id  = blockIdx.y * gridDim.x + blockIdx.x;
    int xcd = id & 7, j = id >> 3;
    int bx  = (xcd & 1) * 8 + (j & 7);
    int by  = (xcd >> 1) * 8 + (j >> 3);
    const int bm0 = by * 128, bn0 = bx * 128;

    const int srow = tid >> 2;
    const int sq   = (tid & 3) ^ ((srow >> 1) & 3);
    const size_t aoff = (size_t)(bm0 + srow) * Dq + sq * 8;
    const size_t boff = (size_t)(bn0 + srow) * Dq + sq * 8;

    const int rowa = (wr * 64 + (l & 15)) * 32;
    const int rowb = (wc * 32 + (l & 15)) * 32;
    const int q0 = (((l >> 4)) ^ (((l & 15) >> 1) & 3)) << 3;

    auto stage = [&](int b, int kt) {
        unsigned short* d = &lds[b * 12288 + (w << 9)];
        gl16(xh  + aoff + kt, d + 0);
        gl16(gwh + boff + kt, d + 4096);
        gl16(uwh + boff + kt, d + 8192);
    };

    f32x4 accg[4][2], accu[4][2];
#pragma unroll
    for (int i = 0; i < 4; i++)
#pragma unroll
        for (int jj = 0; jj < 2; jj++) {
            accg[i][jj] = (f32x4){0.f, 0.f, 0.f, 0.f};
            accu[i][jj] = (f32x4){0.f, 0.f, 0.f, 0.f};
        }

    stage(0, 0);
    int cur = 0;
    for (int kt = 0; kt < Dq; kt += 32) {
        if (kt + 32 < Dq) {
            stage(cur ^ 1, kt + 32);
            WAITV_BAR(3);
        } else {
            WAITV_BAR(0);
        }
        const int cb = cur * 12288;
        bfrag a4[4], g4[2], u4[2];
#pragma unroll
        for (int f = 0; f < 4; f++)
            a4[f] = *(const bfrag*)&lds[cb + rowa + f * 512 + q0];
#pragma unroll
        for (int f = 0; f < 2; f++) {
            g4[f] = *(const bfrag*)&lds[cb + 4096 + rowb + f * 512 + q0];
            u4[f] = *(const bfrag*)&lds[cb + 8192 + rowb + f * 512 + q0];
        }
#pragma unroll
        for (int i = 0; i < 4; i++)
#pragma unroll
            for (int jj = 0; jj < 2; jj++) {
                accg[i][jj] = __builtin_amdgcn_mfma_f32_16x16x32_bf16(a4[i], g4[jj], accg[i][jj], 0, 0, 0);
                accu[i][jj] = __builtin_amdgcn_mfma_f32_16x16x32_bf16(a4[i], u4[jj], accu[i][jj], 0, 0, 0);
            }
        END_BAR();
        cur ^= 1;
    }

    const int crow0 = bm0 + wr * 64 + (l >> 4) * 4;
    const int ccol0 = bn0 + wc * 32 + (l & 15);
#pragma unroll
    for (int i = 0; i < 4; i++)
#pragma unroll
        for (int jj = 0; jj < 2; jj++)
#pragma unroll
            for (int r = 0; r < 4; r++) {
                size_t idx = (size_t)(crow0 + i * 16 + r) * Hq + (ccol0 + jj * 16);
                hh[idx] = f2bf(silu_f(accg[i][jj][r]) * accu[i][jj][r]);
            }
}

// ---------------------------------------------------------------------------
// Final fused GEMM, BK=64, 8 waves (2Mx4N), 3-deep ring (96 KB LDS):
//   out[4096][1024] = hh@dwh^T (K=2048) + acat@kcat^T (K=256)
// ---------------------------------------------------------------------------
__global__ __launch_bounds__(512)
void gfinal(const unsigned short* __restrict__ hh, const unsigned short* __restrict__ dwh,
            const unsigned short* __restrict__ acat, const unsigned short* __restrict__ kcat,
            float* __restrict__ out)
{
    __shared__ __align__(16) unsigned short lds[49152];  // 3 bufs x 16384
    const int tid = threadIdx.x;
    const int l   = tid & 63;
    const int w   = tid >> 6;
    const int wr  = w >> 2, wc = w & 3;

    int nb  = gridDim.x * gridDim.y;                      // 256
    int id  = blockIdx.y * gridDim.x + blockIdx.x;
    int id2 = (id & 7) * (nb >> 3) + (id >> 3);
    int bx  = id2 % gridDim.x, by = id2 / gridDim.x;
    const int bm0 = by * 128, bn0 = bx * 128;

    const int srow = tid >> 3;
    const int sq   = (tid & 7) ^ (srow & 7);
    const int rowa = (wr * 64 + (l & 15)) * 64;
    const int rowb = (wc * 32 + (l & 15)) * 64;
    const int q0 = (((l >> 4)    ) ^ (l & 7)) << 3;
    const int q1 = (((l >> 4) + 4) ^ (l & 7)) << 3;

    f32x4 acc[4][2];
#pragma unroll
    for (int i = 0; i < 4; i++)
#pragma unroll
        for (int j = 0; j < 2; j++) acc[i][j] = (f32x4){0.f, 0.f, 0.f, 0.f};

    // ---- main: K=2048, 3-deep ----
    {
        const size_t aoff = (size_t)(bm0 + srow) * Hq + sq * 8;
        const size_t boff = (size_t)(bn0 + srow) * Hq + sq * 8;
        const size_t r64  = (size_t)64 * Hq;
        auto stage = [&](int b, int kt) {
            unsigned short* d = &lds[b * 16384 + (w << 9)];
            gl16(hh  + aoff + kt,       d + 0);
            gl16(hh  + aoff + kt + r64, d + 4096);
            gl16(dwh + boff + kt,       d + 8192);
            gl16(dwh + boff + kt + r64, d + 12288);
        };
        stage(0, 0);
        stage(1, 64);
        int cur = 0;
        for (int kt = 0; kt < Hq; kt += 64) {
            if (kt + 64 < Hq) { WAITV_BAR(4); } else { WAITV_BAR(0); }
            if (kt + 128 < Hq) {
                int nb3 = (cur + 2 >= 3) ? cur - 1 : cur + 2;
                stage(nb3, kt + 128);
            }
            const int cb = cur * 16384;
#pragma unroll
            for (int ks = 0; ks < 2; ks++) {
                const int qo = ks ? q1 : q0;
                bfrag a4[4], b4[2];
#pragma unroll
                for (int f = 0; f < 4; f++)
                    a4[f] = *(const bfrag*)&lds[cb + rowa + f * 1024 + qo];
#pragma unroll
                for (int f = 0; f < 2; f++)
                    b4[f] = *(const bfrag*)&lds[cb + 8192 + rowb + f * 1024 + qo];
#pragma unroll
                for (int i = 0; i < 4; i++)
#pragma unroll
                    for (int j = 0; j < 2; j++)
                        acc[i][j] = __builtin_amdgcn_mfma_f32_16x16x32_bf16(a4[i], b4[j], acc[i][j], 0, 0, 0);
            }
            cur = (cur == 2) ? 0 : cur + 1;
        }
    }
    END_BAR();
    // ---- tail: K=256 over [acat | kcat], 3-deep (4 iters) ----
    {
        const size_t aoff = (size_t)(bm0 + srow) * 256 + sq * 8;
        const size_t boff = (size_t)(bn0 + srow) * 256 + sq * 8;
        const size_t r64  = (size_t)64 * 256;
        auto stage2 = [&](int b, int kt) {
            unsigned short* d = &lds[b * 16384 + (w << 9)];
            gl16(acat + aoff + kt,       d + 0);
            gl16(acat + aoff + kt + r64, d + 4096);
            gl16(kcat + boff + kt,       d + 8192);
            gl16(kcat + boff + kt + r64, d + 12288);
        };
        stage2(0, 0);
        stage2(1, 64);
        int cur = 0;
        for (int kt = 0; kt < 256; kt += 64) {
            if (kt + 64 < 256) { WAITV_BAR(4); } else { WAITV_BAR(0); }
            if (kt + 128 < 256) {
                int nb3 = (cur + 2 >= 3) ? cur - 1 : cur + 2;
                stage2(nb3, kt + 128);
            }
            const int cb = cur * 16384;
#pragma unroll
            for (int ks = 0; ks < 2; ks++) {
                const int qo = ks ? q1 : q0;
                bfrag a4[4], b4[2];
#pragma unroll
                for (int f = 0; f < 4; f++)
                    a4[f] = *(const bfrag*)&lds[cb + rowa + f * 1024 + qo];
#pragma unroll
                for (int f = 0; f < 2; f++)
                    b4[f] = *(const bfrag*)&lds[cb + 8192 + rowb + f * 1024 + qo];
#pragma unroll
                for (int i = 0; i < 4; i++)
#pragma unroll
                    for (int j = 0; j < 2; j++)
                        acc[i][j] = __builtin_amdgcn_mfma_f32_16x16x32_bf16(a4[i], b4[j], acc[i][j], 0, 0, 0);
            }
            cur = (cur == 2) ? 0 : cur + 1;
        }
    }

    const int crow0 = bm0 + wr * 64 + (l >> 4) * 4;
    const int ccol0 = bn0 + wc * 32 + (l & 15);
#pragma unroll
    for (int i = 0; i < 4; i++)
#pragma unroll
        for (int j = 0; j < 2; j++)
#pragma unroll
            for (int r = 0; r < 4; r++)
                out[(size_t)(crow0 + i * 16 + r) * Dq + ccol0 + j * 16] = acc[i][j][r];
}

// ---------------------------------------------------------------------------
// Reduce NZ split-K partials + LayerNorm over A=128 -> bf16.
// WT: also scatter the bf16 result transposed into aT[b][a][s] (replaces
// the separate transb dispatch; values bit-identical).
// ---------------------------------------------------------------------------
template<int NZ, bool WT>
__global__ __launch_bounds__(256)
void rln(const float* __restrict__ p, unsigned short* __restrict__ oh,
         unsigned short* __restrict__ aT,
         const float* __restrict__ g, const float* __restrict__ b, long pstride)
{
    int row  = blockIdx.x * 4 + (threadIdx.x >> 6);
    int lane = threadIdx.x & 63;
    long base = (long)row * Aq;
    float x0 = 0.f, x1 = 0.f;
#pragma unroll
    for (int z = 0; z < NZ; z++) {
        x0 += p[base + z * pstride + lane];
        x1 += p[base + z * pstride + lane + 64];
    }
    float s  = x0 + x1;
    float ss = x0 * x0 + x1 * x1;
#pragma unroll
    for (int off = 32; off > 0; off >>= 1) {
        s  += __shfl_xor(s, off);
        ss += __shfl_xor(ss, off);
    }
    float m  = s * (1.0f / Aq);
    float v  = ss * (1.0f / Aq) - m * m;
    float rs = rsqrtf(v + 1e-5f);
    unsigned short h0 = f2bf((x0 - m) * rs * g[lane]      + b[lane]);
    unsigned short h1 = f2bf((x1 - m) * rs * g[lane + 64] + b[lane + 64]);
    oh[base + lane]      = h0;
    oh[base + lane + 64] = h1;
    if (WT) {
        int bb2 = row >> 11, sidx = row & 2047;
        unsigned short* t = aT + (size_t)bb2 * Sq * Aq + sidx;
        t[(size_t)lane * Sq]        = h0;
        t[(size_t)(lane + 64) * Sq] = h1;
    }
}

// Reduce NZ split-K partials [bz][NZ][rowsPerB][A] -> scaled bf16 (kcat).
template<int NZ>
__global__ __launch_bounds__(256)
void rbf(const float* __restrict__ p, unsigned short* __restrict__ o,
         int rowsPerB, float scale, int total, int ostride, int ocol, int ocolStep)
{
    int i = blockIdx.x * 256 + threadIdx.x;
    if (i >= total) return;
    int n = i >> 7, a = i & 127;
    int bz = n / rowsPerB, s = n - bz * rowsPerB;
    long base = ((long)bz * NZ) * rowsPerB * Aq + (long)s * Aq + a;
    float acc = 0.f;
#pragma unroll
    for (int z = 0; z < NZ; z++) acc += p[base + (long)z * rowsPerB * Aq];
    o[(long)s * ostride + (ocol + bz * ocolStep) + a +
      (ocolStep ? 0 : (long)bz * rowsPerB * ostride)] = f2bf(acc * scale);
}

// ---------------------------------------------------------------------------
// Merged tail: blocks 0..2047 = rbf<8>(p3 -> acat cols 0..127, scale 0.1);
// blocks 2048..3071 = mix_ln(he bf16 -> acat cols 128..255).
// ---------------------------------------------------------------------------
__global__ __launch_bounds__(256)
void tailk(const float* __restrict__ p3, const unsigned short* __restrict__ he,
           const float* __restrict__ ew, const float* __restrict__ g,
           const float* __restrict__ bb, unsigned short* __restrict__ acat)
{
    if (blockIdx.x < 2048) {
        int i = blockIdx.x * 256 + threadIdx.x;       // < 524288
        int n = i >> 7, a = i & 127;
        int bz = n >> 11, s = n & 2047;
        long base = ((long)bz * 8) * Sq * Aq + (long)s * Aq + a;
        float acc = 0.f;
#pragma unroll
        for (int z = 0; z < 8; z++) acc += p3[base + (long)z * Sq * Aq];
        acat[(long)n * 256 + a] = f2bf(acc * 0.1f);
        return;
    }
    int n    = (blockIdx.x - 2048) * 4 + (threadIdx.x >> 6);
    int lane = threadIdx.x & 63;
    float a0 = 0.0f, a1 = 0.0f;
#pragma unroll
    for (int e = 0; e < Eq; e++) {
        const unsigned short* r = he + ((long)e * Nq + n) * Aq;
        float x0 = bf2f(r[lane]), x1 = bf2f(r[lane + 64]);
        float s  = x0 + x1;
        float ss = x0 * x0 + x1 * x1;
#pragma unroll
        for (int off = 32; off > 0; off >>= 1) {
            s  += __shfl_xor(s, off);
            ss += __shfl_xor(ss, off);
        }
        float m  = s * (1.0f / Aq);
        float v  = ss * (1.0f / Aq) - m * m;
        float rs = rsqrtf(v + 1e-5f);
        float wv = ew[(long)n * Eq + e];
        a0 += wv * ((x0 - m) * rs * g[e * Aq + lane]      + bb[e * Aq + lane]);
        a1 += wv * ((x1 - m) * rs * g[e * Aq + lane + 64] + bb[e * Aq + lane + 64]);
    }
    acat[(long)n * 256 + 128 + lane]      = f2bf(a0);
    acat[(long)n * 256 + 128 + lane + 64] = f2bf(a1);
}

extern "C" void kernel_launch(void* const* d_in, const int* in_sizes, int n_in,
                              void* d_out, int out_size, void* d_ws, size_t ws_size,
                              hipStream_t stream)
{
    const float* x             = (const float*)d_in[0];
    const float* ew            = (const float*)d_in[1];
    const float* up_w          = (const float*)d_in[2];
    const float* gate_w        = (const float*)d_in[3];
    const float* down_w        = (const float*)d_in[4];
    const float* pre_w         = (const float*)d_in[5];
    const float* post_w        = (const float*)d_in[6];
    const float* an_g          = (const float*)d_in[7];
    const float* an_b          = (const float*)d_in[8];
    const float* adapt_proj_w  = (const float*)d_in[9];
    const float* adapter_w     = (const float*)d_in[10];
    const float* adapter_g     = (const float*)d_in[11];
    const float* adapter_b     = (const float*)d_in[12];
    const float* expert_proj_w = (const float*)d_in[13];
    const float* output_proj_w = (const float*)d_in[14];
    float* out = (float*)d_out;

    // ---- workspace (KB offsets; peak ~81 MB) ----
#define OFF(kb) ((char*)d_ws + (size_t)(kb) * 1024)
    float* kdp  = (float*)OFF(0);        // [2][16][D][A] 16MB (phase 1)
    float* p1   = (float*)OFF(16384);    // [8][N][A] 16MB   (phase 1)
    float* p2   = (float*)OFF(0);        // [8][N][A] 16MB   (phase 3)
    float* p3   = (float*)OFF(0);        // [2][8][S][A] 16MB (phase 4, after p2 dead)
    unsigned short* he = (unsigned short*)OFF(16384);    // [E][N][A] bf16 8MB (after p1 dead)
    unsigned short* hh   = (unsigned short*)OFF(32768);  // [N,H] 16MB
    unsigned short* xh   = (unsigned short*)OFF(49152);  // 8MB
    unsigned short* gwh  = (unsigned short*)OFF(57344);  // 4MB
    unsigned short* uwh  = (unsigned short*)OFF(61440);  // 4MB
    unsigned short* dwh  = (unsigned short*)OFF(65536);  // 4MB   } contiguous pair
    unsigned short* oph  = (unsigned short*)OFF(69632);  // 4MB   } for batched kcat
    unsigned short* pwh  = (unsigned short*)OFF(73728);  // .25MB
    unsigned short* powh = (unsigned short*)OFF(73984);  // .5MB
    unsigned short* apT  = (unsigned short*)OFF(74496);  // .5MB  } contiguous pair
    unsigned short* epT  = (unsigned short*)OFF(75008);  // .5MB  }
    unsigned short* ainh = (unsigned short*)OFF(75520);  // 1MB
    unsigned short* ainT = (unsigned short*)OFF(76544);  // [B][A][S] 1MB
    unsigned short* aouth= (unsigned short*)OFF(77568);  // 1MB
    unsigned short* adw  = (unsigned short*)OFF(78592);  // .25MB
    unsigned short* kcat = (unsigned short*)OFF(78848);  // [D][256] .5MB
    unsigned short* acat = (unsigned short*)OFF(79360);  // [N][256] 2MB -> 81408
#undef OFF
    (void)epT;

    dim3 blk(256), blk512(512);
    const long NA = (long)Nq * Aq;

    // 1. conversions + BOTH fp32 transposes in one launch (2048 + 512 blocks)
    convert_all<<<dim3(2560), blk, 0, stream>>>(x, gate_w, up_w, down_w, pre_w,
        post_w, output_proj_w, adapter_w, adapt_proj_w, expert_proj_w,
        xh, gwh, uwh, dwh, pwh, powh, oph, adw, apT);

    // 2. weight fusions (batched bz=2): bz0 = dwh@apT, bz1 = oph@epT
    mg<0><<<dim3(1, 8, 32), blk512, 0, stream>>>(dwh, apT, kdp, Aq, Hq, 16,
        (long)Dq * Hq, (long)Aq * Hq, (long)16 * Dq * Aq, (long)Dq * Aq);
    rbf<16><<<dim3(1024), blk, 0, stream>>>(kdp, kcat, Dq, 1.0f, 2 * Dq * Aq, 256, 0, 128);

    // 3. ain = LN(x @ pre_w^T)  (split-K 8); rln also writes ainT (transposed)
    mg<0><<<dim3(1, 32, 8), blk512, 0, stream>>>(xh, pwh, p1, Aq, Dq, 8, 0, 0, 0, NA);
    rln<8, true><<<dim3(1024), blk, 0, stream>>>(p1, ainh, ainT, an_g, an_b, NA);

    // 4. expert path GEMM: he = bf16(ain @ adapter_w[e]^T)   (p1 dead -> he @16384)
    mg<2><<<dim3(1, 32, 8), blk512, 0, stream>>>(ainh, adw, he, Aq, Aq, 1,
        0, (long)Aq * Aq, NA, 0);

    // 5. fused SwiGLU: hh = bf16(silu(x@gw^T) * (x@uw^T))
    gup<<<dim3(16, 32), blk512, 0, stream>>>(xh, gwh, uwh, hh);

    // 6. aout = LN(hidden @ post_w^T)  (split-K 8)
    mg<0><<<dim3(1, 32, 8), blk512, 0, stream>>>(hh, powh, p2, Aq, Hq, 8, 0, 0, 0, NA);
    rln<8, false><<<dim3(1024), blk, 0, stream>>>(p2, aouth, nullptr, an_g, an_b, NA);

    // 7. FUSED score-combine: p3 partials (no wmat)
    gsc<<<dim3(8, 16, 2), blk512, 0, stream>>>(ainh, aouth, ainT, p3);

    // 8. merged tail: acat[:,0:128] = 0.1*reduce(p3); acat[:,128:256] = mix_ln(he)
    tailk<<<dim3(3072), blk, 0, stream>>>(p3, he, ew, adapter_g, adapter_b, acat);

    // 9. out = hh@dwh^T + acat@kcat^T
    gfinal<<<dim3(8, 32), blk512, 0, stream>>>(hh, dwh, acat, kcat, out);
}

// Round 20
// 159.752 us; speedup vs baseline: 1.0375x; 1.0204x over previous
//
#include <hip/hip_runtime.h>
#include <hip/hip_bf16.h>
#include <math.h>

// Problem constants (B,S,D,E = 2,2048,1024,8)
#define Bq 2
#define Sq 2048
#define Dq 1024
#define Eq 8
#define Hq 2048            // 2*D
#define Aq 128             // H/16
#define Nq (Bq*Sq)         // 4096 tokens

typedef __attribute__((ext_vector_type(4))) float f32x4;
typedef __attribute__((ext_vector_type(8))) short bfrag;   // 8 bf16 in 4 VGPRs

__device__ __forceinline__ float silu_f(float x) {
    return x / (1.0f + expf(-x));
}
__device__ __forceinline__ unsigned short f2bf(float x) {  // RNE fp32->bf16
    unsigned u = __float_as_uint(x);
    u += 0x7fffu + ((u >> 16) & 1u);
    return (unsigned short)(u >> 16);
}
__device__ __forceinline__ float bf2f(unsigned short h) {
    return __uint_as_float(((unsigned)h) << 16);
}
__device__ __forceinline__ void gl16(const unsigned short* g, unsigned short* l) {
    __builtin_amdgcn_global_load_lds(
        (const __attribute__((address_space(1))) void*)g,
        (__attribute__((address_space(3))) void*)(void*)l, 16, 0, 0);
}

// Counted-vmcnt wait-then-barrier (T4). vmcnt retires IN ORDER.
#define WAITV_BAR(N)                                            \
    asm volatile("s_waitcnt vmcnt(" #N ")" ::: "memory");       \
    __builtin_amdgcn_s_barrier();                               \
    asm volatile("" ::: "memory")
#define END_BAR()                                               \
    asm volatile("" ::: "memory");                              \
    __builtin_amdgcn_s_barrier();                               \
    asm volatile("" ::: "memory")
#define WAITV(N) asm volatile("s_waitcnt vmcnt(" #N ")" ::: "memory")
#define BARF()                                                  \
    asm volatile("" ::: "memory");                              \
    __builtin_amdgcn_s_barrier();                               \
    asm volatile("" ::: "memory")

// ---------------------------------------------------------------------------
// convert_all: fp32 -> bf16 for all inputs (blocks 0..2047, grid-stride)
// PLUS the two fp32 transposes (blocks 2048..2559).
// ---------------------------------------------------------------------------
__global__ __launch_bounds__(256)
void convert_all(const float* __restrict__ x,  const float* __restrict__ gw,
                 const float* __restrict__ uw, const float* __restrict__ dw,
                 const float* __restrict__ pw, const float* __restrict__ ow,
                 const float* __restrict__ opw, const float* __restrict__ aw,
                 const float* __restrict__ apw, const float* __restrict__ epw,
                 unsigned short* xh,  unsigned short* gwh, unsigned short* uwh,
                 unsigned short* dwh, unsigned short* pwh, unsigned short* powh,
                 unsigned short* oph, unsigned short* adw, unsigned short* apT)
{
    __shared__ float t[32][33];
    if (blockIdx.x >= 2048) {
        int bid = blockIdx.x - 2048;
        int z   = bid >> 8;
        int rem = bid & 255;
        int bx  = rem & 3, by = rem >> 2;
        const float* in = z ? epw : apw;
        unsigned short* out = apT + (size_t)z * Hq * Aq;
        int tx = threadIdx.x & 31, ty = threadIdx.x >> 5;
        int r0 = by * 32, c0 = bx * 32;
#pragma unroll
        for (int j = 0; j < 4; j++)
            t[ty + j * 8][tx] = in[(size_t)(r0 + ty + j * 8) * Aq + c0 + tx];
        __syncthreads();
#pragma unroll
        for (int j = 0; j < 4; j++)
            out[(size_t)(c0 + ty + j * 8) * Hq + r0 + tx] = f2bf(t[tx][ty + j * 8]);
        return;
    }
    const int T = 3276800;
    for (int i = blockIdx.x * 256 + threadIdx.x; i < T; i += 2048 * 256) {
        const float* in; unsigned short* hi; int j = i;
        if (j < 1048576)                 { in = x;   hi = xh;  }
        else if ((j -= 1048576) < 524288){ in = gw;  hi = gwh; }
        else if ((j -= 524288) < 524288) { in = uw;  hi = uwh; }
        else if ((j -= 524288) < 524288) { in = dw;  hi = dwh; }
        else if ((j -= 524288) < 32768)  { in = pw;  hi = pwh; }
        else if ((j -= 32768) < 65536)   { in = ow;  hi = powh; }
        else if ((j -= 65536) < 524288)  { in = opw; hi = oph; }
        else { j -= 524288;                in = aw;  hi = adw; }
        float4 v = ((const float4*)in)[j];
        ((ushort4*)hi)[j] = make_ushort4(f2bf(v.x), f2bf(v.y), f2bf(v.z), f2bf(v.w));
    }
}

// ---------------------------------------------------------------------------
// 1-term bf16 MFMA GEMM, BK=64, 8 waves (2Mx4N, wave tile 64x32), 2-buf +
// counted-vmcnt. 64 KB LDS. (Proven.)
// EPI: 0 = fp32 store (+bz*zC+kz*pz); 1 = bf16 silu-clip; 2 = bf16 plain.
// ---------------------------------------------------------------------------
template<int EPI>
__global__ __launch_bounds__(512)
void mg(const unsigned short* __restrict__ Ah, const unsigned short* __restrict__ Bh,
        void* __restrict__ Cv, int N, int K, int kchunks,
        long zA, long zB, long zC, long pz)
{
    __shared__ __align__(16) unsigned short lds[32768];  // 2 bufs x (A 8192 | B 8192)

    const int tid = threadIdx.x;
    const int l   = tid & 63;
    const int w   = tid >> 6;                  // 0..7
    const int wr  = w >> 2, wc = w & 3;
    const int bm0 = blockIdx.y * 128, bn0 = blockIdx.x * 128;
    const int bz  = blockIdx.z / kchunks;
    const int kz  = blockIdx.z - bz * kchunks;
    const int kcnt = K / kchunks;
    const int kbeg = kz * kcnt;
    const int kend = kbeg + kcnt;

    const unsigned short* A0 = Ah + (size_t)bz * zA;
    const unsigned short* B0 = Bh + (size_t)bz * zB;

    const int srow = tid >> 3;                 // 0..63 (+64 round 1)
    const int sq   = (tid & 7) ^ (srow & 7);
    const size_t aoff = (size_t)(bm0 + srow) * K + sq * 8;
    const size_t boff = (size_t)(bn0 + srow) * K + sq * 8;
    const size_t r64  = (size_t)64 * K;

    auto stage = [&](int b, int kt) {          // 4 gl16
        unsigned short* d = &lds[b * 16384 + (w << 9)];
        gl16(A0 + aoff + kt,       d + 0);
        gl16(A0 + aoff + kt + r64, d + 4096);
        gl16(B0 + boff + kt,       d + 8192);
        gl16(B0 + boff + kt + r64, d + 12288);
    };

    const int rowa = (wr * 64 + (l & 15)) * 64;
    const int rowb = (wc * 32 + (l & 15)) * 64;
    const int q0 = (((l >> 4)    ) ^ (l & 7)) << 3;
    const int q1 = (((l >> 4) + 4) ^ (l & 7)) << 3;

    f32x4 acc[4][2];
#pragma unroll
    for (int i = 0; i < 4; i++)
#pragma unroll
        for (int j = 0; j < 2; j++) acc[i][j] = (f32x4){0.f, 0.f, 0.f, 0.f};

    stage(0, kbeg);
    int cur = 0;
    for (int kt = kbeg; kt < kend; kt += 64) {
        if (kt + 64 < kend) {
            stage(cur ^ 1, kt + 64);
            WAITV_BAR(4);
        } else {
            WAITV_BAR(0);
        }
        const int cb = cur * 16384;
#pragma unroll
        for (int ks = 0; ks < 2; ks++) {
            const int qo = ks ? q1 : q0;
            bfrag a4[4], b4[2];
#pragma unroll
            for (int f = 0; f < 4; f++)
                a4[f] = *(const bfrag*)&lds[cb + rowa + f * 1024 + qo];
#pragma unroll
            for (int f = 0; f < 2; f++)
                b4[f] = *(const bfrag*)&lds[cb + 8192 + rowb + f * 1024 + qo];
#pragma unroll
            for (int i = 0; i < 4; i++)
#pragma unroll
                for (int j = 0; j < 2; j++)
                    acc[i][j] = __builtin_amdgcn_mfma_f32_16x16x32_bf16(a4[i], b4[j], acc[i][j], 0, 0, 0);
        }
        END_BAR();
        cur ^= 1;
    }

    const int crow0 = bm0 + wr * 64 + (l >> 4) * 4;
    const int ccol0 = bn0 + wc * 32 + (l & 15);
#pragma unroll
    for (int i = 0; i < 4; i++)
#pragma unroll
        for (int j = 0; j < 2; j++)
#pragma unroll
            for (int r = 0; r < 4; r++) {
                size_t idx = (size_t)(crow0 + i * 16 + r) * N + (ccol0 + j * 16);
                float v = acc[i][j][r];
                if (EPI == 0)
                    ((float*)Cv + (size_t)bz * zC + (size_t)kz * pz)[idx] = v;
                else if (EPI == 1)
                    ((unsigned short*)Cv + (size_t)bz * zC)[idx] =
                        f2bf(silu_f(fminf(fmaxf(v, -5.f), 5.f)));
                else
                    ((unsigned short*)Cv + (size_t)bz * zC)[idx] = f2bf(v);
            }
}

// ---------------------------------------------------------------------------
// Fused score-combine (steps 6+7, no wmat). (Proven r17.)
// ---------------------------------------------------------------------------
__global__ __launch_bounds__(512)
void gsc(const unsigned short* __restrict__ ainh, const unsigned short* __restrict__ aouth,
         const unsigned short* __restrict__ ainT, float* __restrict__ p3)
{
    __shared__ __align__(16) unsigned short lds[65536];  // 128 KB
    const int AIN = 0, AOUT = 16384, AINT = 32768, PB = 49152;

    const int tid = threadIdx.x;
    const int l   = tid & 63;
    const int w   = tid >> 6;
    const int wr  = w >> 2, wc = w & 3;
    const int tz  = blockIdx.x;        // 0..7
    const int ib  = blockIdx.y;        // 0..15
    const int b   = blockIdx.z;        // 0..1
    const long SA = (long)Sq * Aq;

    auto stage32 = [&](int base, const unsigned short* src, size_t kstride) {
#pragma unroll
        for (int rd = 0; rd < 4; rd++) {
            int grow = rd * 32 + (w << 2) + (l >> 4);
            int slot = (l & 15) ^ (grow & 15);
            gl16(src + (size_t)grow * kstride + slot * 8,
                 &lds[base + rd * 4096 + (w << 9)]);
        }
    };

    const unsigned short* ainI_src = ainh + (size_t)b * SA + (size_t)(ib * 128) * Aq;
    f32x4 acc2[4][2];
#pragma unroll
    for (int i = 0; i < 4; i++)
#pragma unroll
        for (int j = 0; j < 2; j++) acc2[i][j] = (f32x4){0.f, 0.f, 0.f, 0.f};

    {
        int tglob = tz * 2;
        stage32(AIN,  ainI_src, Aq);
        stage32(AOUT, aouth + (size_t)b * SA + (size_t)(tglob * 128) * Aq, Aq);
        stage32(AINT, ainT  + (size_t)b * SA + (size_t)(tglob * 128), Sq);
        WAITV_BAR(0);
    }

    const int rowa = (wr * 64 + (l & 15)) * 128;
    const int rowb = (wc * 32 + (l & 15)) * 128;

#pragma unroll 1
    for (int t = 0; t < 2; t++) {
        if (t == 1) {
            int tglob = tz * 2 + 1;
            stage32(AOUT, aouth + (size_t)b * SA + (size_t)(tglob * 128) * Aq, Aq);
            stage32(AINT, ainT  + (size_t)b * SA + (size_t)(tglob * 128), Sq);
            WAITV_BAR(0);
        }
        f32x4 acc1[4][2];
#pragma unroll
        for (int i = 0; i < 4; i++)
#pragma unroll
            for (int j = 0; j < 2; j++) acc1[i][j] = (f32x4){0.f, 0.f, 0.f, 0.f};
#pragma unroll
        for (int ks = 0; ks < 4; ks++) {
            const int qo = ((ks * 4 + (l >> 4)) ^ (l & 15)) << 3;
            bfrag a4[4], b4[2];
#pragma unroll
            for (int f = 0; f < 4; f++)
                a4[f] = *(const bfrag*)&lds[AIN + rowa + f * 2048 + qo];
#pragma unroll
            for (int f = 0; f < 2; f++)
                b4[f] = *(const bfrag*)&lds[AOUT + rowb + f * 2048 + qo];
#pragma unroll
            for (int i = 0; i < 4; i++)
#pragma unroll
                for (int j = 0; j < 2; j++)
                    acc1[i][j] = __builtin_amdgcn_mfma_f32_16x16x32_bf16(a4[i], b4[j], acc1[i][j], 0, 0, 0);
        }
        {
            const int prow0 = wr * 64 + (l >> 4) * 4;
            const int pcol0 = wc * 32 + (l & 15);
#pragma unroll
            for (int i = 0; i < 4; i++)
#pragma unroll
                for (int j = 0; j < 2; j++)
#pragma unroll
                    for (int r = 0; r < 4; r++) {
                        int pr = prow0 + i * 16 + r;
                        int pc = pcol0 + j * 16;
                        float v = silu_f(fminf(fmaxf(acc1[i][j][r], -5.f), 5.f));
                        lds[PB + pr * 128 + (((pc >> 3) ^ (pr & 15)) << 3) + (pc & 7)] = f2bf(v);
                    }
        }
        __syncthreads();
#pragma unroll
        for (int ks = 0; ks < 4; ks++) {
            const int qo = ((ks * 4 + (l >> 4)) ^ (l & 15)) << 3;
            bfrag a4[4], b4[2];
#pragma unroll
            for (int f = 0; f < 4; f++)
                a4[f] = *(const bfrag*)&lds[PB + rowa + f * 2048 + qo];
#pragma unroll
            for (int f = 0; f < 2; f++)
                b4[f] = *(const bfrag*)&lds[AINT + rowb + f * 2048 + qo];
#pragma unroll
            for (int i = 0; i < 4; i++)
#pragma unroll
                for (int j = 0; j < 2; j++)
                    acc2[i][j] = __builtin_amdgcn_mfma_f32_16x16x32_bf16(a4[i], b4[j], acc2[i][j], 0, 0, 0);
        }
        __syncthreads();
    }

    const int crow0 = wr * 64 + (l >> 4) * 4;
    const int ccol0 = wc * 32 + (l & 15);
    float* dst = p3 + ((size_t)(b * 8 + tz) * Sq + ib * 128) * Aq;
#pragma unroll
    for (int i = 0; i < 4; i++)
#pragma unroll
        for (int j = 0; j < 2; j++)
#pragma unroll
            for (int r = 0; r < 4; r++)
                dst[(size_t)(crow0 + i * 16 + r) * Aq + ccol0 + j * 16] = acc2[i][j][r];
}

// ---------------------------------------------------------------------------
// Fused gate+up GEMM — 8-PHASE schedule, RACE-FIXED (r19 post-mortem):
// the ds-reads now come AFTER the rendezvous barrier (wave-local vmcnt only
// covers own loads; cross-wave residency needs waitcnt-then-barrier), and
// the stage is issued post-barrier (WAR-safe: all waves' prior-tile reads
// were lgkm-drained by their MFMAs before reaching this barrier).
// Phase = {WAITV(N); BARF; ds-read subtile; stage next unit; setprio(1);
//          16 MFMA; setprio(0)}.  4 barriers/K-tile; vmcnt never 0 mid-loop.
// Accounting (2 loads/unit, in-order retire, steady 8 outstanding):
//   ph0 WAITV(2) -> cur x0,x1,gw resident; ph1 WAITV(2) (last tile: 0) ->
//   cur uw resident; ph2/ph3 no waits (resident since ph0).
// tile 256x128, BK=64, 8 waves 2Mx4N (wave tile 128x32, 16 MFMA/phase),
// LDS 2 x 64 KB. 2D XCD chunk.
//   hh[n,h] = bf16( silu(x@gw^T) * (x@uw^T) )      K=1024, 16 K-tiles.
// ---------------------------------------------------------------------------
__global__ __launch_bounds__(512)
void gup(const unsigned short* __restrict__ xh, const unsigned short* __restrict__ gwh,
         const unsigned short* __restrict__ uwh, unsigned short* __restrict__ hh)
{
    __shared__ __align__(16) unsigned short lds[65536];  // 2 bufs x 32768 ushorts
    const int tid = threadIdx.x;
    const int l   = tid & 63;
    const int w   = tid >> 6;
    const int wr  = w >> 2;          // 0..1 : 128-row half of the 256-row tile
    const int wc  = w & 3;           // 0..3 : 32-col quarter of the 128-col tile

    int id  = blockIdx.y * gridDim.x + blockIdx.x;     // grid (16,16)
    int xcd = id & 7, j0 = id >> 3;
    int bx  = (xcd & 3) * 4 + (j0 & 3);                // 0..15
    int by  = (xcd >> 2) * 8 + (j0 >> 2);              // 0..15
    const int bm0 = by * 256, bn0 = bx * 128;

    // staging: unit = 16 KB (128 rows x 64 cols bf16) = 2 gl16/thread.
    // units: 0 = x rows 0-127, 1 = x rows 128-255, 2 = gw, 3 = uw.
    const int srw = tid >> 3;                          // 0..63 (+64 round 1)
    const int sq  = (tid & 7) ^ (srw & 7);
    auto stageU = [&](int b, int u, int kt) {
        unsigned short* d = &lds[b * 32768 + u * 8192 + (tid << 3)];
        const unsigned short* src = (u < 2) ? xh : (u == 2 ? gwh : uwh);
        int baserow = (u < 2) ? (bm0 + u * 128) : bn0;
        size_t o = (size_t)(baserow + srw) * Dq + kt + sq * 8;
        gl16(src + o,                   d);
        gl16(src + o + (size_t)64 * Dq, d + 4096);
    };

    const int rowa = (wr * 128 + (l & 15)) * 64;       // + i*1024, i=0..7
    const int rowb = (wc * 32  + (l & 15)) * 64;       // + j*1024, j=0..1
    const int q0 = (((l >> 4)    ) ^ (l & 7)) << 3;
    const int q1 = (((l >> 4) + 4) ^ (l & 7)) << 3;

    f32x4 accg[8][2], accu[8][2];
#pragma unroll
    for (int i = 0; i < 8; i++)
#pragma unroll
        for (int jj = 0; jj < 2; jj++) {
            accg[i][jj] = (f32x4){0.f, 0.f, 0.f, 0.f};
            accu[i][jj] = (f32x4){0.f, 0.f, 0.f, 0.f};
        }

    // prologue: all 4 units of tile 0 (issue order u0,u1,u2,u3)
    stageU(0, 0, 0); stageU(0, 1, 0); stageU(0, 2, 0); stageU(0, 3, 0);
    int cur = 0;
    for (int kt = 0; kt < Dq; kt += 64) {
        const int pf = (kt + 64 < Dq);
        const int cb = cur * 32768;
        const int nx = cur ^ 1;
        bfrag a4[8], b4[2];

        // ---- phase 0: ks0 gate ----
        WAITV(2);                // retires cur u0,u1,u2 (own); barrier makes global
        BARF();
#pragma unroll
        for (int f = 0; f < 8; f++)
            a4[f] = *(const bfrag*)&lds[cb + rowa + f * 1024 + q0];
#pragma unroll
        for (int f = 0; f < 2; f++)
            b4[f] = *(const bfrag*)&lds[cb + 16384 + rowb + f * 1024 + q0];
        if (pf) stageU(nx, 0, kt + 64);
        __builtin_amdgcn_s_setprio(1);
#pragma unroll
        for (int i = 0; i < 8; i++)
#pragma unroll
            for (int jj = 0; jj < 2; jj++)
                accg[i][jj] = __builtin_amdgcn_mfma_f32_16x16x32_bf16(a4[i], b4[jj], accg[i][jj], 0, 0, 0);
        __builtin_amdgcn_s_setprio(0);

        // ---- phase 1: ks0 up (reuses a4) ----
        if (pf) { WAITV(2); } else { WAITV(0); }   // retires cur u3
        BARF();
#pragma unroll
        for (int f = 0; f < 2; f++)
            b4[f] = *(const bfrag*)&lds[cb + 24576 + rowb + f * 1024 + q0];
        if (pf) stageU(nx, 1, kt + 64);
        __builtin_amdgcn_s_setprio(1);
#pragma unroll
        for (int i = 0; i < 8; i++)
#pragma unroll
            for (int jj = 0; jj < 2; jj++)
                accu[i][jj] = __builtin_amdgcn_mfma_f32_16x16x32_bf16(a4[i], b4[jj], accu[i][jj], 0, 0, 0);
        __builtin_amdgcn_s_setprio(0);

        // ---- phase 2: ks1 gate (cur fully resident since ph0/ph1) ----
        BARF();
#pragma unroll
        for (int f = 0; f < 8; f++)
            a4[f] = *(const bfrag*)&lds[cb + rowa + f * 1024 + q1];
#pragma unroll
        for (int f = 0; f < 2; f++)
            b4[f] = *(const bfrag*)&lds[cb + 16384 + rowb + f * 1024 + q1];
        if (pf) stageU(nx, 2, kt + 64);
        __builtin_amdgcn_s_setprio(1);
#pragma unroll
        for (int i = 0; i < 8; i++)
#pragma unroll
            for (int jj = 0; jj < 2; jj++)
                accg[i][jj] = __builtin_amdgcn_mfma_f32_16x16x32_bf16(a4[i], b4[jj], accg[i][jj], 0, 0, 0);
        __builtin_amdgcn_s_setprio(0);

        // ---- phase 3: ks1 up ----
        BARF();
#pragma unroll
        for (int f = 0; f < 2; f++)
            b4[f] = *(const bfrag*)&lds[cb + 24576 + rowb + f * 1024 + q1];
        if (pf) stageU(nx, 3, kt + 64);
        __builtin_amdgcn_s_setprio(1);
#pragma unroll
        for (int i = 0; i < 8; i++)
#pragma unroll
            for (int jj = 0; jj < 2; jj++)
                accu[i][jj] = __builtin_amdgcn_mfma_f32_16x16x32_bf16(a4[i], b4[jj], accu[i][jj], 0, 0, 0);
        __builtin_amdgcn_s_setprio(0);

        cur = nx;
    }

    const int crow0 = bm0 + wr * 128 + (l >> 4) * 4;
    const int ccol0 = bn0 + wc * 32 + (l & 15);
#pragma unroll
    for (int i = 0; i < 8; i++)
#pragma unroll
        for (int jj = 0; jj < 2; jj++)
#pragma unroll
            for (int r = 0; r < 4; r++) {
                size_t idx = (size_t)(crow0 + i * 16 + r) * Hq + (ccol0 + jj * 16);
                hh[idx] = f2bf(silu_f(accg[i][jj][r]) * accu[i][jj][r]);
            }
}

// ---------------------------------------------------------------------------
// Final fused GEMM, BK=64, 8 waves (2Mx4N), 3-deep ring (96 KB LDS):
//   out[4096][1024] = hh@dwh^T (K=2048) + acat@kcat^T (K=256)
// ---------------------------------------------------------------------------
__global__ __launch_bounds__(512)
void gfinal(const unsigned short* __restrict__ hh, const unsigned short* __restrict__ dwh,
            const unsigned short* __restrict__ acat, const unsigned short* __restrict__ kcat,
            float* __restrict__ out)
{
    __shared__ __align__(16) unsigned short lds[49152];  // 3 bufs x 16384
    const int tid = threadIdx.x;
    const int l   = tid & 63;
    const int w   = tid >> 6;
    const int wr  = w >> 2, wc = w & 3;

    int nb  = gridDim.x * gridDim.y;                      // 256
    int id  = blockIdx.y * gridDim.x + blockIdx.x;
    int id2 = (id & 7) * (nb >> 3) + (id >> 3);
    int bx  = id2 % gridDim.x, by = id2 / gridDim.x;
    const int bm0 = by * 128, bn0 = bx * 128;

    const int srow = tid >> 3;
    const int sq   = (tid & 7) ^ (srow & 7);
    const int rowa = (wr * 64 + (l & 15)) * 64;
    const int rowb = (wc * 32 + (l & 15)) * 64;
    const int q0 = (((l >> 4)    ) ^ (l & 7)) << 3;
    const int q1 = (((l >> 4) + 4) ^ (l & 7)) << 3;

    f32x4 acc[4][2];
#pragma unroll
    for (int i = 0; i < 4; i++)
#pragma unroll
        for (int j = 0; j < 2; j++) acc[i][j] = (f32x4){0.f, 0.f, 0.f, 0.f};

    // ---- main: K=2048, 3-deep ----
    {
        const size_t aoff = (size_t)(bm0 + srow) * Hq + sq * 8;
        const size_t boff = (size_t)(bn0 + srow) * Hq + sq * 8;
        const size_t r64  = (size_t)64 * Hq;
        auto stage = [&](int b, int kt) {
            unsigned short* d = &lds[b * 16384 + (w << 9)];
            gl16(hh  + aoff + kt,       d + 0);
            gl16(hh  + aoff + kt + r64, d + 4096);
            gl16(dwh + boff + kt,       d + 8192);
            gl16(dwh + boff + kt + r64, d + 12288);
        };
        stage(0, 0);
        stage(1, 64);
        int cur = 0;
        for (int kt = 0; kt < Hq; kt += 64) {
            if (kt + 64 < Hq) { WAITV_BAR(4); } else { WAITV_BAR(0); }
            if (kt + 128 < Hq) {
                int nb3 = (cur + 2 >= 3) ? cur - 1 : cur + 2;
                stage(nb3, kt + 128);
            }
            const int cb = cur * 16384;
#pragma unroll
            for (int ks = 0; ks < 2; ks++) {
                const int qo = ks ? q1 : q0;
                bfrag a4[4], b4[2];
#pragma unroll
                for (int f = 0; f < 4; f++)
                    a4[f] = *(const bfrag*)&lds[cb + rowa + f * 1024 + qo];
#pragma unroll
                for (int f = 0; f < 2; f++)
                    b4[f] = *(const bfrag*)&lds[cb + 8192 + rowb + f * 1024 + qo];
#pragma unroll
                for (int i = 0; i < 4; i++)
#pragma unroll
                    for (int j = 0; j < 2; j++)
                        acc[i][j] = __builtin_amdgcn_mfma_f32_16x16x32_bf16(a4[i], b4[j], acc[i][j], 0, 0, 0);
            }
            cur = (cur == 2) ? 0 : cur + 1;
        }
    }
    END_BAR();
    // ---- tail: K=256 over [acat | kcat], 3-deep (4 iters) ----
    {
        const size_t aoff = (size_t)(bm0 + srow) * 256 + sq * 8;
        const size_t boff = (size_t)(bn0 + srow) * 256 + sq * 8;
        const size_t r64  = (size_t)64 * 256;
        auto stage2 = [&](int b, int kt) {
            unsigned short* d = &lds[b * 16384 + (w << 9)];
            gl16(acat + aoff + kt,       d + 0);
            gl16(acat + aoff + kt + r64, d + 4096);
            gl16(kcat + boff + kt,       d + 8192);
            gl16(kcat + boff + kt + r64, d + 12288);
        };
        stage2(0, 0);
        stage2(1, 64);
        int cur = 0;
        for (int kt = 0; kt < 256; kt += 64) {
            if (kt + 64 < 256) { WAITV_BAR(4); } else { WAITV_BAR(0); }
            if (kt + 128 < 256) {
                int nb3 = (cur + 2 >= 3) ? cur - 1 : cur + 2;
                stage2(nb3, kt + 128);
            }
            const int cb = cur * 16384;
#pragma unroll
            for (int ks = 0; ks < 2; ks++) {
                const int qo = ks ? q1 : q0;
                bfrag a4[4], b4[2];
#pragma unroll
                for (int f = 0; f < 4; f++)
                    a4[f] = *(const bfrag*)&lds[cb + rowa + f * 1024 + qo];
#pragma unroll
                for (int f = 0; f < 2; f++)
                    b4[f] = *(const bfrag*)&lds[cb + 8192 + rowb + f * 1024 + qo];
#pragma unroll
                for (int i = 0; i < 4; i++)
#pragma unroll
                    for (int j = 0; j < 2; j++)
                        acc[i][j] = __builtin_amdgcn_mfma_f32_16x16x32_bf16(a4[i], b4[j], acc[i][j], 0, 0, 0);
            }
            cur = (cur == 2) ? 0 : cur + 1;
        }
    }

    const int crow0 = bm0 + wr * 64 + (l >> 4) * 4;
    const int ccol0 = bn0 + wc * 32 + (l & 15);
#pragma unroll
    for (int i = 0; i < 4; i++)
#pragma unroll
        for (int j = 0; j < 2; j++)
#pragma unroll
            for (int r = 0; r < 4; r++)
                out[(size_t)(crow0 + i * 16 + r) * Dq + ccol0 + j * 16] = acc[i][j][r];
}

// ---------------------------------------------------------------------------
// Reduce NZ split-K partials + LayerNorm over A=128 -> bf16.
// WT: also scatter transposed into aT[b][a][s].
// ---------------------------------------------------------------------------
template<int NZ, bool WT>
__global__ __launch_bounds__(256)
void rln(const float* __restrict__ p, unsigned short* __restrict__ oh,
         unsigned short* __restrict__ aT,
         const float* __restrict__ g, const float* __restrict__ b, long pstride)
{
    int row  = blockIdx.x * 4 + (threadIdx.x >> 6);
    int lane = threadIdx.x & 63;
    long base = (long)row * Aq;
    float x0 = 0.f, x1 = 0.f;
#pragma unroll
    for (int z = 0; z < NZ; z++) {
        x0 += p[base + z * pstride + lane];
        x1 += p[base + z * pstride + lane + 64];
    }
    float s  = x0 + x1;
    float ss = x0 * x0 + x1 * x1;
#pragma unroll
    for (int off = 32; off > 0; off >>= 1) {
        s  += __shfl_xor(s, off);
        ss += __shfl_xor(ss, off);
    }
    float m  = s * (1.0f / Aq);
    float v  = ss * (1.0f / Aq) - m * m;
    float rs = rsqrtf(v + 1e-5f);
    unsigned short h0 = f2bf((x0 - m) * rs * g[lane]      + b[lane]);
    unsigned short h1 = f2bf((x1 - m) * rs * g[lane + 64] + b[lane + 64]);
    oh[base + lane]      = h0;
    oh[base + lane + 64] = h1;
    if (WT) {
        int bb2 = row >> 11, sidx = row & 2047;
        unsigned short* t = aT + (size_t)bb2 * Sq * Aq + sidx;
        t[(size_t)lane * Sq]        = h0;
        t[(size_t)(lane + 64) * Sq] = h1;
    }
}

// Reduce NZ split-K partials [bz][NZ][rowsPerB][A] -> scaled bf16 (kcat).
template<int NZ>
__global__ __launch_bounds__(256)
void rbf(const float* __restrict__ p, unsigned short* __restrict__ o,
         int rowsPerB, float scale, int total, int ostride, int ocol, int ocolStep)
{
    int i = blockIdx.x * 256 + threadIdx.x;
    if (i >= total) return;
    int n = i >> 7, a = i & 127;
    int bz = n / rowsPerB, s = n - bz * rowsPerB;
    long base = ((long)bz * NZ) * rowsPerB * Aq + (long)s * Aq + a;
    float acc = 0.f;
#pragma unroll
    for (int z = 0; z < NZ; z++) acc += p[base + (long)z * rowsPerB * Aq];
    o[(long)s * ostride + (ocol + bz * ocolStep) + a +
      (ocolStep ? 0 : (long)bz * rowsPerB * ostride)] = f2bf(acc * scale);
}

// ---------------------------------------------------------------------------
// Merged tail: blocks 0..2047 = rbf<8>(p3 -> acat cols 0..127, scale 0.1);
// blocks 2048..3071 = mix_ln(he bf16 -> acat cols 128..255).
// ---------------------------------------------------------------------------
__global__ __launch_bounds__(256)
void tailk(const float* __restrict__ p3, const unsigned short* __restrict__ he,
           const float* __restrict__ ew, const float* __restrict__ g,
           const float* __restrict__ bb, unsigned short* __restrict__ acat)
{
    if (blockIdx.x < 2048) {
        int i = blockIdx.x * 256 + threadIdx.x;       // < 524288
        int n = i >> 7, a = i & 127;
        int bz = n >> 11, s = n & 2047;
        long base = ((long)bz * 8) * Sq * Aq + (long)s * Aq + a;
        float acc = 0.f;
#pragma unroll
        for (int z = 0; z < 8; z++) acc += p3[base + (long)z * Sq * Aq];
        acat[(long)n * 256 + a] = f2bf(acc * 0.1f);
        return;
    }
    int n    = (blockIdx.x - 2048) * 4 + (threadIdx.x >> 6);
    int lane = threadIdx.x & 63;
    float a0 = 0.0f, a1 = 0.0f;
#pragma unroll
    for (int e = 0; e < Eq; e++) {
        const unsigned short* r = he + ((long)e * Nq + n) * Aq;
        float x0 = bf2f(r[lane]), x1 = bf2f(r[lane + 64]);
        float s  = x0 + x1;
        float ss = x0 * x0 + x1 * x1;
#pragma unroll
        for (int off = 32; off > 0; off >>= 1) {
            s  += __shfl_xor(s, off);
            ss += __shfl_xor(ss, off);
        }
        float m  = s * (1.0f / Aq);
        float v  = ss * (1.0f / Aq) - m * m;
        float rs = rsqrtf(v + 1e-5f);
        float wv = ew[(long)n * Eq + e];
        a0 += wv * ((x0 - m) * rs * g[e * Aq + lane]      + bb[e * Aq + lane]);
        a1 += wv * ((x1 - m) * rs * g[e * Aq + lane + 64] + bb[e * Aq + lane + 64]);
    }
    acat[(long)n * 256 + 128 + lane]      = f2bf(a0);
    acat[(long)n * 256 + 128 + lane + 64] = f2bf(a1);
}

extern "C" void kernel_launch(void* const* d_in, const int* in_sizes, int n_in,
                              void* d_out, int out_size, void* d_ws, size_t ws_size,
                              hipStream_t stream)
{
    const float* x             = (const float*)d_in[0];
    const float* ew            = (const float*)d_in[1];
    const float* up_w          = (const float*)d_in[2];
    const float* gate_w        = (const float*)d_in[3];
    const float* down_w        = (const float*)d_in[4];
    const float* pre_w         = (const float*)d_in[5];
    const float* post_w        = (const float*)d_in[6];
    const float* an_g          = (const float*)d_in[7];
    const float* an_b          = (const float*)d_in[8];
    const float* adapt_proj_w  = (const float*)d_in[9];
    const float* adapter_w     = (const float*)d_in[10];
    const float* adapter_g     = (const float*)d_in[11];
    const float* adapter_b     = (const float*)d_in[12];
    const float* expert_proj_w = (const float*)d_in[13];
    const float* output_proj_w = (const float*)d_in[14];
    float* out = (float*)d_out;

    // ---- workspace (KB offsets; peak ~81 MB) ----
#define OFF(kb) ((char*)d_ws + (size_t)(kb) * 1024)
    float* kdp  = (float*)OFF(0);        // [2][16][D][A] 16MB (phase 1)
    float* p1   = (float*)OFF(16384);    // [8][N][A] 16MB   (phase 1)
    float* p2   = (float*)OFF(0);        // [8][N][A] 16MB   (phase 3)
    float* p3   = (float*)OFF(0);        // [2][8][S][A] 16MB (phase 4, after p2 dead)
    unsigned short* he = (unsigned short*)OFF(16384);    // [E][N][A] bf16 8MB (after p1 dead)
    unsigned short* hh   = (unsigned short*)OFF(32768);  // [N,H] 16MB
    unsigned short* xh   = (unsigned short*)OFF(49152);  // 8MB
    unsigned short* gwh  = (unsigned short*)OFF(57344);  // 4MB
    unsigned short* uwh  = (unsigned short*)OFF(61440);  // 4MB
    unsigned short* dwh  = (unsigned short*)OFF(65536);  // 4MB   } contiguous pair
    unsigned short* oph  = (unsigned short*)OFF(69632);  // 4MB   } for batched kcat
    unsigned short* pwh  = (unsigned short*)OFF(73728);  // .25MB
    unsigned short* powh = (unsigned short*)OFF(73984);  // .5MB
    unsigned short* apT  = (unsigned short*)OFF(74496);  // .5MB  } contiguous pair
    unsigned short* epT  = (unsigned short*)OFF(75008);  // .5MB  }
    unsigned short* ainh = (unsigned short*)OFF(75520);  // 1MB
    unsigned short* ainT = (unsigned short*)OFF(76544);  // [B][A][S] 1MB
    unsigned short* aouth= (unsigned short*)OFF(77568);  // 1MB
    unsigned short* adw  = (unsigned short*)OFF(78592);  // .25MB
    unsigned short* kcat = (unsigned short*)OFF(78848);  // [D][256] .5MB
    unsigned short* acat = (unsigned short*)OFF(79360);  // [N][256] 2MB -> 81408
#undef OFF
    (void)epT;

    dim3 blk(256), blk512(512);
    const long NA = (long)Nq * Aq;

    // 1. conversions + BOTH fp32 transposes in one launch (2048 + 512 blocks)
    convert_all<<<dim3(2560), blk, 0, stream>>>(x, gate_w, up_w, down_w, pre_w,
        post_w, output_proj_w, adapter_w, adapt_proj_w, expert_proj_w,
        xh, gwh, uwh, dwh, pwh, powh, oph, adw, apT);

    // 2. weight fusions (batched bz=2): bz0 = dwh@apT, bz1 = oph@epT
    mg<0><<<dim3(1, 8, 32), blk512, 0, stream>>>(dwh, apT, kdp, Aq, Hq, 16,
        (long)Dq * Hq, (long)Aq * Hq, (long)16 * Dq * Aq, (long)Dq * Aq);
    rbf<16><<<dim3(1024), blk, 0, stream>>>(kdp, kcat, Dq, 1.0f, 2 * Dq * Aq, 256, 0, 128);

    // 3. ain = LN(x @ pre_w^T)  (split-K 8); rln also writes ainT (transposed)
    mg<0><<<dim3(1, 32, 8), blk512, 0, stream>>>(xh, pwh, p1, Aq, Dq, 8, 0, 0, 0, NA);
    rln<8, true><<<dim3(1024), blk, 0, stream>>>(p1, ainh, ainT, an_g, an_b, NA);

    // 4. expert path GEMM: he = bf16(ain @ adapter_w[e]^T)
    mg<2><<<dim3(1, 32, 8), blk512, 0, stream>>>(ainh, adw, he, Aq, Aq, 1,
        0, (long)Aq * Aq, NA, 0);

    // 5. fused SwiGLU: hh = bf16(silu(x@gw^T) * (x@uw^T))  256x128, 8-PHASE (fixed)
    gup<<<dim3(16, 16), blk512, 0, stream>>>(xh, gwh, uwh, hh);

    // 6. aout = LN(hidden @ post_w^T)  (split-K 8)
    mg<0><<<dim3(1, 32, 8), blk512, 0, stream>>>(hh, powh, p2, Aq, Hq, 8, 0, 0, 0, NA);
    rln<8, false><<<dim3(1024), blk, 0, stream>>>(p2, aouth, nullptr, an_g, an_b, NA);

    // 7. FUSED score-combine: p3 partials (no wmat)
    gsc<<<dim3(8, 16, 2), blk512, 0, stream>>>(ainh, aouth, ainT, p3);

    // 8. merged tail: acat[:,0:128] = 0.1*reduce(p3); acat[:,128:256] = mix_ln(he)
    tailk<<<dim3(3072), blk, 0, stream>>>(p3, he, ew, adapter_g, adapter_b, acat);

    // 9. out = hh@dwh^T + acat@kcat^T
    gfinal<<<dim3(8, 32), blk512, 0, stream>>>(hh, dwh, acat, kcat, out);
}

// Round 21
// 154.028 us; speedup vs baseline: 1.0761x; 1.0372x over previous
//
#include <hip/hip_runtime.h>
#include <hip/hip_bf16.h>
#include <math.h>

// Problem constants (B,S,D,E = 2,2048,1024,8)
#define Bq 2
#define Sq 2048
#define Dq 1024
#define Eq 8
#define Hq 2048            // 2*D
#define Aq 128             // H/16
#define Nq (Bq*Sq)         // 4096 tokens

typedef __attribute__((ext_vector_type(4))) float f32x4;
typedef __attribute__((ext_vector_type(8))) short bfrag;   // 8 bf16 in 4 VGPRs

__device__ __forceinline__ float silu_f(float x) {
    return x / (1.0f + expf(-x));
}
__device__ __forceinline__ unsigned short f2bf(float x) {  // RNE fp32->bf16
    unsigned u = __float_as_uint(x);
    u += 0x7fffu + ((u >> 16) & 1u);
    return (unsigned short)(u >> 16);
}
__device__ __forceinline__ float bf2f(unsigned short h) {
    return __uint_as_float(((unsigned)h) << 16);
}
__device__ __forceinline__ void gl16(const unsigned short* g, unsigned short* l) {
    __builtin_amdgcn_global_load_lds(
        (const __attribute__((address_space(1))) void*)g,
        (__attribute__((address_space(3))) void*)(void*)l, 16, 0, 0);
}

// Counted-vmcnt wait-then-barrier (T4). vmcnt retires IN ORDER.
#define WAITV_BAR(N)                                            \
    asm volatile("s_waitcnt vmcnt(" #N ")" ::: "memory");       \
    __builtin_amdgcn_s_barrier();                               \
    asm volatile("" ::: "memory")
#define END_BAR()                                               \
    asm volatile("" ::: "memory");                              \
    __builtin_amdgcn_s_barrier();                               \
    asm volatile("" ::: "memory")
#define WAITV(N) asm volatile("s_waitcnt vmcnt(" #N ")" ::: "memory")
#define BARF()                                                  \
    asm volatile("" ::: "memory");                              \
    __builtin_amdgcn_s_barrier();                               \
    asm volatile("" ::: "memory")

// ---------------------------------------------------------------------------
// convert_all: fp32 -> bf16 for all inputs (blocks 0..2047, grid-stride)
// PLUS the two fp32 transposes (blocks 2048..2559).
// ---------------------------------------------------------------------------
__global__ __launch_bounds__(256)
void convert_all(const float* __restrict__ x,  const float* __restrict__ gw,
                 const float* __restrict__ uw, const float* __restrict__ dw,
                 const float* __restrict__ pw, const float* __restrict__ ow,
                 const float* __restrict__ opw, const float* __restrict__ aw,
                 const float* __restrict__ apw, const float* __restrict__ epw,
                 unsigned short* xh,  unsigned short* gwh, unsigned short* uwh,
                 unsigned short* dwh, unsigned short* pwh, unsigned short* powh,
                 unsigned short* oph, unsigned short* adw, unsigned short* apT)
{
    __shared__ float t[32][33];
    if (blockIdx.x >= 2048) {
        int bid = blockIdx.x - 2048;
        int z   = bid >> 8;
        int rem = bid & 255;
        int bx  = rem & 3, by = rem >> 2;
        const float* in = z ? epw : apw;
        unsigned short* out = apT + (size_t)z * Hq * Aq;
        int tx = threadIdx.x & 31, ty = threadIdx.x >> 5;
        int r0 = by * 32, c0 = bx * 32;
#pragma unroll
        for (int j = 0; j < 4; j++)
            t[ty + j * 8][tx] = in[(size_t)(r0 + ty + j * 8) * Aq + c0 + tx];
        __syncthreads();
#pragma unroll
        for (int j = 0; j < 4; j++)
            out[(size_t)(c0 + ty + j * 8) * Hq + r0 + tx] = f2bf(t[tx][ty + j * 8]);
        return;
    }
    const int T = 3276800;
    for (int i = blockIdx.x * 256 + threadIdx.x; i < T; i += 2048 * 256) {
        const float* in; unsigned short* hi; int j = i;
        if (j < 1048576)                 { in = x;   hi = xh;  }
        else if ((j -= 1048576) < 524288){ in = gw;  hi = gwh; }
        else if ((j -= 524288) < 524288) { in = uw;  hi = uwh; }
        else if ((j -= 524288) < 524288) { in = dw;  hi = dwh; }
        else if ((j -= 524288) < 32768)  { in = pw;  hi = pwh; }
        else if ((j -= 32768) < 65536)   { in = ow;  hi = powh; }
        else if ((j -= 65536) < 524288)  { in = opw; hi = oph; }
        else { j -= 524288;                in = aw;  hi = adw; }
        float4 v = ((const float4*)in)[j];
        ((ushort4*)hi)[j] = make_ushort4(f2bf(v.x), f2bf(v.y), f2bf(v.z), f2bf(v.w));
    }
}

// ---------------------------------------------------------------------------
// 1-term bf16 MFMA GEMM, BK=64, 8 waves (2Mx4N, wave tile 64x32), 2-buf +
// counted-vmcnt. 64 KB LDS. (Proven.)
// EPI: 0 = fp32 store (+bz*zC+kz*pz); 1 = bf16 silu-clip; 2 = bf16 plain.
// ---------------------------------------------------------------------------
template<int EPI>
__global__ __launch_bounds__(512)
void mg(const unsigned short* __restrict__ Ah, const unsigned short* __restrict__ Bh,
        void* __restrict__ Cv, int N, int K, int kchunks,
        long zA, long zB, long zC, long pz)
{
    __shared__ __align__(16) unsigned short lds[32768];  // 2 bufs x (A 8192 | B 8192)

    const int tid = threadIdx.x;
    const int l   = tid & 63;
    const int w   = tid >> 6;                  // 0..7
    const int wr  = w >> 2, wc = w & 3;
    const int bm0 = blockIdx.y * 128, bn0 = blockIdx.x * 128;
    const int bz  = blockIdx.z / kchunks;
    const int kz  = blockIdx.z - bz * kchunks;
    const int kcnt = K / kchunks;
    const int kbeg = kz * kcnt;
    const int kend = kbeg + kcnt;

    const unsigned short* A0 = Ah + (size_t)bz * zA;
    const unsigned short* B0 = Bh + (size_t)bz * zB;

    const int srow = tid >> 3;                 // 0..63 (+64 round 1)
    const int sq   = (tid & 7) ^ (srow & 7);
    const size_t aoff = (size_t)(bm0 + srow) * K + sq * 8;
    const size_t boff = (size_t)(bn0 + srow) * K + sq * 8;
    const size_t r64  = (size_t)64 * K;

    auto stage = [&](int b, int kt) {          // 4 gl16
        unsigned short* d = &lds[b * 16384 + (w << 9)];
        gl16(A0 + aoff + kt,       d + 0);
        gl16(A0 + aoff + kt + r64, d + 4096);
        gl16(B0 + boff + kt,       d + 8192);
        gl16(B0 + boff + kt + r64, d + 12288);
    };

    const int rowa = (wr * 64 + (l & 15)) * 64;
    const int rowb = (wc * 32 + (l & 15)) * 64;
    const int q0 = (((l >> 4)    ) ^ (l & 7)) << 3;
    const int q1 = (((l >> 4) + 4) ^ (l & 7)) << 3;

    f32x4 acc[4][2];
#pragma unroll
    for (int i = 0; i < 4; i++)
#pragma unroll
        for (int j = 0; j < 2; j++) acc[i][j] = (f32x4){0.f, 0.f, 0.f, 0.f};

    stage(0, kbeg);
    int cur = 0;
    for (int kt = kbeg; kt < kend; kt += 64) {
        if (kt + 64 < kend) {
            stage(cur ^ 1, kt + 64);
            WAITV_BAR(4);
        } else {
            WAITV_BAR(0);
        }
        const int cb = cur * 16384;
#pragma unroll
        for (int ks = 0; ks < 2; ks++) {
            const int qo = ks ? q1 : q0;
            bfrag a4[4], b4[2];
#pragma unroll
            for (int f = 0; f < 4; f++)
                a4[f] = *(const bfrag*)&lds[cb + rowa + f * 1024 + qo];
#pragma unroll
            for (int f = 0; f < 2; f++)
                b4[f] = *(const bfrag*)&lds[cb + 8192 + rowb + f * 1024 + qo];
#pragma unroll
            for (int i = 0; i < 4; i++)
#pragma unroll
                for (int j = 0; j < 2; j++)
                    acc[i][j] = __builtin_amdgcn_mfma_f32_16x16x32_bf16(a4[i], b4[j], acc[i][j], 0, 0, 0);
        }
        END_BAR();
        cur ^= 1;
    }

    const int crow0 = bm0 + wr * 64 + (l >> 4) * 4;
    const int ccol0 = bn0 + wc * 32 + (l & 15);
#pragma unroll
    for (int i = 0; i < 4; i++)
#pragma unroll
        for (int j = 0; j < 2; j++)
#pragma unroll
            for (int r = 0; r < 4; r++) {
                size_t idx = (size_t)(crow0 + i * 16 + r) * N + (ccol0 + j * 16);
                float v = acc[i][j][r];
                if (EPI == 0)
                    ((float*)Cv + (size_t)bz * zC + (size_t)kz * pz)[idx] = v;
                else if (EPI == 1)
                    ((unsigned short*)Cv + (size_t)bz * zC)[idx] =
                        f2bf(silu_f(fminf(fmaxf(v, -5.f), 5.f)));
                else
                    ((unsigned short*)Cv + (size_t)bz * zC)[idx] = f2bf(v);
            }
}

// ---------------------------------------------------------------------------
// mgpair: the two independent 256-block mg<0> launches merged (r21):
//   blocks 0..255   : kcat partials  (dwh@apT / oph@epT, batched, split-K 16)
//   blocks 256..511 : p1 partials    (xh@pwh, split-K 8)
// Same proven mg body; parameters selected per block. fp32 stores.
// ---------------------------------------------------------------------------
__global__ __launch_bounds__(512)
void mgpair(const unsigned short* __restrict__ dwh, const unsigned short* __restrict__ apT,
            float* __restrict__ kdp,
            const unsigned short* __restrict__ xh, const unsigned short* __restrict__ pwh,
            float* __restrict__ p1)
{
    __shared__ __align__(16) unsigned short lds[32768];

    const int tid = threadIdx.x;
    const int l   = tid & 63;
    const int w   = tid >> 6;
    const int wr  = w >> 2, wc = w & 3;

    const unsigned short *Ah, *Bh; float* Cv;
    int K, kchunks, by, zidx;
    long zA, zB, zC, pz;
    int bid = blockIdx.x;
    if (bid < 256) {
        Ah = dwh; Bh = apT; Cv = kdp; K = Hq; kchunks = 16;
        zA = (long)Dq * Hq; zB = (long)Aq * Hq; zC = (long)16 * Dq * Aq; pz = (long)Dq * Aq;
        by = bid & 7; zidx = bid >> 3;
    } else {
        int r = bid - 256;
        Ah = xh; Bh = pwh; Cv = p1; K = Dq; kchunks = 8;
        zA = 0; zB = 0; zC = 0; pz = (long)Nq * Aq;
        by = r & 31; zidx = r >> 5;
    }
    const int N = Aq;
    const int bm0 = by * 128, bn0 = 0;
    const int bz  = zidx / kchunks;
    const int kz  = zidx - bz * kchunks;
    const int kcnt = K / kchunks;
    const int kbeg = kz * kcnt;
    const int kend = kbeg + kcnt;

    const unsigned short* A0 = Ah + (size_t)bz * zA;
    const unsigned short* B0 = Bh + (size_t)bz * zB;

    const int srow = tid >> 3;
    const int sq   = (tid & 7) ^ (srow & 7);
    const size_t aoff = (size_t)(bm0 + srow) * K + sq * 8;
    const size_t boff = (size_t)(bn0 + srow) * K + sq * 8;
    const size_t r64  = (size_t)64 * K;

    auto stage = [&](int b, int kt) {
        unsigned short* d = &lds[b * 16384 + (w << 9)];
        gl16(A0 + aoff + kt,       d + 0);
        gl16(A0 + aoff + kt + r64, d + 4096);
        gl16(B0 + boff + kt,       d + 8192);
        gl16(B0 + boff + kt + r64, d + 12288);
    };

    const int rowa = (wr * 64 + (l & 15)) * 64;
    const int rowb = (wc * 32 + (l & 15)) * 64;
    const int q0 = (((l >> 4)    ) ^ (l & 7)) << 3;
    const int q1 = (((l >> 4) + 4) ^ (l & 7)) << 3;

    f32x4 acc[4][2];
#pragma unroll
    for (int i = 0; i < 4; i++)
#pragma unroll
        for (int j = 0; j < 2; j++) acc[i][j] = (f32x4){0.f, 0.f, 0.f, 0.f};

    stage(0, kbeg);
    int cur = 0;
    for (int kt = kbeg; kt < kend; kt += 64) {
        if (kt + 64 < kend) {
            stage(cur ^ 1, kt + 64);
            WAITV_BAR(4);
        } else {
            WAITV_BAR(0);
        }
        const int cb = cur * 16384;
#pragma unroll
        for (int ks = 0; ks < 2; ks++) {
            const int qo = ks ? q1 : q0;
            bfrag a4[4], b4[2];
#pragma unroll
            for (int f = 0; f < 4; f++)
                a4[f] = *(const bfrag*)&lds[cb + rowa + f * 1024 + qo];
#pragma unroll
            for (int f = 0; f < 2; f++)
                b4[f] = *(const bfrag*)&lds[cb + 8192 + rowb + f * 1024 + qo];
#pragma unroll
            for (int i = 0; i < 4; i++)
#pragma unroll
                for (int j = 0; j < 2; j++)
                    acc[i][j] = __builtin_amdgcn_mfma_f32_16x16x32_bf16(a4[i], b4[j], acc[i][j], 0, 0, 0);
        }
        END_BAR();
        cur ^= 1;
    }

    const int crow0 = bm0 + wr * 64 + (l >> 4) * 4;
    const int ccol0 = bn0 + wc * 32 + (l & 15);
    float* C = Cv + (size_t)bz * zC + (size_t)kz * pz;
#pragma unroll
    for (int i = 0; i < 4; i++)
#pragma unroll
        for (int j = 0; j < 2; j++)
#pragma unroll
            for (int r = 0; r < 4; r++)
                C[(size_t)(crow0 + i * 16 + r) * N + (ccol0 + j * 16)] = acc[i][j][r];
}

// ---------------------------------------------------------------------------
// Fused score-combine (steps 6+7, no wmat). (Proven r17.)
// ---------------------------------------------------------------------------
__global__ __launch_bounds__(512)
void gsc(const unsigned short* __restrict__ ainh, const unsigned short* __restrict__ aouth,
         const unsigned short* __restrict__ ainT, float* __restrict__ p3)
{
    __shared__ __align__(16) unsigned short lds[65536];  // 128 KB
    const int AIN = 0, AOUT = 16384, AINT = 32768, PB = 49152;

    const int tid = threadIdx.x;
    const int l   = tid & 63;
    const int w   = tid >> 6;
    const int wr  = w >> 2, wc = w & 3;
    const int tz  = blockIdx.x;        // 0..7
    const int ib  = blockIdx.y;        // 0..15
    const int b   = blockIdx.z;        // 0..1
    const long SA = (long)Sq * Aq;

    auto stage32 = [&](int base, const unsigned short* src, size_t kstride) {
#pragma unroll
        for (int rd = 0; rd < 4; rd++) {
            int grow = rd * 32 + (w << 2) + (l >> 4);
            int slot = (l & 15) ^ (grow & 15);
            gl16(src + (size_t)grow * kstride + slot * 8,
                 &lds[base + rd * 4096 + (w << 9)]);
        }
    };

    const unsigned short* ainI_src = ainh + (size_t)b * SA + (size_t)(ib * 128) * Aq;
    f32x4 acc2[4][2];
#pragma unroll
    for (int i = 0; i < 4; i++)
#pragma unroll
        for (int j = 0; j < 2; j++) acc2[i][j] = (f32x4){0.f, 0.f, 0.f, 0.f};

    {
        int tglob = tz * 2;
        stage32(AIN,  ainI_src, Aq);
        stage32(AOUT, aouth + (size_t)b * SA + (size_t)(tglob * 128) * Aq, Aq);
        stage32(AINT, ainT  + (size_t)b * SA + (size_t)(tglob * 128), Sq);
        WAITV_BAR(0);
    }

    const int rowa = (wr * 64 + (l & 15)) * 128;
    const int rowb = (wc * 32 + (l & 15)) * 128;

#pragma unroll 1
    for (int t = 0; t < 2; t++) {
        if (t == 1) {
            int tglob = tz * 2 + 1;
            stage32(AOUT, aouth + (size_t)b * SA + (size_t)(tglob * 128) * Aq, Aq);
            stage32(AINT, ainT  + (size_t)b * SA + (size_t)(tglob * 128), Sq);
            WAITV_BAR(0);
        }
        f32x4 acc1[4][2];
#pragma unroll
        for (int i = 0; i < 4; i++)
#pragma unroll
            for (int j = 0; j < 2; j++) acc1[i][j] = (f32x4){0.f, 0.f, 0.f, 0.f};
#pragma unroll
        for (int ks = 0; ks < 4; ks++) {
            const int qo = ((ks * 4 + (l >> 4)) ^ (l & 15)) << 3;
            bfrag a4[4], b4[2];
#pragma unroll
            for (int f = 0; f < 4; f++)
                a4[f] = *(const bfrag*)&lds[AIN + rowa + f * 2048 + qo];
#pragma unroll
            for (int f = 0; f < 2; f++)
                b4[f] = *(const bfrag*)&lds[AOUT + rowb + f * 2048 + qo];
#pragma unroll
            for (int i = 0; i < 4; i++)
#pragma unroll
                for (int j = 0; j < 2; j++)
                    acc1[i][j] = __builtin_amdgcn_mfma_f32_16x16x32_bf16(a4[i], b4[j], acc1[i][j], 0, 0, 0);
        }
        {
            const int prow0 = wr * 64 + (l >> 4) * 4;
            const int pcol0 = wc * 32 + (l & 15);
#pragma unroll
            for (int i = 0; i < 4; i++)
#pragma unroll
                for (int j = 0; j < 2; j++)
#pragma unroll
                    for (int r = 0; r < 4; r++) {
                        int pr = prow0 + i * 16 + r;
                        int pc = pcol0 + j * 16;
                        float v = silu_f(fminf(fmaxf(acc1[i][j][r], -5.f), 5.f));
                        lds[PB + pr * 128 + (((pc >> 3) ^ (pr & 15)) << 3) + (pc & 7)] = f2bf(v);
                    }
        }
        __syncthreads();
#pragma unroll
        for (int ks = 0; ks < 4; ks++) {
            const int qo = ((ks * 4 + (l >> 4)) ^ (l & 15)) << 3;
            bfrag a4[4], b4[2];
#pragma unroll
            for (int f = 0; f < 4; f++)
                a4[f] = *(const bfrag*)&lds[PB + rowa + f * 2048 + qo];
#pragma unroll
            for (int f = 0; f < 2; f++)
                b4[f] = *(const bfrag*)&lds[AINT + rowb + f * 2048 + qo];
#pragma unroll
            for (int i = 0; i < 4; i++)
#pragma unroll
                for (int j = 0; j < 2; j++)
                    acc2[i][j] = __builtin_amdgcn_mfma_f32_16x16x32_bf16(a4[i], b4[j], acc2[i][j], 0, 0, 0);
        }
        __syncthreads();
    }

    const int crow0 = wr * 64 + (l >> 4) * 4;
    const int ccol0 = wc * 32 + (l & 15);
    float* dst = p3 + ((size_t)(b * 8 + tz) * Sq + ib * 128) * Aq;
#pragma unroll
    for (int i = 0; i < 4; i++)
#pragma unroll
        for (int j = 0; j < 2; j++)
#pragma unroll
            for (int r = 0; r < 4; r++)
                dst[(size_t)(crow0 + i * 16 + r) * Aq + ccol0 + j * 16] = acc2[i][j][r];
}

// ---------------------------------------------------------------------------
// Fused gate+up GEMM — 8-PHASE schedule, race-fixed (proven r20):
// Phase = {WAITV(N); BARF; ds-read subtile; stage next unit; setprio(1);
//          16 MFMA; setprio(0)}.  4 barriers/K-tile; vmcnt never 0 mid-loop.
// tile 256x128, BK=64, 8 waves 2Mx4N (wave tile 128x32), LDS 2 x 64 KB.
// ---------------------------------------------------------------------------
__global__ __launch_bounds__(512)
void gup(const unsigned short* __restrict__ xh, const unsigned short* __restrict__ gwh,
         const unsigned short* __restrict__ uwh, unsigned short* __restrict__ hh)
{
    __shared__ __align__(16) unsigned short lds[65536];  // 2 bufs x 32768 ushorts
    const int tid = threadIdx.x;
    const int l   = tid & 63;
    const int w   = tid >> 6;
    const int wr  = w >> 2;
    const int wc  = w & 3;

    int id  = blockIdx.y * gridDim.x + blockIdx.x;     // grid (16,16)
    int xcd = id & 7, j0 = id >> 3;
    int bx  = (xcd & 3) * 4 + (j0 & 3);
    int by  = (xcd >> 2) * 8 + (j0 >> 2);
    const int bm0 = by * 256, bn0 = bx * 128;

    const int srw = tid >> 3;
    const int sq  = (tid & 7) ^ (srw & 7);
    auto stageU = [&](int b, int u, int kt) {
        unsigned short* d = &lds[b * 32768 + u * 8192 + (tid << 3)];
        const unsigned short* src = (u < 2) ? xh : (u == 2 ? gwh : uwh);
        int baserow = (u < 2) ? (bm0 + u * 128) : bn0;
        size_t o = (size_t)(baserow + srw) * Dq + kt + sq * 8;
        gl16(src + o,                   d);
        gl16(src + o + (size_t)64 * Dq, d + 4096);
    };

    const int rowa = (wr * 128 + (l & 15)) * 64;
    const int rowb = (wc * 32  + (l & 15)) * 64;
    const int q0 = (((l >> 4)    ) ^ (l & 7)) << 3;
    const int q1 = (((l >> 4) + 4) ^ (l & 7)) << 3;

    f32x4 accg[8][2], accu[8][2];
#pragma unroll
    for (int i = 0; i < 8; i++)
#pragma unroll
        for (int jj = 0; jj < 2; jj++) {
            accg[i][jj] = (f32x4){0.f, 0.f, 0.f, 0.f};
            accu[i][jj] = (f32x4){0.f, 0.f, 0.f, 0.f};
        }

    stageU(0, 0, 0); stageU(0, 1, 0); stageU(0, 2, 0); stageU(0, 3, 0);
    int cur = 0;
    for (int kt = 0; kt < Dq; kt += 64) {
        const int pf = (kt + 64 < Dq);
        const int cb = cur * 32768;
        const int nx = cur ^ 1;
        bfrag a4[8], b4[2];

        // ---- phase 0: ks0 gate ----
        WAITV(2);
        BARF();
#pragma unroll
        for (int f = 0; f < 8; f++)
            a4[f] = *(const bfrag*)&lds[cb + rowa + f * 1024 + q0];
#pragma unroll
        for (int f = 0; f < 2; f++)
            b4[f] = *(const bfrag*)&lds[cb + 16384 + rowb + f * 1024 + q0];
        if (pf) stageU(nx, 0, kt + 64);
        __builtin_amdgcn_s_setprio(1);
#pragma unroll
        for (int i = 0; i < 8; i++)
#pragma unroll
            for (int jj = 0; jj < 2; jj++)
                accg[i][jj] = __builtin_amdgcn_mfma_f32_16x16x32_bf16(a4[i], b4[jj], accg[i][jj], 0, 0, 0);
        __builtin_amdgcn_s_setprio(0);

        // ---- phase 1: ks0 up ----
        if (pf) { WAITV(2); } else { WAITV(0); }
        BARF();
#pragma unroll
        for (int f = 0; f < 2; f++)
            b4[f] = *(const bfrag*)&lds[cb + 24576 + rowb + f * 1024 + q0];
        if (pf) stageU(nx, 1, kt + 64);
        __builtin_amdgcn_s_setprio(1);
#pragma unroll
        for (int i = 0; i < 8; i++)
#pragma unroll
            for (int jj = 0; jj < 2; jj++)
                accu[i][jj] = __builtin_amdgcn_mfma_f32_16x16x32_bf16(a4[i], b4[jj], accu[i][jj], 0, 0, 0);
        __builtin_amdgcn_s_setprio(0);

        // ---- phase 2: ks1 gate ----
        BARF();
#pragma unroll
        for (int f = 0; f < 8; f++)
            a4[f] = *(const bfrag*)&lds[cb + rowa + f * 1024 + q1];
#pragma unroll
        for (int f = 0; f < 2; f++)
            b4[f] = *(const bfrag*)&lds[cb + 16384 + rowb + f * 1024 + q1];
        if (pf) stageU(nx, 2, kt + 64);
        __builtin_amdgcn_s_setprio(1);
#pragma unroll
        for (int i = 0; i < 8; i++)
#pragma unroll
            for (int jj = 0; jj < 2; jj++)
                accg[i][jj] = __builtin_amdgcn_mfma_f32_16x16x32_bf16(a4[i], b4[jj], accg[i][jj], 0, 0, 0);
        __builtin_amdgcn_s_setprio(0);

        // ---- phase 3: ks1 up ----
        BARF();
#pragma unroll
        for (int f = 0; f < 2; f++)
            b4[f] = *(const bfrag*)&lds[cb + 24576 + rowb + f * 1024 + q1];
        if (pf) stageU(nx, 3, kt + 64);
        __builtin_amdgcn_s_setprio(1);
#pragma unroll
        for (int i = 0; i < 8; i++)
#pragma unroll
            for (int jj = 0; jj < 2; jj++)
                accu[i][jj] = __builtin_amdgcn_mfma_f32_16x16x32_bf16(a4[i], b4[jj], accu[i][jj], 0, 0, 0);
        __builtin_amdgcn_s_setprio(0);

        cur = nx;
    }

    const int crow0 = bm0 + wr * 128 + (l >> 4) * 4;
    const int ccol0 = bn0 + wc * 32 + (l & 15);
#pragma unroll
    for (int i = 0; i < 8; i++)
#pragma unroll
        for (int jj = 0; jj < 2; jj++)
#pragma unroll
            for (int r = 0; r < 4; r++) {
                size_t idx = (size_t)(crow0 + i * 16 + r) * Hq + (ccol0 + jj * 16);
                hh[idx] = f2bf(silu_f(accg[i][jj][r]) * accu[i][jj][r]);
            }
}

// ---------------------------------------------------------------------------
// Final fused GEMM, BK=64, 8 waves (2Mx4N), 3-deep ring (96 KB LDS), with
// the r20-proven 2-phase split in the main loop: ks0/ks1 separated by a
// barrier, half-stage per phase, setprio around each 8-MFMA cluster.
// vmcnt audit: loads issue A-then-B per tile; WAITV_BAR(4) retires exactly
// the oldest tile (in-order). Ring WAR safety unchanged (stage targets
// buf((cur+2)%3), readers of it passed the top rendezvous last iteration).
//   out[4096][1024] = hh@dwh^T (K=2048) + acat@kcat^T (K=256)
// ---------------------------------------------------------------------------
__global__ __launch_bounds__(512)
void gfinal(const unsigned short* __restrict__ hh, const unsigned short* __restrict__ dwh,
            const unsigned short* __restrict__ acat, const unsigned short* __restrict__ kcat,
            float* __restrict__ out)
{
    __shared__ __align__(16) unsigned short lds[49152];  // 3 bufs x 16384
    const int tid = threadIdx.x;
    const int l   = tid & 63;
    const int w   = tid >> 6;
    const int wr  = w >> 2, wc = w & 3;

    int nb  = gridDim.x * gridDim.y;                      // 256
    int id  = blockIdx.y * gridDim.x + blockIdx.x;
    int id2 = (id & 7) * (nb >> 3) + (id >> 3);
    int bx  = id2 % gridDim.x, by = id2 / gridDim.x;
    const int bm0 = by * 128, bn0 = bx * 128;

    const int srow = tid >> 3;
    const int sq   = (tid & 7) ^ (srow & 7);
    const int rowa = (wr * 64 + (l & 15)) * 64;
    const int rowb = (wc * 32 + (l & 15)) * 64;
    const int q0 = (((l >> 4)    ) ^ (l & 7)) << 3;
    const int q1 = (((l >> 4) + 4) ^ (l & 7)) << 3;

    f32x4 acc[4][2];
#pragma unroll
    for (int i = 0; i < 4; i++)
#pragma unroll
        for (int j = 0; j < 2; j++) acc[i][j] = (f32x4){0.f, 0.f, 0.f, 0.f};

    // ---- main: K=2048, 3-deep ring, 2-phase ----
    {
        const size_t aoff = (size_t)(bm0 + srow) * Hq + sq * 8;
        const size_t boff = (size_t)(bn0 + srow) * Hq + sq * 8;
        const size_t r64  = (size_t)64 * Hq;
        auto stageA = [&](int b, int kt) {     // 2 gl16 (hh half)
            unsigned short* d = &lds[b * 16384 + (w << 9)];
            gl16(hh + aoff + kt,       d + 0);
            gl16(hh + aoff + kt + r64, d + 4096);
        };
        auto stageB = [&](int b, int kt) {     // 2 gl16 (dwh half)
            unsigned short* d = &lds[b * 16384 + (w << 9)];
            gl16(dwh + boff + kt,       d + 8192);
            gl16(dwh + boff + kt + r64, d + 12288);
        };
        stageA(0, 0);  stageB(0, 0);
        stageA(1, 64); stageB(1, 64);
        int cur = 0;
        for (int kt = 0; kt < Hq; kt += 64) {
            if (kt + 64 < Hq) { WAITV_BAR(4); } else { WAITV_BAR(0); }
            const int pf  = (kt + 128 < Hq);
            const int nb3 = (cur + 2 >= 3) ? cur - 1 : cur + 2;
            const int cb  = cur * 16384;
            bfrag a4[4], b4[2];
            // ---- phase 0: ks0 ----
#pragma unroll
            for (int f = 0; f < 4; f++)
                a4[f] = *(const bfrag*)&lds[cb + rowa + f * 1024 + q0];
#pragma unroll
            for (int f = 0; f < 2; f++)
                b4[f] = *(const bfrag*)&lds[cb + 8192 + rowb + f * 1024 + q0];
            if (pf) stageA(nb3, kt + 128);
            __builtin_amdgcn_s_setprio(1);
#pragma unroll
            for (int i = 0; i < 4; i++)
#pragma unroll
                for (int j = 0; j < 2; j++)
                    acc[i][j] = __builtin_amdgcn_mfma_f32_16x16x32_bf16(a4[i], b4[j], acc[i][j], 0, 0, 0);
            __builtin_amdgcn_s_setprio(0);
            BARF();
            // ---- phase 1: ks1 ----
#pragma unroll
            for (int f = 0; f < 4; f++)
                a4[f] = *(const bfrag*)&lds[cb + rowa + f * 1024 + q1];
#pragma unroll
            for (int f = 0; f < 2; f++)
                b4[f] = *(const bfrag*)&lds[cb + 8192 + rowb + f * 1024 + q1];
            if (pf) stageB(nb3, kt + 128);
            __builtin_amdgcn_s_setprio(1);
#pragma unroll
            for (int i = 0; i < 4; i++)
#pragma unroll
                for (int j = 0; j < 2; j++)
                    acc[i][j] = __builtin_amdgcn_mfma_f32_16x16x32_bf16(a4[i], b4[j], acc[i][j], 0, 0, 0);
            __builtin_amdgcn_s_setprio(0);
            cur = (cur == 2) ? 0 : cur + 1;
        }
    }
    END_BAR();   // all waves' main reads done before tail staging reuses bufs
    // ---- tail: K=256 over [acat | kcat], 3-deep (4 iters) ----
    {
        const size_t aoff = (size_t)(bm0 + srow) * 256 + sq * 8;
        const size_t boff = (size_t)(bn0 + srow) * 256 + sq * 8;
        const size_t r64  = (size_t)64 * 256;
        auto stage2 = [&](int b, int kt) {
            unsigned short* d = &lds[b * 16384 + (w << 9)];
            gl16(acat + aoff + kt,       d + 0);
            gl16(acat + aoff + kt + r64, d + 4096);
            gl16(kcat + boff + kt,       d + 8192);
            gl16(kcat + boff + kt + r64, d + 12288);
        };
        stage2(0, 0);
        stage2(1, 64);
        int cur = 0;
        for (int kt = 0; kt < 256; kt += 64) {
            if (kt + 64 < 256) { WAITV_BAR(4); } else { WAITV_BAR(0); }
            if (kt + 128 < 256) {
                int nb3 = (cur + 2 >= 3) ? cur - 1 : cur + 2;
                stage2(nb3, kt + 128);
            }
            const int cb = cur * 16384;
#pragma unroll
            for (int ks = 0; ks < 2; ks++) {
                const int qo = ks ? q1 : q0;
                bfrag a4[4], b4[2];
#pragma unroll
                for (int f = 0; f < 4; f++)
                    a4[f] = *(const bfrag*)&lds[cb + rowa + f * 1024 + qo];
#pragma unroll
                for (int f = 0; f < 2; f++)
                    b4[f] = *(const bfrag*)&lds[cb + 8192 + rowb + f * 1024 + qo];
#pragma unroll
                for (int i = 0; i < 4; i++)
#pragma unroll
                    for (int j = 0; j < 2; j++)
                        acc[i][j] = __builtin_amdgcn_mfma_f32_16x16x32_bf16(a4[i], b4[j], acc[i][j], 0, 0, 0);
            }
            cur = (cur == 2) ? 0 : cur + 1;
        }
    }

    const int crow0 = bm0 + wr * 64 + (l >> 4) * 4;
    const int ccol0 = bn0 + wc * 32 + (l & 15);
#pragma unroll
    for (int i = 0; i < 4; i++)
#pragma unroll
        for (int j = 0; j < 2; j++)
#pragma unroll
            for (int r = 0; r < 4; r++)
                out[(size_t)(crow0 + i * 16 + r) * Dq + ccol0 + j * 16] = acc[i][j][r];
}

// ---------------------------------------------------------------------------
// Reduce NZ split-K partials + LayerNorm over A=128 -> bf16.
// WT: also scatter transposed into aT[b][a][s].
// ---------------------------------------------------------------------------
template<int NZ, bool WT>
__global__ __launch_bounds__(256)
void rln(const float* __restrict__ p, unsigned short* __restrict__ oh,
         unsigned short* __restrict__ aT,
         const float* __restrict__ g, const float* __restrict__ b, long pstride)
{
    int row  = blockIdx.x * 4 + (threadIdx.x >> 6);
    int lane = threadIdx.x & 63;
    long base = (long)row * Aq;
    float x0 = 0.f, x1 = 0.f;
#pragma unroll
    for (int z = 0; z < NZ; z++) {
        x0 += p[base + z * pstride + lane];
        x1 += p[base + z * pstride + lane + 64];
    }
    float s  = x0 + x1;
    float ss = x0 * x0 + x1 * x1;
#pragma unroll
    for (int off = 32; off > 0; off >>= 1) {
        s  += __shfl_xor(s, off);
        ss += __shfl_xor(ss, off);
    }
    float m  = s * (1.0f / Aq);
    float v  = ss * (1.0f / Aq) - m * m;
    float rs = rsqrtf(v + 1e-5f);
    unsigned short h0 = f2bf((x0 - m) * rs * g[lane]      + b[lane]);
    unsigned short h1 = f2bf((x1 - m) * rs * g[lane + 64] + b[lane + 64]);
    oh[base + lane]      = h0;
    oh[base + lane + 64] = h1;
    if (WT) {
        int bb2 = row >> 11, sidx = row & 2047;
        unsigned short* t = aT + (size_t)bb2 * Sq * Aq + sidx;
        t[(size_t)lane * Sq]        = h0;
        t[(size_t)(lane + 64) * Sq] = h1;
    }
}

// ---------------------------------------------------------------------------
// rlnrbf (r21 merge): blocks 0..1023 = kcat reduce (rbf<16> semantics);
// blocks 1024..2047 = ain LN + transposed scatter (rln<8,true> semantics).
// ---------------------------------------------------------------------------
__global__ __launch_bounds__(256)
void rlnrbf(const float* __restrict__ kdp, const float* __restrict__ p1,
            unsigned short* __restrict__ kcat,
            unsigned short* __restrict__ ainh, unsigned short* __restrict__ ainT,
            const float* __restrict__ g, const float* __restrict__ b)
{
    if (blockIdx.x < 1024) {
        int i = blockIdx.x * 256 + threadIdx.x;       // < 262144
        int n = i >> 7, a = i & 127;
        int bz = n >> 10, s = n & 1023;
        long base = (long)bz * 16 * Dq * Aq + (long)s * Aq + a;
        float acc = 0.f;
#pragma unroll
        for (int z = 0; z < 16; z++) acc += kdp[base + (long)z * Dq * Aq];
        kcat[(long)s * 256 + bz * 128 + a] = f2bf(acc);
        return;
    }
    int row  = (blockIdx.x - 1024) * 4 + (threadIdx.x >> 6);
    int lane = threadIdx.x & 63;
    long base = (long)row * Aq;
    float x0 = 0.f, x1 = 0.f;
#pragma unroll
    for (int z = 0; z < 8; z++) {
        x0 += p1[base + (long)z * Nq * Aq + lane];
        x1 += p1[base + (long)z * Nq * Aq + lane + 64];
    }
    float s  = x0 + x1;
    float ss = x0 * x0 + x1 * x1;
#pragma unroll
    for (int off = 32; off > 0; off >>= 1) {
        s  += __shfl_xor(s, off);
        ss += __shfl_xor(ss, off);
    }
    float m  = s * (1.0f / Aq);
    float v  = ss * (1.0f / Aq) - m * m;
    float rs = rsqrtf(v + 1e-5f);
    unsigned short h0 = f2bf((x0 - m) * rs * g[lane]      + b[lane]);
    unsigned short h1 = f2bf((x1 - m) * rs * g[lane + 64] + b[lane + 64]);
    ainh[base + lane]      = h0;
    ainh[base + lane + 64] = h1;
    int bb2 = row >> 11, sidx = row & 2047;
    unsigned short* t = ainT + (size_t)bb2 * Sq * Aq + sidx;
    t[(size_t)lane * Sq]        = h0;
    t[(size_t)(lane + 64) * Sq] = h1;
}

// ---------------------------------------------------------------------------
// Merged tail: blocks 0..2047 = reduce(p3) -> acat cols 0..127 (scale 0.1);
// blocks 2048..3071 = mix_ln(he bf16 -> acat cols 128..255).
// ---------------------------------------------------------------------------
__global__ __launch_bounds__(256)
void tailk(const float* __restrict__ p3, const unsigned short* __restrict__ he,
           const float* __restrict__ ew, const float* __restrict__ g,
           const float* __restrict__ bb, unsigned short* __restrict__ acat)
{
    if (blockIdx.x < 2048) {
        int i = blockIdx.x * 256 + threadIdx.x;       // < 524288
        int n = i >> 7, a = i & 127;
        int bz = n >> 11, s = n & 2047;
        long base = ((long)bz * 8) * Sq * Aq + (long)s * Aq + a;
        float acc = 0.f;
#pragma unroll
        for (int z = 0; z < 8; z++) acc += p3[base + (long)z * Sq * Aq];
        acat[(long)n * 256 + a] = f2bf(acc * 0.1f);
        return;
    }
    int n    = (blockIdx.x - 2048) * 4 + (threadIdx.x >> 6);
    int lane = threadIdx.x & 63;
    float a0 = 0.0f, a1 = 0.0f;
#pragma unroll
    for (int e = 0; e < Eq; e++) {
        const unsigned short* r = he + ((long)e * Nq + n) * Aq;
        float x0 = bf2f(r[lane]), x1 = bf2f(r[lane + 64]);
        float s  = x0 + x1;
        float ss = x0 * x0 + x1 * x1;
#pragma unroll
        for (int off = 32; off > 0; off >>= 1) {
            s  += __shfl_xor(s, off);
            ss += __shfl_xor(ss, off);
        }
        float m  = s * (1.0f / Aq);
        float v  = ss * (1.0f / Aq) - m * m;
        float rs = rsqrtf(v + 1e-5f);
        float wv = ew[(long)n * Eq + e];
        a0 += wv * ((x0 - m) * rs * g[e * Aq + lane]      + bb[e * Aq + lane]);
        a1 += wv * ((x1 - m) * rs * g[e * Aq + lane + 64] + bb[e * Aq + lane + 64]);
    }
    acat[(long)n * 256 + 128 + lane]      = f2bf(a0);
    acat[(long)n * 256 + 128 + lane + 64] = f2bf(a1);
}

extern "C" void kernel_launch(void* const* d_in, const int* in_sizes, int n_in,
                              void* d_out, int out_size, void* d_ws, size_t ws_size,
                              hipStream_t stream)
{
    const float* x             = (const float*)d_in[0];
    const float* ew            = (const float*)d_in[1];
    const float* up_w          = (const float*)d_in[2];
    const float* gate_w        = (const float*)d_in[3];
    const float* down_w        = (const float*)d_in[4];
    const float* pre_w         = (const float*)d_in[5];
    const float* post_w        = (const float*)d_in[6];
    const float* an_g          = (const float*)d_in[7];
    const float* an_b          = (const float*)d_in[8];
    const float* adapt_proj_w  = (const float*)d_in[9];
    const float* adapter_w     = (const float*)d_in[10];
    const float* adapter_g     = (const float*)d_in[11];
    const float* adapter_b     = (const float*)d_in[12];
    const float* expert_proj_w = (const float*)d_in[13];
    const float* output_proj_w = (const float*)d_in[14];
    float* out = (float*)d_out;

    // ---- workspace (KB offsets; peak ~81 MB) ----
#define OFF(kb) ((char*)d_ws + (size_t)(kb) * 1024)
    float* kdp  = (float*)OFF(0);        // [2][16][D][A] 16MB (phase 1)
    float* p1   = (float*)OFF(16384);    // [8][N][A] 16MB   (phase 1)
    float* p2   = (float*)OFF(0);        // [8][N][A] 16MB   (phase 3)
    float* p3   = (float*)OFF(0);        // [2][8][S][A] 16MB (phase 4, after p2 dead)
    unsigned short* he = (unsigned short*)OFF(16384);    // [E][N][A] bf16 8MB (after p1 dead)
    unsigned short* hh   = (unsigned short*)OFF(32768);  // [N,H] 16MB
    unsigned short* xh   = (unsigned short*)OFF(49152);  // 8MB
    unsigned short* gwh  = (unsigned short*)OFF(57344);  // 4MB
    unsigned short* uwh  = (unsigned short*)OFF(61440);  // 4MB
    unsigned short* dwh  = (unsigned short*)OFF(65536);  // 4MB   } contiguous pair
    unsigned short* oph  = (unsigned short*)OFF(69632);  // 4MB   } for batched kcat
    unsigned short* pwh  = (unsigned short*)OFF(73728);  // .25MB
    unsigned short* powh = (unsigned short*)OFF(73984);  // .5MB
    unsigned short* apT  = (unsigned short*)OFF(74496);  // .5MB  } contiguous pair
    unsigned short* epT  = (unsigned short*)OFF(75008);  // .5MB  }
    unsigned short* ainh = (unsigned short*)OFF(75520);  // 1MB
    unsigned short* ainT = (unsigned short*)OFF(76544);  // [B][A][S] 1MB
    unsigned short* aouth= (unsigned short*)OFF(77568);  // 1MB
    unsigned short* adw  = (unsigned short*)OFF(78592);  // .25MB
    unsigned short* kcat = (unsigned short*)OFF(78848);  // [D][256] .5MB
    unsigned short* acat = (unsigned short*)OFF(79360);  // [N][256] 2MB -> 81408
#undef OFF
    (void)epT;

    dim3 blk(256), blk512(512);
    const long NA = (long)Nq * Aq;

    // 1. conversions + BOTH fp32 transposes in one launch (2048 + 512 blocks)
    convert_all<<<dim3(2560), blk, 0, stream>>>(x, gate_w, up_w, down_w, pre_w,
        post_w, output_proj_w, adapter_w, adapt_proj_w, expert_proj_w,
        xh, gwh, uwh, dwh, pwh, powh, oph, adw, apT);

    // 2. MERGED: kcat partials (blocks 0..255) + p1 partials (blocks 256..511)
    mgpair<<<dim3(512), blk512, 0, stream>>>(dwh, apT, kdp, xh, pwh, p1);

    // 3. MERGED: kcat reduce (blocks 0..1023) + ain LN/transpose (1024..2047)
    rlnrbf<<<dim3(2048), blk, 0, stream>>>(kdp, p1, kcat, ainh, ainT, an_g, an_b);

    // 4. expert path GEMM: he = bf16(ain @ adapter_w[e]^T)
    mg<2><<<dim3(1, 32, 8), blk512, 0, stream>>>(ainh, adw, he, Aq, Aq, 1,
        0, (long)Aq * Aq, NA, 0);

    // 5. fused SwiGLU: hh = bf16(silu(x@gw^T) * (x@uw^T))  256x128, 8-PHASE
    gup<<<dim3(16, 16), blk512, 0, stream>>>(xh, gwh, uwh, hh);

    // 6. aout = LN(hidden @ post_w^T)  (split-K 8)
    mg<0><<<dim3(1, 32, 8), blk512, 0, stream>>>(hh, powh, p2, Aq, Hq, 8, 0, 0, 0, NA);
    rln<8, false><<<dim3(1024), blk, 0, stream>>>(p2, aouth, nullptr, an_g, an_b, NA);

    // 7. FUSED score-combine: p3 partials (no wmat)
    gsc<<<dim3(8, 16, 2), blk512, 0, stream>>>(ainh, aouth, ainT, p3);

    // 8. merged tail: acat[:,0:128] = 0.1*reduce(p3); acat[:,128:256] = mix_ln(he)
    tailk<<<dim3(3072), blk, 0, stream>>>(p3, he, ew, adapter_g, adapter_b, acat);

    // 9. out = hh@dwh^T + acat@kcat^T   (2-phase main loop)
    gfinal<<<dim3(8, 32), blk512, 0, stream>>>(hh, dwh, acat, kcat, out);
}

// Round 22
// 147.035 us; speedup vs baseline: 1.1273x; 1.0476x over previous
//
#include <hip/hip_runtime.h>
#include <hip/hip_bf16.h>
#include <math.h>

// Problem constants (B,S,D,E = 2,2048,1024,8)
#define Bq 2
#define Sq 2048
#define Dq 1024
#define Eq 8
#define Hq 2048            // 2*D
#define Aq 128             // H/16
#define Nq (Bq*Sq)         // 4096 tokens

typedef __attribute__((ext_vector_type(4))) float f32x4;
typedef __attribute__((ext_vector_type(8))) short bfrag;   // 8 bf16 in 4 VGPRs

__device__ __forceinline__ float silu_f(float x) {
    return x / (1.0f + expf(-x));
}
__device__ __forceinline__ unsigned short f2bf(float x) {  // RNE fp32->bf16
    unsigned u = __float_as_uint(x);
    u += 0x7fffu + ((u >> 16) & 1u);
    return (unsigned short)(u >> 16);
}
__device__ __forceinline__ float bf2f(unsigned short h) {
    return __uint_as_float(((unsigned)h) << 16);
}
__device__ __forceinline__ void gl16(const unsigned short* g, unsigned short* l) {
    __builtin_amdgcn_global_load_lds(
        (const __attribute__((address_space(1))) void*)g,
        (__attribute__((address_space(3))) void*)(void*)l, 16, 0, 0);
}

// Counted-vmcnt wait-then-barrier (T4). vmcnt retires IN ORDER.
#define WAITV_BAR(N)                                            \
    asm volatile("s_waitcnt vmcnt(" #N ")" ::: "memory");       \
    __builtin_amdgcn_s_barrier();                               \
    asm volatile("" ::: "memory")
#define END_BAR()                                               \
    asm volatile("" ::: "memory");                              \
    __builtin_amdgcn_s_barrier();                               \
    asm volatile("" ::: "memory")
#define WAITV(N) asm volatile("s_waitcnt vmcnt(" #N ")" ::: "memory")
#define BARF()                                                  \
    asm volatile("" ::: "memory");                              \
    __builtin_amdgcn_s_barrier();                               \
    asm volatile("" ::: "memory")

// ---------------------------------------------------------------------------
// convert_all: fp32 -> bf16 for all inputs (blocks 0..2047, grid-stride)
// PLUS the two fp32 transposes (blocks 2048..2559).
// ---------------------------------------------------------------------------
__global__ __launch_bounds__(256)
void convert_all(const float* __restrict__ x,  const float* __restrict__ gw,
                 const float* __restrict__ uw, const float* __restrict__ dw,
                 const float* __restrict__ pw, const float* __restrict__ ow,
                 const float* __restrict__ opw, const float* __restrict__ aw,
                 const float* __restrict__ apw, const float* __restrict__ epw,
                 unsigned short* xh,  unsigned short* gwh, unsigned short* uwh,
                 unsigned short* dwh, unsigned short* pwh, unsigned short* powh,
                 unsigned short* oph, unsigned short* adw, unsigned short* apT)
{
    __shared__ float t[32][33];
    if (blockIdx.x >= 2048) {
        int bid = blockIdx.x - 2048;
        int z   = bid >> 8;
        int rem = bid & 255;
        int bx  = rem & 3, by = rem >> 2;
        const float* in = z ? epw : apw;
        unsigned short* out = apT + (size_t)z * Hq * Aq;
        int tx = threadIdx.x & 31, ty = threadIdx.x >> 5;
        int r0 = by * 32, c0 = bx * 32;
#pragma unroll
        for (int j = 0; j < 4; j++)
            t[ty + j * 8][tx] = in[(size_t)(r0 + ty + j * 8) * Aq + c0 + tx];
        __syncthreads();
#pragma unroll
        for (int j = 0; j < 4; j++)
            out[(size_t)(c0 + ty + j * 8) * Hq + r0 + tx] = f2bf(t[tx][ty + j * 8]);
        return;
    }
    const int T = 3276800;
    for (int i = blockIdx.x * 256 + threadIdx.x; i < T; i += 2048 * 256) {
        const float* in; unsigned short* hi; int j = i;
        if (j < 1048576)                 { in = x;   hi = xh;  }
        else if ((j -= 1048576) < 524288){ in = gw;  hi = gwh; }
        else if ((j -= 524288) < 524288) { in = uw;  hi = uwh; }
        else if ((j -= 524288) < 524288) { in = dw;  hi = dwh; }
        else if ((j -= 524288) < 32768)  { in = pw;  hi = pwh; }
        else if ((j -= 32768) < 65536)   { in = ow;  hi = powh; }
        else if ((j -= 65536) < 524288)  { in = opw; hi = oph; }
        else { j -= 524288;                in = aw;  hi = adw; }
        float4 v = ((const float4*)in)[j];
        ((ushort4*)hi)[j] = make_ushort4(f2bf(v.x), f2bf(v.y), f2bf(v.z), f2bf(v.w));
    }
}

// ---------------------------------------------------------------------------
// 1-term bf16 MFMA GEMM, BK=64, 8 waves (2Mx4N, wave tile 64x32), 2-buf +
// counted-vmcnt. 64 KB LDS. (Proven.)  Used for he (EPI=2).
// ---------------------------------------------------------------------------
template<int EPI>
__global__ __launch_bounds__(512)
void mg(const unsigned short* __restrict__ Ah, const unsigned short* __restrict__ Bh,
        void* __restrict__ Cv, int N, int K, int kchunks,
        long zA, long zB, long zC, long pz)
{
    __shared__ __align__(16) unsigned short lds[32768];  // 2 bufs x (A 8192 | B 8192)

    const int tid = threadIdx.x;
    const int l   = tid & 63;
    const int w   = tid >> 6;                  // 0..7
    const int wr  = w >> 2, wc = w & 3;
    const int bm0 = blockIdx.y * 128, bn0 = blockIdx.x * 128;
    const int bz  = blockIdx.z / kchunks;
    const int kz  = blockIdx.z - bz * kchunks;
    const int kcnt = K / kchunks;
    const int kbeg = kz * kcnt;
    const int kend = kbeg + kcnt;

    const unsigned short* A0 = Ah + (size_t)bz * zA;
    const unsigned short* B0 = Bh + (size_t)bz * zB;

    const int srow = tid >> 3;                 // 0..63 (+64 round 1)
    const int sq   = (tid & 7) ^ (srow & 7);
    const size_t aoff = (size_t)(bm0 + srow) * K + sq * 8;
    const size_t boff = (size_t)(bn0 + srow) * K + sq * 8;
    const size_t r64  = (size_t)64 * K;

    auto stage = [&](int b, int kt) {          // 4 gl16
        unsigned short* d = &lds[b * 16384 + (w << 9)];
        gl16(A0 + aoff + kt,       d + 0);
        gl16(A0 + aoff + kt + r64, d + 4096);
        gl16(B0 + boff + kt,       d + 8192);
        gl16(B0 + boff + kt + r64, d + 12288);
    };

    const int rowa = (wr * 64 + (l & 15)) * 64;
    const int rowb = (wc * 32 + (l & 15)) * 64;
    const int q0 = (((l >> 4)    ) ^ (l & 7)) << 3;
    const int q1 = (((l >> 4) + 4) ^ (l & 7)) << 3;

    f32x4 acc[4][2];
#pragma unroll
    for (int i = 0; i < 4; i++)
#pragma unroll
        for (int j = 0; j < 2; j++) acc[i][j] = (f32x4){0.f, 0.f, 0.f, 0.f};

    stage(0, kbeg);
    int cur = 0;
    for (int kt = kbeg; kt < kend; kt += 64) {
        if (kt + 64 < kend) {
            stage(cur ^ 1, kt + 64);
            WAITV_BAR(4);
        } else {
            WAITV_BAR(0);
        }
        const int cb = cur * 16384;
#pragma unroll
        for (int ks = 0; ks < 2; ks++) {
            const int qo = ks ? q1 : q0;
            bfrag a4[4], b4[2];
#pragma unroll
            for (int f = 0; f < 4; f++)
                a4[f] = *(const bfrag*)&lds[cb + rowa + f * 1024 + qo];
#pragma unroll
            for (int f = 0; f < 2; f++)
                b4[f] = *(const bfrag*)&lds[cb + 8192 + rowb + f * 1024 + qo];
#pragma unroll
            for (int i = 0; i < 4; i++)
#pragma unroll
                for (int j = 0; j < 2; j++)
                    acc[i][j] = __builtin_amdgcn_mfma_f32_16x16x32_bf16(a4[i], b4[j], acc[i][j], 0, 0, 0);
        }
        END_BAR();
        cur ^= 1;
    }

    const int crow0 = bm0 + wr * 64 + (l >> 4) * 4;
    const int ccol0 = bn0 + wc * 32 + (l & 15);
#pragma unroll
    for (int i = 0; i < 4; i++)
#pragma unroll
        for (int j = 0; j < 2; j++)
#pragma unroll
            for (int r = 0; r < 4; r++) {
                size_t idx = (size_t)(crow0 + i * 16 + r) * N + (ccol0 + j * 16);
                float v = acc[i][j][r];
                if (EPI == 0)
                    ((float*)Cv + (size_t)bz * zC + (size_t)kz * pz)[idx] = v;
                else if (EPI == 1)
                    ((unsigned short*)Cv + (size_t)bz * zC)[idx] =
                        f2bf(silu_f(fminf(fmaxf(v, -5.f), 5.f)));
                else
                    ((unsigned short*)Cv + (size_t)bz * zC)[idx] = f2bf(v);
            }
}

// ---------------------------------------------------------------------------
// mgpair: kcat partials (blocks 0..255) + p1 partials (blocks 256..511).
// (Proven r21.)
// ---------------------------------------------------------------------------
__global__ __launch_bounds__(512)
void mgpair(const unsigned short* __restrict__ dwh, const unsigned short* __restrict__ apT,
            float* __restrict__ kdp,
            const unsigned short* __restrict__ xh, const unsigned short* __restrict__ pwh,
            float* __restrict__ p1)
{
    __shared__ __align__(16) unsigned short lds[32768];

    const int tid = threadIdx.x;
    const int l   = tid & 63;
    const int w   = tid >> 6;
    const int wr  = w >> 2, wc = w & 3;

    const unsigned short *Ah, *Bh; float* Cv;
    int K, kchunks, by, zidx;
    long zA, zB, zC, pz;
    int bid = blockIdx.x;
    if (bid < 256) {
        Ah = dwh; Bh = apT; Cv = kdp; K = Hq; kchunks = 16;
        zA = (long)Dq * Hq; zB = (long)Aq * Hq; zC = (long)16 * Dq * Aq; pz = (long)Dq * Aq;
        by = bid & 7; zidx = bid >> 3;
    } else {
        int r = bid - 256;
        Ah = xh; Bh = pwh; Cv = p1; K = Dq; kchunks = 8;
        zA = 0; zB = 0; zC = 0; pz = (long)Nq * Aq;
        by = r & 31; zidx = r >> 5;
    }
    const int N = Aq;
    const int bm0 = by * 128, bn0 = 0;
    const int bz  = zidx / kchunks;
    const int kz  = zidx - bz * kchunks;
    const int kcnt = K / kchunks;
    const int kbeg = kz * kcnt;
    const int kend = kbeg + kcnt;

    const unsigned short* A0 = Ah + (size_t)bz * zA;
    const unsigned short* B0 = Bh + (size_t)bz * zB;

    const int srow = tid >> 3;
    const int sq   = (tid & 7) ^ (srow & 7);
    const size_t aoff = (size_t)(bm0 + srow) * K + sq * 8;
    const size_t boff = (size_t)(bn0 + srow) * K + sq * 8;
    const size_t r64  = (size_t)64 * K;

    auto stage = [&](int b, int kt) {
        unsigned short* d = &lds[b * 16384 + (w << 9)];
        gl16(A0 + aoff + kt,       d + 0);
        gl16(A0 + aoff + kt + r64, d + 4096);
        gl16(B0 + boff + kt,       d + 8192);
        gl16(B0 + boff + kt + r64, d + 12288);
    };

    const int rowa = (wr * 64 + (l & 15)) * 64;
    const int rowb = (wc * 32 + (l & 15)) * 64;
    const int q0 = (((l >> 4)    ) ^ (l & 7)) << 3;
    const int q1 = (((l >> 4) + 4) ^ (l & 7)) << 3;

    f32x4 acc[4][2];
#pragma unroll
    for (int i = 0; i < 4; i++)
#pragma unroll
        for (int j = 0; j < 2; j++) acc[i][j] = (f32x4){0.f, 0.f, 0.f, 0.f};

    stage(0, kbeg);
    int cur = 0;
    for (int kt = kbeg; kt < kend; kt += 64) {
        if (kt + 64 < kend) {
            stage(cur ^ 1, kt + 64);
            WAITV_BAR(4);
        } else {
            WAITV_BAR(0);
        }
        const int cb = cur * 16384;
#pragma unroll
        for (int ks = 0; ks < 2; ks++) {
            const int qo = ks ? q1 : q0;
            bfrag a4[4], b4[2];
#pragma unroll
            for (int f = 0; f < 4; f++)
                a4[f] = *(const bfrag*)&lds[cb + rowa + f * 1024 + qo];
#pragma unroll
            for (int f = 0; f < 2; f++)
                b4[f] = *(const bfrag*)&lds[cb + 8192 + rowb + f * 1024 + qo];
#pragma unroll
            for (int i = 0; i < 4; i++)
#pragma unroll
                for (int j = 0; j < 2; j++)
                    acc[i][j] = __builtin_amdgcn_mfma_f32_16x16x32_bf16(a4[i], b4[j], acc[i][j], 0, 0, 0);
        }
        END_BAR();
        cur ^= 1;
    }

    const int crow0 = bm0 + wr * 64 + (l >> 4) * 4;
    const int ccol0 = bn0 + wc * 32 + (l & 15);
    float* C = Cv + (size_t)bz * zC + (size_t)kz * pz;
#pragma unroll
    for (int i = 0; i < 4; i++)
#pragma unroll
        for (int j = 0; j < 2; j++)
#pragma unroll
            for (int r = 0; r < 4; r++)
                C[(size_t)(crow0 + i * 16 + r) * N + (ccol0 + j * 16)] = acc[i][j][r];
}

// ---------------------------------------------------------------------------
// Fused score-combine (steps 6+7, no wmat). (Proven r17.)
// ---------------------------------------------------------------------------
__global__ __launch_bounds__(512)
void gsc(const unsigned short* __restrict__ ainh, const unsigned short* __restrict__ aouth,
         const unsigned short* __restrict__ ainT, float* __restrict__ p3)
{
    __shared__ __align__(16) unsigned short lds[65536];  // 128 KB
    const int AIN = 0, AOUT = 16384, AINT = 32768, PB = 49152;

    const int tid = threadIdx.x;
    const int l   = tid & 63;
    const int w   = tid >> 6;
    const int wr  = w >> 2, wc = w & 3;
    const int tz  = blockIdx.x;        // 0..7
    const int ib  = blockIdx.y;        // 0..15
    const int b   = blockIdx.z;        // 0..1
    const long SA = (long)Sq * Aq;

    auto stage32 = [&](int base, const unsigned short* src, size_t kstride) {
#pragma unroll
        for (int rd = 0; rd < 4; rd++) {
            int grow = rd * 32 + (w << 2) + (l >> 4);
            int slot = (l & 15) ^ (grow & 15);
            gl16(src + (size_t)grow * kstride + slot * 8,
                 &lds[base + rd * 4096 + (w << 9)]);
        }
    };

    const unsigned short* ainI_src = ainh + (size_t)b * SA + (size_t)(ib * 128) * Aq;
    f32x4 acc2[4][2];
#pragma unroll
    for (int i = 0; i < 4; i++)
#pragma unroll
        for (int j = 0; j < 2; j++) acc2[i][j] = (f32x4){0.f, 0.f, 0.f, 0.f};

    {
        int tglob = tz * 2;
        stage32(AIN,  ainI_src, Aq);
        stage32(AOUT, aouth + (size_t)b * SA + (size_t)(tglob * 128) * Aq, Aq);
        stage32(AINT, ainT  + (size_t)b * SA + (size_t)(tglob * 128), Sq);
        WAITV_BAR(0);
    }

    const int rowa = (wr * 64 + (l & 15)) * 128;
    const int rowb = (wc * 32 + (l & 15)) * 128;

#pragma unroll 1
    for (int t = 0; t < 2; t++) {
        if (t == 1) {
            int tglob = tz * 2 + 1;
            stage32(AOUT, aouth + (size_t)b * SA + (size_t)(tglob * 128) * Aq, Aq);
            stage32(AINT, ainT  + (size_t)b * SA + (size_t)(tglob * 128), Sq);
            WAITV_BAR(0);
        }
        f32x4 acc1[4][2];
#pragma unroll
        for (int i = 0; i < 4; i++)
#pragma unroll
            for (int j = 0; j < 2; j++) acc1[i][j] = (f32x4){0.f, 0.f, 0.f, 0.f};
#pragma unroll
        for (int ks = 0; ks < 4; ks++) {
            const int qo = ((ks * 4 + (l >> 4)) ^ (l & 15)) << 3;
            bfrag a4[4], b4[2];
#pragma unroll
            for (int f = 0; f < 4; f++)
                a4[f] = *(const bfrag*)&lds[AIN + rowa + f * 2048 + qo];
#pragma unroll
            for (int f = 0; f < 2; f++)
                b4[f] = *(const bfrag*)&lds[AOUT + rowb + f * 2048 + qo];
#pragma unroll
            for (int i = 0; i < 4; i++)
#pragma unroll
                for (int j = 0; j < 2; j++)
                    acc1[i][j] = __builtin_amdgcn_mfma_f32_16x16x32_bf16(a4[i], b4[j], acc1[i][j], 0, 0, 0);
        }
        {
            const int prow0 = wr * 64 + (l >> 4) * 4;
            const int pcol0 = wc * 32 + (l & 15);
#pragma unroll
            for (int i = 0; i < 4; i++)
#pragma unroll
                for (int j = 0; j < 2; j++)
#pragma unroll
                    for (int r = 0; r < 4; r++) {
                        int pr = prow0 + i * 16 + r;
                        int pc = pcol0 + j * 16;
                        float v = silu_f(fminf(fmaxf(acc1[i][j][r], -5.f), 5.f));
                        lds[PB + pr * 128 + (((pc >> 3) ^ (pr & 15)) << 3) + (pc & 7)] = f2bf(v);
                    }
        }
        __syncthreads();
#pragma unroll
        for (int ks = 0; ks < 4; ks++) {
            const int qo = ((ks * 4 + (l >> 4)) ^ (l & 15)) << 3;
            bfrag a4[4], b4[2];
#pragma unroll
            for (int f = 0; f < 4; f++)
                a4[f] = *(const bfrag*)&lds[PB + rowa + f * 2048 + qo];
#pragma unroll
            for (int f = 0; f < 2; f++)
                b4[f] = *(const bfrag*)&lds[AINT + rowb + f * 2048 + qo];
#pragma unroll
            for (int i = 0; i < 4; i++)
#pragma unroll
                for (int j = 0; j < 2; j++)
                    acc2[i][j] = __builtin_amdgcn_mfma_f32_16x16x32_bf16(a4[i], b4[j], acc2[i][j], 0, 0, 0);
        }
        __syncthreads();
    }

    const int crow0 = wr * 64 + (l >> 4) * 4;
    const int ccol0 = wc * 32 + (l & 15);
    float* dst = p3 + ((size_t)(b * 8 + tz) * Sq + ib * 128) * Aq;
#pragma unroll
    for (int i = 0; i < 4; i++)
#pragma unroll
        for (int j = 0; j < 2; j++)
#pragma unroll
            for (int r = 0; r < 4; r++)
                dst[(size_t)(crow0 + i * 16 + r) * Aq + ccol0 + j * 16] = acc2[i][j][r];
}

// ---------------------------------------------------------------------------
// Fused gate+up GEMM — 8-PHASE schedule (proven r20) + NEW r22 epilogue:
// after the main loop, the 256x128 hh tile (in registers) is round-tripped
// through LDS (gsc's proven 16-slot swizzle) and multiplied by the matching
// 128x128 post_w chunk (staged with gsc's stage pattern) to emit the aout
// partial  p2b[bx] = hh_tile @ post_w_chunk^T  as bf16 — this replaces the
// separate step-6 GEMM dispatch entirely.
//   hh[n,h] = bf16( silu(x@gw^T) * (x@uw^T) );  p2b[bx][n][a] partials.
// ---------------------------------------------------------------------------
__global__ __launch_bounds__(512)
void gup(const unsigned short* __restrict__ xh, const unsigned short* __restrict__ gwh,
         const unsigned short* __restrict__ uwh, const unsigned short* __restrict__ powh,
         unsigned short* __restrict__ hh, unsigned short* __restrict__ p2b)
{
    __shared__ __align__(16) unsigned short lds[65536];  // 2 bufs x 32768 ushorts
    const int tid = threadIdx.x;
    const int l   = tid & 63;
    const int w   = tid >> 6;
    const int wr  = w >> 2;
    const int wc  = w & 3;

    int id  = blockIdx.y * gridDim.x + blockIdx.x;     // grid (16,16)
    int xcd = id & 7, j0 = id >> 3;
    int bx  = (xcd & 3) * 4 + (j0 & 3);
    int by  = (xcd >> 2) * 8 + (j0 >> 2);
    const int bm0 = by * 256, bn0 = bx * 128;

    const int srw = tid >> 3;
    const int sq  = (tid & 7) ^ (srw & 7);
    auto stageU = [&](int b, int u, int kt) {
        unsigned short* d = &lds[b * 32768 + u * 8192 + (tid << 3)];
        const unsigned short* src = (u < 2) ? xh : (u == 2 ? gwh : uwh);
        int baserow = (u < 2) ? (bm0 + u * 128) : bn0;
        size_t o = (size_t)(baserow + srw) * Dq + kt + sq * 8;
        gl16(src + o,                   d);
        gl16(src + o + (size_t)64 * Dq, d + 4096);
    };

    const int rowa = (wr * 128 + (l & 15)) * 64;
    const int rowb = (wc * 32  + (l & 15)) * 64;
    const int q0 = (((l >> 4)    ) ^ (l & 7)) << 3;
    const int q1 = (((l >> 4) + 4) ^ (l & 7)) << 3;

    f32x4 accg[8][2], accu[8][2];
#pragma unroll
    for (int i = 0; i < 8; i++)
#pragma unroll
        for (int jj = 0; jj < 2; jj++) {
            accg[i][jj] = (f32x4){0.f, 0.f, 0.f, 0.f};
            accu[i][jj] = (f32x4){0.f, 0.f, 0.f, 0.f};
        }

    stageU(0, 0, 0); stageU(0, 1, 0); stageU(0, 2, 0); stageU(0, 3, 0);
    int cur = 0;
    for (int kt = 0; kt < Dq; kt += 64) {
        const int pf = (kt + 64 < Dq);
        const int cb = cur * 32768;
        const int nx = cur ^ 1;
        bfrag a4[8], b4[2];

        // ---- phase 0: ks0 gate ----
        WAITV(2);
        BARF();
#pragma unroll
        for (int f = 0; f < 8; f++)
            a4[f] = *(const bfrag*)&lds[cb + rowa + f * 1024 + q0];
#pragma unroll
        for (int f = 0; f < 2; f++)
            b4[f] = *(const bfrag*)&lds[cb + 16384 + rowb + f * 1024 + q0];
        if (pf) stageU(nx, 0, kt + 64);
        __builtin_amdgcn_s_setprio(1);
#pragma unroll
        for (int i = 0; i < 8; i++)
#pragma unroll
            for (int jj = 0; jj < 2; jj++)
                accg[i][jj] = __builtin_amdgcn_mfma_f32_16x16x32_bf16(a4[i], b4[jj], accg[i][jj], 0, 0, 0);
        __builtin_amdgcn_s_setprio(0);

        // ---- phase 1: ks0 up ----
        if (pf) { WAITV(2); } else { WAITV(0); }
        BARF();
#pragma unroll
        for (int f = 0; f < 2; f++)
            b4[f] = *(const bfrag*)&lds[cb + 24576 + rowb + f * 1024 + q0];
        if (pf) stageU(nx, 1, kt + 64);
        __builtin_amdgcn_s_setprio(1);
#pragma unroll
        for (int i = 0; i < 8; i++)
#pragma unroll
            for (int jj = 0; jj < 2; jj++)
                accu[i][jj] = __builtin_amdgcn_mfma_f32_16x16x32_bf16(a4[i], b4[jj], accu[i][jj], 0, 0, 0);
        __builtin_amdgcn_s_setprio(0);

        // ---- phase 2: ks1 gate ----
        BARF();
#pragma unroll
        for (int f = 0; f < 8; f++)
            a4[f] = *(const bfrag*)&lds[cb + rowa + f * 1024 + q1];
#pragma unroll
        for (int f = 0; f < 2; f++)
            b4[f] = *(const bfrag*)&lds[cb + 16384 + rowb + f * 1024 + q1];
        if (pf) stageU(nx, 2, kt + 64);
        __builtin_amdgcn_s_setprio(1);
#pragma unroll
        for (int i = 0; i < 8; i++)
#pragma unroll
            for (int jj = 0; jj < 2; jj++)
                accg[i][jj] = __builtin_amdgcn_mfma_f32_16x16x32_bf16(a4[i], b4[jj], accg[i][jj], 0, 0, 0);
        __builtin_amdgcn_s_setprio(0);

        // ---- phase 3: ks1 up ----
        BARF();
#pragma unroll
        for (int f = 0; f < 2; f++)
            b4[f] = *(const bfrag*)&lds[cb + 24576 + rowb + f * 1024 + q1];
        if (pf) stageU(nx, 3, kt + 64);
        __builtin_amdgcn_s_setprio(1);
#pragma unroll
        for (int i = 0; i < 8; i++)
#pragma unroll
            for (int jj = 0; jj < 2; jj++)
                accu[i][jj] = __builtin_amdgcn_mfma_f32_16x16x32_bf16(a4[i], b4[jj], accu[i][jj], 0, 0, 0);
        __builtin_amdgcn_s_setprio(0);

        cur = nx;
    }

    // ---- r22 fused epilogue ----
    END_BAR();   // all waves' last-phase LDS reads retired -> LDS reusable
    // stage the post_w chunk [A=128 rows][H-cols bn0..bn0+127] (16-slot swz)
#pragma unroll
    for (int rd = 0; rd < 4; rd++) {
        int grow = rd * 32 + (w << 2) + (l >> 4);
        int slot = (l & 15) ^ (grow & 15);
        gl16(powh + (size_t)grow * Hq + bn0 + slot * 8,
             &lds[32768 + rd * 4096 + (tid << 3)]);
    }
    // compute hh; store to global AND into LDS A-tile [256][128] (16-slot swz)
    const int crow0 = bm0 + wr * 128 + (l >> 4) * 4;
    const int ccol0 = bn0 + wc * 32 + (l & 15);
    const int lrow0 = wr * 128 + (l >> 4) * 4;
    const int lcol0 = wc * 32 + (l & 15);
#pragma unroll
    for (int i = 0; i < 8; i++)
#pragma unroll
        for (int jj = 0; jj < 2; jj++)
#pragma unroll
            for (int r = 0; r < 4; r++) {
                float hv = silu_f(accg[i][jj][r]) * accu[i][jj][r];
                unsigned short hb = f2bf(hv);
                hh[(size_t)(crow0 + i * 16 + r) * Hq + (ccol0 + jj * 16)] = hb;
                int pr = lrow0 + i * 16 + r;
                int pc = lcol0 + jj * 16;
                lds[pr * 128 + (((pc >> 3) ^ (pr & 15)) << 3) + (pc & 7)] = hb;
            }
    __syncthreads();   // drains vmcnt (B stage + hh stores) and lgkm (A writes)
    // partial = hh_tile @ post_w_chunk^T  (K=128, 4 k-steps)
    f32x4 acc2[8][2];
#pragma unroll
    for (int i = 0; i < 8; i++)
#pragma unroll
        for (int jj = 0; jj < 2; jj++) acc2[i][jj] = (f32x4){0.f, 0.f, 0.f, 0.f};
    const int rowa2 = (wr * 128 + (l & 15)) * 128;
    const int rowb2 = 32768 + (wc * 32 + (l & 15)) * 128;
#pragma unroll
    for (int ks = 0; ks < 4; ks++) {
        const int qo = ((ks * 4 + (l >> 4)) ^ (l & 15)) << 3;
        bfrag a4[8], b4[2];
#pragma unroll
        for (int f = 0; f < 8; f++)
            a4[f] = *(const bfrag*)&lds[rowa2 + f * 2048 + qo];
#pragma unroll
        for (int f = 0; f < 2; f++)
            b4[f] = *(const bfrag*)&lds[rowb2 + f * 2048 + qo];
#pragma unroll
        for (int i = 0; i < 8; i++)
#pragma unroll
            for (int jj = 0; jj < 2; jj++)
                acc2[i][jj] = __builtin_amdgcn_mfma_f32_16x16x32_bf16(a4[i], b4[jj], acc2[i][jj], 0, 0, 0);
    }
    unsigned short* dst = p2b + (size_t)bx * Nq * Aq;
#pragma unroll
    for (int i = 0; i < 8; i++)
#pragma unroll
        for (int jj = 0; jj < 2; jj++)
#pragma unroll
            for (int r = 0; r < 4; r++)
                dst[(size_t)(crow0 + i * 16 + r) * Aq + (wc * 32 + jj * 16 + (l & 15))] =
                    f2bf(acc2[i][jj][r]);
}

// ---------------------------------------------------------------------------
// Final fused GEMM, BK=64, 8 waves (2Mx4N), 3-deep ring, 2-phase main loop.
// (Proven r21.)  out[4096][1024] = hh@dwh^T (K=2048) + acat@kcat^T (K=256)
// ---------------------------------------------------------------------------
__global__ __launch_bounds__(512)
void gfinal(const unsigned short* __restrict__ hh, const unsigned short* __restrict__ dwh,
            const unsigned short* __restrict__ acat, const unsigned short* __restrict__ kcat,
            float* __restrict__ out)
{
    __shared__ __align__(16) unsigned short lds[49152];  // 3 bufs x 16384
    const int tid = threadIdx.x;
    const int l   = tid & 63;
    const int w   = tid >> 6;
    const int wr  = w >> 2, wc = w & 3;

    int nb  = gridDim.x * gridDim.y;                      // 256
    int id  = blockIdx.y * gridDim.x + blockIdx.x;
    int id2 = (id & 7) * (nb >> 3) + (id >> 3);
    int bx  = id2 % gridDim.x, by = id2 / gridDim.x;
    const int bm0 = by * 128, bn0 = bx * 128;

    const int srow = tid >> 3;
    const int sq   = (tid & 7) ^ (srow & 7);
    const int rowa = (wr * 64 + (l & 15)) * 64;
    const int rowb = (wc * 32 + (l & 15)) * 64;
    const int q0 = (((l >> 4)    ) ^ (l & 7)) << 3;
    const int q1 = (((l >> 4) + 4) ^ (l & 7)) << 3;

    f32x4 acc[4][2];
#pragma unroll
    for (int i = 0; i < 4; i++)
#pragma unroll
        for (int j = 0; j < 2; j++) acc[i][j] = (f32x4){0.f, 0.f, 0.f, 0.f};

    // ---- main: K=2048, 3-deep ring, 2-phase ----
    {
        const size_t aoff = (size_t)(bm0 + srow) * Hq + sq * 8;
        const size_t boff = (size_t)(bn0 + srow) * Hq + sq * 8;
        const size_t r64  = (size_t)64 * Hq;
        auto stageA = [&](int b, int kt) {
            unsigned short* d = &lds[b * 16384 + (w << 9)];
            gl16(hh + aoff + kt,       d + 0);
            gl16(hh + aoff + kt + r64, d + 4096);
        };
        auto stageB = [&](int b, int kt) {
            unsigned short* d = &lds[b * 16384 + (w << 9)];
            gl16(dwh + boff + kt,       d + 8192);
            gl16(dwh + boff + kt + r64, d + 12288);
        };
        stageA(0, 0);  stageB(0, 0);
        stageA(1, 64); stageB(1, 64);
        int cur = 0;
        for (int kt = 0; kt < Hq; kt += 64) {
            if (kt + 64 < Hq) { WAITV_BAR(4); } else { WAITV_BAR(0); }
            const int pf  = (kt + 128 < Hq);
            const int nb3 = (cur + 2 >= 3) ? cur - 1 : cur + 2;
            const int cb  = cur * 16384;
            bfrag a4[4], b4[2];
            // ---- phase 0: ks0 ----
#pragma unroll
            for (int f = 0; f < 4; f++)
                a4[f] = *(const bfrag*)&lds[cb + rowa + f * 1024 + q0];
#pragma unroll
            for (int f = 0; f < 2; f++)
                b4[f] = *(const bfrag*)&lds[cb + 8192 + rowb + f * 1024 + q0];
            if (pf) stageA(nb3, kt + 128);
            __builtin_amdgcn_s_setprio(1);
#pragma unroll
            for (int i = 0; i < 4; i++)
#pragma unroll
                for (int j = 0; j < 2; j++)
                    acc[i][j] = __builtin_amdgcn_mfma_f32_16x16x32_bf16(a4[i], b4[j], acc[i][j], 0, 0, 0);
            __builtin_amdgcn_s_setprio(0);
            BARF();
            // ---- phase 1: ks1 ----
#pragma unroll
            for (int f = 0; f < 4; f++)
                a4[f] = *(const bfrag*)&lds[cb + rowa + f * 1024 + q1];
#pragma unroll
            for (int f = 0; f < 2; f++)
                b4[f] = *(const bfrag*)&lds[cb + 8192 + rowb + f * 1024 + q1];
            if (pf) stageB(nb3, kt + 128);
            __builtin_amdgcn_s_setprio(1);
#pragma unroll
            for (int i = 0; i < 4; i++)
#pragma unroll
                for (int j = 0; j < 2; j++)
                    acc[i][j] = __builtin_amdgcn_mfma_f32_16x16x32_bf16(a4[i], b4[j], acc[i][j], 0, 0, 0);
            __builtin_amdgcn_s_setprio(0);
            cur = (cur == 2) ? 0 : cur + 1;
        }
    }
    END_BAR();
    // ---- tail: K=256 over [acat | kcat], 3-deep (4 iters) ----
    {
        const size_t aoff = (size_t)(bm0 + srow) * 256 + sq * 8;
        const size_t boff = (size_t)(bn0 + srow) * 256 + sq * 8;
        const size_t r64  = (size_t)64 * 256;
        auto stage2 = [&](int b, int kt) {
            unsigned short* d = &lds[b * 16384 + (w << 9)];
            gl16(acat + aoff + kt,       d + 0);
            gl16(acat + aoff + kt + r64, d + 4096);
            gl16(kcat + boff + kt,       d + 8192);
            gl16(kcat + boff + kt + r64, d + 12288);
        };
        stage2(0, 0);
        stage2(1, 64);
        int cur = 0;
        for (int kt = 0; kt < 256; kt += 64) {
            if (kt + 64 < 256) { WAITV_BAR(4); } else { WAITV_BAR(0); }
            if (kt + 128 < 256) {
                int nb3 = (cur + 2 >= 3) ? cur - 1 : cur + 2;
                stage2(nb3, kt + 128);
            }
            const int cb = cur * 16384;
#pragma unroll
            for (int ks = 0; ks < 2; ks++) {
                const int qo = ks ? q1 : q0;
                bfrag a4[4], b4[2];
#pragma unroll
                for (int f = 0; f < 4; f++)
                    a4[f] = *(const bfrag*)&lds[cb + rowa + f * 1024 + qo];
#pragma unroll
                for (int f = 0; f < 2; f++)
                    b4[f] = *(const bfrag*)&lds[cb + 8192 + rowb + f * 1024 + qo];
#pragma unroll
                for (int i = 0; i < 4; i++)
#pragma unroll
                    for (int j = 0; j < 2; j++)
                        acc[i][j] = __builtin_amdgcn_mfma_f32_16x16x32_bf16(a4[i], b4[j], acc[i][j], 0, 0, 0);
            }
            cur = (cur == 2) ? 0 : cur + 1;
        }
    }

    const int crow0 = bm0 + wr * 64 + (l >> 4) * 4;
    const int ccol0 = bn0 + wc * 32 + (l & 15);
#pragma unroll
    for (int i = 0; i < 4; i++)
#pragma unroll
        for (int j = 0; j < 2; j++)
#pragma unroll
            for (int r = 0; r < 4; r++)
                out[(size_t)(crow0 + i * 16 + r) * Dq + ccol0 + j * 16] = acc[i][j][r];
}

// ---------------------------------------------------------------------------
// rln16b (r22): reduce 16 bf16 aout-partials (p2b from gup) + LayerNorm.
// ---------------------------------------------------------------------------
__global__ __launch_bounds__(256)
void rln16b(const unsigned short* __restrict__ p2b, unsigned short* __restrict__ oh,
            const float* __restrict__ g, const float* __restrict__ b)
{
    int row  = blockIdx.x * 4 + (threadIdx.x >> 6);
    int lane = threadIdx.x & 63;
    long base = (long)row * Aq;
    const long PS = (long)Nq * Aq;
    float x0 = 0.f, x1 = 0.f;
#pragma unroll
    for (int z = 0; z < 16; z++) {
        x0 += bf2f(p2b[base + z * PS + lane]);
        x1 += bf2f(p2b[base + z * PS + lane + 64]);
    }
    float s  = x0 + x1;
    float ss = x0 * x0 + x1 * x1;
#pragma unroll
    for (int off = 32; off > 0; off >>= 1) {
        s  += __shfl_xor(s, off);
        ss += __shfl_xor(ss, off);
    }
    float m  = s * (1.0f / Aq);
    float v  = ss * (1.0f / Aq) - m * m;
    float rs = rsqrtf(v + 1e-5f);
    oh[base + lane]      = f2bf((x0 - m) * rs * g[lane]      + b[lane]);
    oh[base + lane + 64] = f2bf((x1 - m) * rs * g[lane + 64] + b[lane + 64]);
}

// ---------------------------------------------------------------------------
// rlnrbf: kcat reduce (blocks 0..1023) + ain LN/transpose (1024..2047).
// (Proven r21.)
// ---------------------------------------------------------------------------
__global__ __launch_bounds__(256)
void rlnrbf(const float* __restrict__ kdp, const float* __restrict__ p1,
            unsigned short* __restrict__ kcat,
            unsigned short* __restrict__ ainh, unsigned short* __restrict__ ainT,
            const float* __restrict__ g, const float* __restrict__ b)
{
    if (blockIdx.x < 1024) {
        int i = blockIdx.x * 256 + threadIdx.x;       // < 262144
        int n = i >> 7, a = i & 127;
        int bz = n >> 10, s = n & 1023;
        long base = (long)bz * 16 * Dq * Aq + (long)s * Aq + a;
        float acc = 0.f;
#pragma unroll
        for (int z = 0; z < 16; z++) acc += kdp[base + (long)z * Dq * Aq];
        kcat[(long)s * 256 + bz * 128 + a] = f2bf(acc);
        return;
    }
    int row  = (blockIdx.x - 1024) * 4 + (threadIdx.x >> 6);
    int lane = threadIdx.x & 63;
    long base = (long)row * Aq;
    float x0 = 0.f, x1 = 0.f;
#pragma unroll
    for (int z = 0; z < 8; z++) {
        x0 += p1[base + (long)z * Nq * Aq + lane];
        x1 += p1[base + (long)z * Nq * Aq + lane + 64];
    }
    float s  = x0 + x1;
    float ss = x0 * x0 + x1 * x1;
#pragma unroll
    for (int off = 32; off > 0; off >>= 1) {
        s  += __shfl_xor(s, off);
        ss += __shfl_xor(ss, off);
    }
    float m  = s * (1.0f / Aq);
    float v  = ss * (1.0f / Aq) - m * m;
    float rs = rsqrtf(v + 1e-5f);
    unsigned short h0 = f2bf((x0 - m) * rs * g[lane]      + b[lane]);
    unsigned short h1 = f2bf((x1 - m) * rs * g[lane + 64] + b[lane + 64]);
    ainh[base + lane]      = h0;
    ainh[base + lane + 64] = h1;
    int bb2 = row >> 11, sidx = row & 2047;
    unsigned short* t = ainT + (size_t)bb2 * Sq * Aq + sidx;
    t[(size_t)lane * Sq]        = h0;
    t[(size_t)(lane + 64) * Sq] = h1;
}

// ---------------------------------------------------------------------------
// Merged tail: blocks 0..2047 = reduce(p3) -> acat cols 0..127 (scale 0.1);
// blocks 2048..3071 = mix_ln(he bf16 -> acat cols 128..255).
// ---------------------------------------------------------------------------
__global__ __launch_bounds__(256)
void tailk(const float* __restrict__ p3, const unsigned short* __restrict__ he,
           const float* __restrict__ ew, const float* __restrict__ g,
           const float* __restrict__ bb, unsigned short* __restrict__ acat)
{
    if (blockIdx.x < 2048) {
        int i = blockIdx.x * 256 + threadIdx.x;       // < 524288
        int n = i >> 7, a = i & 127;
        int bz = n >> 11, s = n & 2047;
        long base = ((long)bz * 8) * Sq * Aq + (long)s * Aq + a;
        float acc = 0.f;
#pragma unroll
        for (int z = 0; z < 8; z++) acc += p3[base + (long)z * Sq * Aq];
        acat[(long)n * 256 + a] = f2bf(acc * 0.1f);
        return;
    }
    int n    = (blockIdx.x - 2048) * 4 + (threadIdx.x >> 6);
    int lane = threadIdx.x & 63;
    float a0 = 0.0f, a1 = 0.0f;
#pragma unroll
    for (int e = 0; e < Eq; e++) {
        const unsigned short* r = he + ((long)e * Nq + n) * Aq;
        float x0 = bf2f(r[lane]), x1 = bf2f(r[lane + 64]);
        float s  = x0 + x1;
        float ss = x0 * x0 + x1 * x1;
#pragma unroll
        for (int off = 32; off > 0; off >>= 1) {
            s  += __shfl_xor(s, off);
            ss += __shfl_xor(ss, off);
        }
        float m  = s * (1.0f / Aq);
        float v  = ss * (1.0f / Aq) - m * m;
        float rs = rsqrtf(v + 1e-5f);
        float wv = ew[(long)n * Eq + e];
        a0 += wv * ((x0 - m) * rs * g[e * Aq + lane]      + bb[e * Aq + lane]);
        a1 += wv * ((x1 - m) * rs * g[e * Aq + lane + 64] + bb[e * Aq + lane + 64]);
    }
    acat[(long)n * 256 + 128 + lane]      = f2bf(a0);
    acat[(long)n * 256 + 128 + lane + 64] = f2bf(a1);
}

extern "C" void kernel_launch(void* const* d_in, const int* in_sizes, int n_in,
                              void* d_out, int out_size, void* d_ws, size_t ws_size,
                              hipStream_t stream)
{
    const float* x             = (const float*)d_in[0];
    const float* ew            = (const float*)d_in[1];
    const float* up_w          = (const float*)d_in[2];
    const float* gate_w        = (const float*)d_in[3];
    const float* down_w        = (const float*)d_in[4];
    const float* pre_w         = (const float*)d_in[5];
    const float* post_w        = (const float*)d_in[6];
    const float* an_g          = (const float*)d_in[7];
    const float* an_b          = (const float*)d_in[8];
    const float* adapt_proj_w  = (const float*)d_in[9];
    const float* adapter_w     = (const float*)d_in[10];
    const float* adapter_g     = (const float*)d_in[11];
    const float* adapter_b     = (const float*)d_in[12];
    const float* expert_proj_w = (const float*)d_in[13];
    const float* output_proj_w = (const float*)d_in[14];
    float* out = (float*)d_out;

    // ---- workspace (KB offsets; peak ~96 MB) ----
#define OFF(kb) ((char*)d_ws + (size_t)(kb) * 1024)
    float* kdp  = (float*)OFF(0);        // [2][16][D][A] 16MB (phase 1)
    float* p1   = (float*)OFF(16384);    // [8][N][A] 16MB   (phase 1)
    float* p3   = (float*)OFF(0);        // [2][8][S][A] 16MB (after kdp dead)
    unsigned short* he = (unsigned short*)OFF(16384);    // [E][N][A] bf16 8MB (after p1 dead)
    unsigned short* hh   = (unsigned short*)OFF(32768);  // [N,H] 16MB
    unsigned short* xh   = (unsigned short*)OFF(49152);  // 8MB
    unsigned short* gwh  = (unsigned short*)OFF(57344);  // 4MB
    unsigned short* uwh  = (unsigned short*)OFF(61440);  // 4MB
    unsigned short* dwh  = (unsigned short*)OFF(65536);  // 4MB
    unsigned short* oph  = (unsigned short*)OFF(69632);  // 4MB
    unsigned short* pwh  = (unsigned short*)OFF(73728);  // .25MB
    unsigned short* powh = (unsigned short*)OFF(73984);  // .5MB
    unsigned short* apT  = (unsigned short*)OFF(74496);  // .5MB } contiguous pair
    unsigned short* epT  = (unsigned short*)OFF(75008);  // .5MB }
    unsigned short* ainh = (unsigned short*)OFF(75520);  // 1MB
    unsigned short* ainT = (unsigned short*)OFF(76544);  // [B][A][S] 1MB
    unsigned short* aouth= (unsigned short*)OFF(77568);  // 1MB
    unsigned short* adw  = (unsigned short*)OFF(78592);  // .25MB
    unsigned short* kcat = (unsigned short*)OFF(78848);  // [D][256] .5MB
    unsigned short* acat = (unsigned short*)OFF(79360);  // [N][256] 2MB -> 81408
    unsigned short* p2b  = (unsigned short*)OFF(81920);  // [16][N][A] bf16 16MB -> 98304
#undef OFF
    (void)epT;

    dim3 blk(256), blk512(512);
    const long NA = (long)Nq * Aq;

    // 1. conversions + BOTH fp32 transposes in one launch (2048 + 512 blocks)
    convert_all<<<dim3(2560), blk, 0, stream>>>(x, gate_w, up_w, down_w, pre_w,
        post_w, output_proj_w, adapter_w, adapt_proj_w, expert_proj_w,
        xh, gwh, uwh, dwh, pwh, powh, oph, adw, apT);

    // 2. MERGED: kcat partials (blocks 0..255) + p1 partials (blocks 256..511)
    mgpair<<<dim3(512), blk512, 0, stream>>>(dwh, apT, kdp, xh, pwh, p1);

    // 3. MERGED: kcat reduce (blocks 0..1023) + ain LN/transpose (1024..2047)
    rlnrbf<<<dim3(2048), blk, 0, stream>>>(kdp, p1, kcat, ainh, ainT, an_g, an_b);

    // 4. expert path GEMM: he = bf16(ain @ adapter_w[e]^T)
    mg<2><<<dim3(1, 32, 8), blk512, 0, stream>>>(ainh, adw, he, Aq, Aq, 1,
        0, (long)Aq * Aq, NA, 0);

    // 5. fused SwiGLU + aout-partial epilogue: hh + p2b  (8-PHASE, 256x128)
    gup<<<dim3(16, 16), blk512, 0, stream>>>(xh, gwh, uwh, powh, hh, p2b);

    // 6. aout = LN(reduce16(p2b))   [replaces the step-6 GEMM dispatch]
    rln16b<<<dim3(1024), blk, 0, stream>>>(p2b, aouth, an_g, an_b);

    // 7. FUSED score-combine: p3 partials (no wmat)
    gsc<<<dim3(8, 16, 2), blk512, 0, stream>>>(ainh, aouth, ainT, p3);

    // 8. merged tail: acat[:,0:128] = 0.1*reduce(p3); acat[:,128:256] = mix_ln(he)
    tailk<<<dim3(3072), blk, 0, stream>>>(p3, he, ew, adapter_g, adapter_b, acat);

    // 9. out = hh@dwh^T + acat@kcat^T   (2-phase main loop)
    gfinal<<<dim3(8, 32), blk512, 0, stream>>>(hh, dwh, acat, kcat, out);
}

// Round 23
// 140.111 us; speedup vs baseline: 1.1830x; 1.0494x over previous
//
#include <hip/hip_runtime.h>
#include <hip/hip_bf16.h>
#include <math.h>

// Problem constants (B,S,D,E = 2,2048,1024,8)
#define Bq 2
#define Sq 2048
#define Dq 1024
#define Eq 8
#define Hq 2048            // 2*D
#define Aq 128             // H/16
#define Nq (Bq*Sq)         // 4096 tokens

typedef __attribute__((ext_vector_type(4))) float f32x4;
typedef __attribute__((ext_vector_type(8))) short bfrag;   // 8 bf16 in 4 VGPRs

__device__ __forceinline__ float silu_f(float x) {
    return x / (1.0f + expf(-x));
}
__device__ __forceinline__ unsigned short f2bf(float x) {  // RNE fp32->bf16
    unsigned u = __float_as_uint(x);
    u += 0x7fffu + ((u >> 16) & 1u);
    return (unsigned short)(u >> 16);
}
__device__ __forceinline__ float bf2f(unsigned short h) {
    return __uint_as_float(((unsigned)h) << 16);
}
__device__ __forceinline__ void gl16(const unsigned short* g, unsigned short* l) {
    __builtin_amdgcn_global_load_lds(
        (const __attribute__((address_space(1))) void*)g,
        (__attribute__((address_space(3))) void*)(void*)l, 16, 0, 0);
}

// Counted-vmcnt wait-then-barrier (T4). vmcnt retires IN ORDER.
#define WAITV_BAR(N)                                            \
    asm volatile("s_waitcnt vmcnt(" #N ")" ::: "memory");       \
    __builtin_amdgcn_s_barrier();                               \
    asm volatile("" ::: "memory")
#define END_BAR()                                               \
    asm volatile("" ::: "memory");                              \
    __builtin_amdgcn_s_barrier();                               \
    asm volatile("" ::: "memory")
#define WAITV(N) asm volatile("s_waitcnt vmcnt(" #N ")" ::: "memory")
#define BARF()                                                  \
    asm volatile("" ::: "memory");                              \
    __builtin_amdgcn_s_barrier();                               \
    asm volatile("" ::: "memory")

// ---------------------------------------------------------------------------
// convert_all: fp32 -> bf16 for all inputs (blocks 0..2047, grid-stride)
// PLUS the two fp32 transposes (blocks 2048..2559).
// ---------------------------------------------------------------------------
__global__ __launch_bounds__(256)
void convert_all(const float* __restrict__ x,  const float* __restrict__ gw,
                 const float* __restrict__ uw, const float* __restrict__ dw,
                 const float* __restrict__ pw, const float* __restrict__ ow,
                 const float* __restrict__ opw, const float* __restrict__ aw,
                 const float* __restrict__ apw, const float* __restrict__ epw,
                 unsigned short* xh,  unsigned short* gwh, unsigned short* uwh,
                 unsigned short* dwh, unsigned short* pwh, unsigned short* powh,
                 unsigned short* oph, unsigned short* adw, unsigned short* apT)
{
    __shared__ float t[32][33];
    if (blockIdx.x >= 2048) {
        int bid = blockIdx.x - 2048;
        int z   = bid >> 8;
        int rem = bid & 255;
        int bx  = rem & 3, by = rem >> 2;
        const float* in = z ? epw : apw;
        unsigned short* out = apT + (size_t)z * Hq * Aq;
        int tx = threadIdx.x & 31, ty = threadIdx.x >> 5;
        int r0 = by * 32, c0 = bx * 32;
#pragma unroll
        for (int j = 0; j < 4; j++)
            t[ty + j * 8][tx] = in[(size_t)(r0 + ty + j * 8) * Aq + c0 + tx];
        __syncthreads();
#pragma unroll
        for (int j = 0; j < 4; j++)
            out[(size_t)(c0 + ty + j * 8) * Hq + r0 + tx] = f2bf(t[tx][ty + j * 8]);
        return;
    }
    const int T = 3276800;
    for (int i = blockIdx.x * 256 + threadIdx.x; i < T; i += 2048 * 256) {
        const float* in; unsigned short* hi; int j = i;
        if (j < 1048576)                 { in = x;   hi = xh;  }
        else if ((j -= 1048576) < 524288){ in = gw;  hi = gwh; }
        else if ((j -= 524288) < 524288) { in = uw;  hi = uwh; }
        else if ((j -= 524288) < 524288) { in = dw;  hi = dwh; }
        else if ((j -= 524288) < 32768)  { in = pw;  hi = pwh; }
        else if ((j -= 32768) < 65536)   { in = ow;  hi = powh; }
        else if ((j -= 65536) < 524288)  { in = opw; hi = oph; }
        else { j -= 524288;                in = aw;  hi = adw; }
        float4 v = ((const float4*)in)[j];
        ((ushort4*)hi)[j] = make_ushort4(f2bf(v.x), f2bf(v.y), f2bf(v.z), f2bf(v.w));
    }
}

// ---------------------------------------------------------------------------
// mgpair: kcat partials (blocks 0..255) + p1 partials (blocks 256..511).
// (Proven r21.)
// ---------------------------------------------------------------------------
__global__ __launch_bounds__(512)
void mgpair(const unsigned short* __restrict__ dwh, const unsigned short* __restrict__ apT,
            float* __restrict__ kdp,
            const unsigned short* __restrict__ xh, const unsigned short* __restrict__ pwh,
            float* __restrict__ p1)
{
    __shared__ __align__(16) unsigned short lds[32768];

    const int tid = threadIdx.x;
    const int l   = tid & 63;
    const int w   = tid >> 6;
    const int wr  = w >> 2, wc = w & 3;

    const unsigned short *Ah, *Bh; float* Cv;
    int K, kchunks, by, zidx;
    long zA, zB, zC, pz;
    int bid = blockIdx.x;
    if (bid < 256) {
        Ah = dwh; Bh = apT; Cv = kdp; K = Hq; kchunks = 16;
        zA = (long)Dq * Hq; zB = (long)Aq * Hq; zC = (long)16 * Dq * Aq; pz = (long)Dq * Aq;
        by = bid & 7; zidx = bid >> 3;
    } else {
        int r = bid - 256;
        Ah = xh; Bh = pwh; Cv = p1; K = Dq; kchunks = 8;
        zA = 0; zB = 0; zC = 0; pz = (long)Nq * Aq;
        by = r & 31; zidx = r >> 5;
    }
    const int N = Aq;
    const int bm0 = by * 128, bn0 = 0;
    const int bz  = zidx / kchunks;
    const int kz  = zidx - bz * kchunks;
    const int kcnt = K / kchunks;
    const int kbeg = kz * kcnt;
    const int kend = kbeg + kcnt;

    const unsigned short* A0 = Ah + (size_t)bz * zA;
    const unsigned short* B0 = Bh + (size_t)bz * zB;

    const int srow = tid >> 3;
    const int sq   = (tid & 7) ^ (srow & 7);
    const size_t aoff = (size_t)(bm0 + srow) * K + sq * 8;
    const size_t boff = (size_t)(bn0 + srow) * K + sq * 8;
    const size_t r64  = (size_t)64 * K;

    auto stage = [&](int b, int kt) {
        unsigned short* d = &lds[b * 16384 + (w << 9)];
        gl16(A0 + aoff + kt,       d + 0);
        gl16(A0 + aoff + kt + r64, d + 4096);
        gl16(B0 + boff + kt,       d + 8192);
        gl16(B0 + boff + kt + r64, d + 12288);
    };

    const int rowa = (wr * 64 + (l & 15)) * 64;
    const int rowb = (wc * 32 + (l & 15)) * 64;
    const int q0 = (((l >> 4)    ) ^ (l & 7)) << 3;
    const int q1 = (((l >> 4) + 4) ^ (l & 7)) << 3;

    f32x4 acc[4][2];
#pragma unroll
    for (int i = 0; i < 4; i++)
#pragma unroll
        for (int j = 0; j < 2; j++) acc[i][j] = (f32x4){0.f, 0.f, 0.f, 0.f};

    stage(0, kbeg);
    int cur = 0;
    for (int kt = kbeg; kt < kend; kt += 64) {
        if (kt + 64 < kend) {
            stage(cur ^ 1, kt + 64);
            WAITV_BAR(4);
        } else {
            WAITV_BAR(0);
        }
        const int cb = cur * 16384;
#pragma unroll
        for (int ks = 0; ks < 2; ks++) {
            const int qo = ks ? q1 : q0;
            bfrag a4[4], b4[2];
#pragma unroll
            for (int f = 0; f < 4; f++)
                a4[f] = *(const bfrag*)&lds[cb + rowa + f * 1024 + qo];
#pragma unroll
            for (int f = 0; f < 2; f++)
                b4[f] = *(const bfrag*)&lds[cb + 8192 + rowb + f * 1024 + qo];
#pragma unroll
            for (int i = 0; i < 4; i++)
#pragma unroll
                for (int j = 0; j < 2; j++)
                    acc[i][j] = __builtin_amdgcn_mfma_f32_16x16x32_bf16(a4[i], b4[j], acc[i][j], 0, 0, 0);
        }
        END_BAR();
        cur ^= 1;
    }

    const int crow0 = bm0 + wr * 64 + (l >> 4) * 4;
    const int ccol0 = bn0 + wc * 32 + (l & 15);
    float* C = Cv + (size_t)bz * zC + (size_t)kz * pz;
#pragma unroll
    for (int i = 0; i < 4; i++)
#pragma unroll
        for (int j = 0; j < 2; j++)
#pragma unroll
            for (int r = 0; r < 4; r++)
                C[(size_t)(crow0 + i * 16 + r) * N + (ccol0 + j * 16)] = acc[i][j][r];
}

// ---------------------------------------------------------------------------
// Fused score-combine (steps 6+7, no wmat). (Proven r17.)
// ---------------------------------------------------------------------------
__global__ __launch_bounds__(512)
void gsc(const unsigned short* __restrict__ ainh, const unsigned short* __restrict__ aouth,
         const unsigned short* __restrict__ ainT, float* __restrict__ p3)
{
    __shared__ __align__(16) unsigned short lds[65536];  // 128 KB
    const int AIN = 0, AOUT = 16384, AINT = 32768, PB = 49152;

    const int tid = threadIdx.x;
    const int l   = tid & 63;
    const int w   = tid >> 6;
    const int wr  = w >> 2, wc = w & 3;
    const int tz  = blockIdx.x;        // 0..7
    const int ib  = blockIdx.y;        // 0..15
    const int b   = blockIdx.z;        // 0..1
    const long SA = (long)Sq * Aq;

    auto stage32 = [&](int base, const unsigned short* src, size_t kstride) {
#pragma unroll
        for (int rd = 0; rd < 4; rd++) {
            int grow = rd * 32 + (w << 2) + (l >> 4);
            int slot = (l & 15) ^ (grow & 15);
            gl16(src + (size_t)grow * kstride + slot * 8,
                 &lds[base + rd * 4096 + (w << 9)]);
        }
    };

    const unsigned short* ainI_src = ainh + (size_t)b * SA + (size_t)(ib * 128) * Aq;
    f32x4 acc2[4][2];
#pragma unroll
    for (int i = 0; i < 4; i++)
#pragma unroll
        for (int j = 0; j < 2; j++) acc2[i][j] = (f32x4){0.f, 0.f, 0.f, 0.f};

    {
        int tglob = tz * 2;
        stage32(AIN,  ainI_src, Aq);
        stage32(AOUT, aouth + (size_t)b * SA + (size_t)(tglob * 128) * Aq, Aq);
        stage32(AINT, ainT  + (size_t)b * SA + (size_t)(tglob * 128), Sq);
        WAITV_BAR(0);
    }

    const int rowa = (wr * 64 + (l & 15)) * 128;
    const int rowb = (wc * 32 + (l & 15)) * 128;

#pragma unroll 1
    for (int t = 0; t < 2; t++) {
        if (t == 1) {
            int tglob = tz * 2 + 1;
            stage32(AOUT, aouth + (size_t)b * SA + (size_t)(tglob * 128) * Aq, Aq);
            stage32(AINT, ainT  + (size_t)b * SA + (size_t)(tglob * 128), Sq);
            WAITV_BAR(0);
        }
        f32x4 acc1[4][2];
#pragma unroll
        for (int i = 0; i < 4; i++)
#pragma unroll
            for (int j = 0; j < 2; j++) acc1[i][j] = (f32x4){0.f, 0.f, 0.f, 0.f};
#pragma unroll
        for (int ks = 0; ks < 4; ks++) {
            const int qo = ((ks * 4 + (l >> 4)) ^ (l & 15)) << 3;
            bfrag a4[4], b4[2];
#pragma unroll
            for (int f = 0; f < 4; f++)
                a4[f] = *(const bfrag*)&lds[AIN + rowa + f * 2048 + qo];
#pragma unroll
            for (int f = 0; f < 2; f++)
                b4[f] = *(const bfrag*)&lds[AOUT + rowb + f * 2048 + qo];
#pragma unroll
            for (int i = 0; i < 4; i++)
#pragma unroll
                for (int j = 0; j < 2; j++)
                    acc1[i][j] = __builtin_amdgcn_mfma_f32_16x16x32_bf16(a4[i], b4[j], acc1[i][j], 0, 0, 0);
        }
        {
            const int prow0 = wr * 64 + (l >> 4) * 4;
            const int pcol0 = wc * 32 + (l & 15);
#pragma unroll
            for (int i = 0; i < 4; i++)
#pragma unroll
                for (int j = 0; j < 2; j++)
#pragma unroll
                    for (int r = 0; r < 4; r++) {
                        int pr = prow0 + i * 16 + r;
                        int pc = pcol0 + j * 16;
                        float v = silu_f(fminf(fmaxf(acc1[i][j][r], -5.f), 5.f));
                        lds[PB + pr * 128 + (((pc >> 3) ^ (pr & 15)) << 3) + (pc & 7)] = f2bf(v);
                    }
        }
        __syncthreads();
#pragma unroll
        for (int ks = 0; ks < 4; ks++) {
            const int qo = ((ks * 4 + (l >> 4)) ^ (l & 15)) << 3;
            bfrag a4[4], b4[2];
#pragma unroll
            for (int f = 0; f < 4; f++)
                a4[f] = *(const bfrag*)&lds[PB + rowa + f * 2048 + qo];
#pragma unroll
            for (int f = 0; f < 2; f++)
                b4[f] = *(const bfrag*)&lds[AINT + rowb + f * 2048 + qo];
#pragma unroll
            for (int i = 0; i < 4; i++)
#pragma unroll
                for (int j = 0; j < 2; j++)
                    acc2[i][j] = __builtin_amdgcn_mfma_f32_16x16x32_bf16(a4[i], b4[j], acc2[i][j], 0, 0, 0);
        }
        __syncthreads();
    }

    const int crow0 = wr * 64 + (l >> 4) * 4;
    const int ccol0 = wc * 32 + (l & 15);
    float* dst = p3 + ((size_t)(b * 8 + tz) * Sq + ib * 128) * Aq;
#pragma unroll
    for (int i = 0; i < 4; i++)
#pragma unroll
        for (int j = 0; j < 2; j++)
#pragma unroll
            for (int r = 0; r < 4; r++)
                dst[(size_t)(crow0 + i * 16 + r) * Aq + ccol0 + j * 16] = acc2[i][j][r];
}

// ---------------------------------------------------------------------------
// guphe (r23): merged launch —
//   blocks 0..255   : 8-PHASE fused SwiGLU + aout-partial epilogue (proven r22)
//   blocks 256..511 : he GEMM  he[e] = bf16(ain @ adapter_w[e]^T)  (proven mg
//                     body, K=128, 2 K-steps; e = (bid-256)>>5, by = bid&31)
// he blocks backfill CUs as gup blocks retire; one fewer dispatch.
// ---------------------------------------------------------------------------
__global__ __launch_bounds__(512)
void guphe(const unsigned short* __restrict__ xh, const unsigned short* __restrict__ gwh,
           const unsigned short* __restrict__ uwh, const unsigned short* __restrict__ powh,
           unsigned short* __restrict__ hh, unsigned short* __restrict__ p2b,
           const unsigned short* __restrict__ ainh, const unsigned short* __restrict__ adw,
           unsigned short* __restrict__ he)
{
    __shared__ __align__(16) unsigned short lds[65536];  // gup: all; he: first 32K
    const int tid = threadIdx.x;
    const int l   = tid & 63;
    const int w   = tid >> 6;

    if (blockIdx.x >= 256) {
        // ================== he path (mg<2> body) ==================
        int r   = blockIdx.x - 256;
        int by  = r & 31;
        int e   = r >> 5;
        const int wr  = w >> 2, wc = w & 3;
        const int bm0 = by * 128;
        const int K = Aq;                       // 128
        const unsigned short* A0 = ainh;
        const unsigned short* B0 = adw + (size_t)e * Aq * Aq;

        const int srow = tid >> 3;
        const int sq   = (tid & 7) ^ (srow & 7);
        const size_t aoff = (size_t)(bm0 + srow) * K + sq * 8;
        const size_t boff = (size_t)srow * K + sq * 8;
        const size_t r64  = (size_t)64 * K;

        auto stage = [&](int b, int kt) {
            unsigned short* d = &lds[b * 16384 + (w << 9)];
            gl16(A0 + aoff + kt,       d + 0);
            gl16(A0 + aoff + kt + r64, d + 4096);
            gl16(B0 + boff + kt,       d + 8192);
            gl16(B0 + boff + kt + r64, d + 12288);
        };

        const int rowa = (wr * 64 + (l & 15)) * 64;
        const int rowb = (wc * 32 + (l & 15)) * 64;
        const int q0 = (((l >> 4)    ) ^ (l & 7)) << 3;
        const int q1 = (((l >> 4) + 4) ^ (l & 7)) << 3;

        f32x4 acc[4][2];
#pragma unroll
        for (int i = 0; i < 4; i++)
#pragma unroll
            for (int j = 0; j < 2; j++) acc[i][j] = (f32x4){0.f, 0.f, 0.f, 0.f};

        stage(0, 0);
        int cur = 0;
        for (int kt = 0; kt < K; kt += 64) {
            if (kt + 64 < K) {
                stage(cur ^ 1, kt + 64);
                WAITV_BAR(4);
            } else {
                WAITV_BAR(0);
            }
            const int cb = cur * 16384;
#pragma unroll
            for (int ks = 0; ks < 2; ks++) {
                const int qo = ks ? q1 : q0;
                bfrag a4[4], b4[2];
#pragma unroll
                for (int f = 0; f < 4; f++)
                    a4[f] = *(const bfrag*)&lds[cb + rowa + f * 1024 + qo];
#pragma unroll
                for (int f = 0; f < 2; f++)
                    b4[f] = *(const bfrag*)&lds[cb + 8192 + rowb + f * 1024 + qo];
#pragma unroll
                for (int i = 0; i < 4; i++)
#pragma unroll
                    for (int j = 0; j < 2; j++)
                        acc[i][j] = __builtin_amdgcn_mfma_f32_16x16x32_bf16(a4[i], b4[j], acc[i][j], 0, 0, 0);
            }
            END_BAR();
            cur ^= 1;
        }

        const int crow0 = bm0 + wr * 64 + (l >> 4) * 4;
        const int ccol0 = wc * 32 + (l & 15);
        unsigned short* C = he + (size_t)e * Nq * Aq;
#pragma unroll
        for (int i = 0; i < 4; i++)
#pragma unroll
            for (int j = 0; j < 2; j++)
#pragma unroll
                for (int r2 = 0; r2 < 4; r2++)
                    C[(size_t)(crow0 + i * 16 + r2) * Aq + (ccol0 + j * 16)] =
                        f2bf(acc[i][j][r2]);
        return;
    }

    // ================== gup path (proven r22) ==================
    const int wr  = w >> 2;
    const int wc  = w & 3;
    int id  = blockIdx.x;                              // 0..255
    int xcd = id & 7, j0 = id >> 3;
    int bx  = (xcd & 3) * 4 + (j0 & 3);
    int by  = (xcd >> 2) * 8 + (j0 >> 2);
    const int bm0 = by * 256, bn0 = bx * 128;

    const int srw = tid >> 3;
    const int sq  = (tid & 7) ^ (srw & 7);
    auto stageU = [&](int b, int u, int kt) {
        unsigned short* d = &lds[b * 32768 + u * 8192 + (tid << 3)];
        const unsigned short* src = (u < 2) ? xh : (u == 2 ? gwh : uwh);
        int baserow = (u < 2) ? (bm0 + u * 128) : bn0;
        size_t o = (size_t)(baserow + srw) * Dq + kt + sq * 8;
        gl16(src + o,                   d);
        gl16(src + o + (size_t)64 * Dq, d + 4096);
    };

    const int rowa = (wr * 128 + (l & 15)) * 64;
    const int rowb = (wc * 32  + (l & 15)) * 64;
    const int q0 = (((l >> 4)    ) ^ (l & 7)) << 3;
    const int q1 = (((l >> 4) + 4) ^ (l & 7)) << 3;

    f32x4 accg[8][2], accu[8][2];
#pragma unroll
    for (int i = 0; i < 8; i++)
#pragma unroll
        for (int jj = 0; jj < 2; jj++) {
            accg[i][jj] = (f32x4){0.f, 0.f, 0.f, 0.f};
            accu[i][jj] = (f32x4){0.f, 0.f, 0.f, 0.f};
        }

    stageU(0, 0, 0); stageU(0, 1, 0); stageU(0, 2, 0); stageU(0, 3, 0);
    int cur = 0;
    for (int kt = 0; kt < Dq; kt += 64) {
        const int pf = (kt + 64 < Dq);
        const int cb = cur * 32768;
        const int nx = cur ^ 1;
        bfrag a4[8], b4[2];

        // ---- phase 0: ks0 gate ----
        WAITV(2);
        BARF();
#pragma unroll
        for (int f = 0; f < 8; f++)
            a4[f] = *(const bfrag*)&lds[cb + rowa + f * 1024 + q0];
#pragma unroll
        for (int f = 0; f < 2; f++)
            b4[f] = *(const bfrag*)&lds[cb + 16384 + rowb + f * 1024 + q0];
        if (pf) stageU(nx, 0, kt + 64);
        __builtin_amdgcn_s_setprio(1);
#pragma unroll
        for (int i = 0; i < 8; i++)
#pragma unroll
            for (int jj = 0; jj < 2; jj++)
                accg[i][jj] = __builtin_amdgcn_mfma_f32_16x16x32_bf16(a4[i], b4[jj], accg[i][jj], 0, 0, 0);
        __builtin_amdgcn_s_setprio(0);

        // ---- phase 1: ks0 up ----
        if (pf) { WAITV(2); } else { WAITV(0); }
        BARF();
#pragma unroll
        for (int f = 0; f < 2; f++)
            b4[f] = *(const bfrag*)&lds[cb + 24576 + rowb + f * 1024 + q0];
        if (pf) stageU(nx, 1, kt + 64);
        __builtin_amdgcn_s_setprio(1);
#pragma unroll
        for (int i = 0; i < 8; i++)
#pragma unroll
            for (int jj = 0; jj < 2; jj++)
                accu[i][jj] = __builtin_amdgcn_mfma_f32_16x16x32_bf16(a4[i], b4[jj], accu[i][jj], 0, 0, 0);
        __builtin_amdgcn_s_setprio(0);

        // ---- phase 2: ks1 gate ----
        BARF();
#pragma unroll
        for (int f = 0; f < 8; f++)
            a4[f] = *(const bfrag*)&lds[cb + rowa + f * 1024 + q1];
#pragma unroll
        for (int f = 0; f < 2; f++)
            b4[f] = *(const bfrag*)&lds[cb + 16384 + rowb + f * 1024 + q1];
        if (pf) stageU(nx, 2, kt + 64);
        __builtin_amdgcn_s_setprio(1);
#pragma unroll
        for (int i = 0; i < 8; i++)
#pragma unroll
            for (int jj = 0; jj < 2; jj++)
                accg[i][jj] = __builtin_amdgcn_mfma_f32_16x16x32_bf16(a4[i], b4[jj], accg[i][jj], 0, 0, 0);
        __builtin_amdgcn_s_setprio(0);

        // ---- phase 3: ks1 up ----
        BARF();
#pragma unroll
        for (int f = 0; f < 2; f++)
            b4[f] = *(const bfrag*)&lds[cb + 24576 + rowb + f * 1024 + q1];
        if (pf) stageU(nx, 3, kt + 64);
        __builtin_amdgcn_s_setprio(1);
#pragma unroll
        for (int i = 0; i < 8; i++)
#pragma unroll
            for (int jj = 0; jj < 2; jj++)
                accu[i][jj] = __builtin_amdgcn_mfma_f32_16x16x32_bf16(a4[i], b4[jj], accu[i][jj], 0, 0, 0);
        __builtin_amdgcn_s_setprio(0);

        cur = nx;
    }

    // ---- fused epilogue (proven r22) ----
    END_BAR();
#pragma unroll
    for (int rd = 0; rd < 4; rd++) {
        int grow = rd * 32 + (w << 2) + (l >> 4);
        int slot = (l & 15) ^ (grow & 15);
        gl16(powh + (size_t)grow * Hq + bn0 + slot * 8,
             &lds[32768 + rd * 4096 + (tid << 3)]);
    }
    const int crow0 = bm0 + wr * 128 + (l >> 4) * 4;
    const int ccol0 = bn0 + wc * 32 + (l & 15);
    const int lrow0 = wr * 128 + (l >> 4) * 4;
    const int lcol0 = wc * 32 + (l & 15);
#pragma unroll
    for (int i = 0; i < 8; i++)
#pragma unroll
        for (int jj = 0; jj < 2; jj++)
#pragma unroll
            for (int r2 = 0; r2 < 4; r2++) {
                float hv = silu_f(accg[i][jj][r2]) * accu[i][jj][r2];
                unsigned short hb = f2bf(hv);
                hh[(size_t)(crow0 + i * 16 + r2) * Hq + (ccol0 + jj * 16)] = hb;
                int pr = lrow0 + i * 16 + r2;
                int pc = lcol0 + jj * 16;
                lds[pr * 128 + (((pc >> 3) ^ (pr & 15)) << 3) + (pc & 7)] = hb;
            }
    __syncthreads();
    f32x4 acc2[8][2];
#pragma unroll
    for (int i = 0; i < 8; i++)
#pragma unroll
        for (int jj = 0; jj < 2; jj++) acc2[i][jj] = (f32x4){0.f, 0.f, 0.f, 0.f};
    const int rowa2 = (wr * 128 + (l & 15)) * 128;
    const int rowb2 = 32768 + (wc * 32 + (l & 15)) * 128;
#pragma unroll
    for (int ks = 0; ks < 4; ks++) {
        const int qo = ((ks * 4 + (l >> 4)) ^ (l & 15)) << 3;
        bfrag a4[8], b4[2];
#pragma unroll
        for (int f = 0; f < 8; f++)
            a4[f] = *(const bfrag*)&lds[rowa2 + f * 2048 + qo];
#pragma unroll
        for (int f = 0; f < 2; f++)
            b4[f] = *(const bfrag*)&lds[rowb2 + f * 2048 + qo];
#pragma unroll
        for (int i = 0; i < 8; i++)
#pragma unroll
            for (int jj = 0; jj < 2; jj++)
                acc2[i][jj] = __builtin_amdgcn_mfma_f32_16x16x32_bf16(a4[i], b4[jj], acc2[i][jj], 0, 0, 0);
    }
    unsigned short* dst = p2b + (size_t)bx * Nq * Aq;
#pragma unroll
    for (int i = 0; i < 8; i++)
#pragma unroll
        for (int jj = 0; jj < 2; jj++)
#pragma unroll
            for (int r2 = 0; r2 < 4; r2++)
                dst[(size_t)(crow0 + i * 16 + r2) * Aq + (wc * 32 + jj * 16 + (l & 15))] =
                    f2bf(acc2[i][jj][r2]);
}

// ---------------------------------------------------------------------------
// Final fused GEMM, BK=64, 8 waves (2Mx4N), 3-deep ring, 2-phase main loop.
// (Proven r21.)  out[4096][1024] = hh@dwh^T (K=2048) + acat@kcat^T (K=256)
// ---------------------------------------------------------------------------
__global__ __launch_bounds__(512)
void gfinal(const unsigned short* __restrict__ hh, const unsigned short* __restrict__ dwh,
            const unsigned short* __restrict__ acat, const unsigned short* __restrict__ kcat,
            float* __restrict__ out)
{
    __shared__ __align__(16) unsigned short lds[49152];  // 3 bufs x 16384
    const int tid = threadIdx.x;
    const int l   = tid & 63;
    const int w   = tid >> 6;
    const int wr  = w >> 2, wc = w & 3;

    int nb  = gridDim.x * gridDim.y;                      // 256
    int id  = blockIdx.y * gridDim.x + blockIdx.x;
    int id2 = (id & 7) * (nb >> 3) + (id >> 3);
    int bx  = id2 % gridDim.x, by = id2 / gridDim.x;
    const int bm0 = by * 128, bn0 = bx * 128;

    const int srow = tid >> 3;
    const int sq   = (tid & 7) ^ (srow & 7);
    const int rowa = (wr * 64 + (l & 15)) * 64;
    const int rowb = (wc * 32 + (l & 15)) * 64;
    const int q0 = (((l >> 4)    ) ^ (l & 7)) << 3;
    const int q1 = (((l >> 4) + 4) ^ (l & 7)) << 3;

    f32x4 acc[4][2];
#pragma unroll
    for (int i = 0; i < 4; i++)
#pragma unroll
        for (int j = 0; j < 2; j++) acc[i][j] = (f32x4){0.f, 0.f, 0.f, 0.f};

    // ---- main: K=2048, 3-deep ring, 2-phase ----
    {
        const size_t aoff = (size_t)(bm0 + srow) * Hq + sq * 8;
        const size_t boff = (size_t)(bn0 + srow) * Hq + sq * 8;
        const size_t r64  = (size_t)64 * Hq;
        auto stageA = [&](int b, int kt) {
            unsigned short* d = &lds[b * 16384 + (w << 9)];
            gl16(hh + aoff + kt,       d + 0);
            gl16(hh + aoff + kt + r64, d + 4096);
        };
        auto stageB = [&](int b, int kt) {
            unsigned short* d = &lds[b * 16384 + (w << 9)];
            gl16(dwh + boff + kt,       d + 8192);
            gl16(dwh + boff + kt + r64, d + 12288);
        };
        stageA(0, 0);  stageB(0, 0);
        stageA(1, 64); stageB(1, 64);
        int cur = 0;
        for (int kt = 0; kt < Hq; kt += 64) {
            if (kt + 64 < Hq) { WAITV_BAR(4); } else { WAITV_BAR(0); }
            const int pf  = (kt + 128 < Hq);
            const int nb3 = (cur + 2 >= 3) ? cur - 1 : cur + 2;
            const int cb  = cur * 16384;
            bfrag a4[4], b4[2];
            // ---- phase 0: ks0 ----
#pragma unroll
            for (int f = 0; f < 4; f++)
                a4[f] = *(const bfrag*)&lds[cb + rowa + f * 1024 + q0];
#pragma unroll
            for (int f = 0; f < 2; f++)
                b4[f] = *(const bfrag*)&lds[cb + 8192 + rowb + f * 1024 + q0];
            if (pf) stageA(nb3, kt + 128);
            __builtin_amdgcn_s_setprio(1);
#pragma unroll
            for (int i = 0; i < 4; i++)
#pragma unroll
                for (int j = 0; j < 2; j++)
                    acc[i][j] = __builtin_amdgcn_mfma_f32_16x16x32_bf16(a4[i], b4[j], acc[i][j], 0, 0, 0);
            __builtin_amdgcn_s_setprio(0);
            BARF();
            // ---- phase 1: ks1 ----
#pragma unroll
            for (int f = 0; f < 4; f++)
                a4[f] = *(const bfrag*)&lds[cb + rowa + f * 1024 + q1];
#pragma unroll
            for (int f = 0; f < 2; f++)
                b4[f] = *(const bfrag*)&lds[cb + 8192 + rowb + f * 1024 + q1];
            if (pf) stageB(nb3, kt + 128);
            __builtin_amdgcn_s_setprio(1);
#pragma unroll
            for (int i = 0; i < 4; i++)
#pragma unroll
                for (int j = 0; j < 2; j++)
                    acc[i][j] = __builtin_amdgcn_mfma_f32_16x16x32_bf16(a4[i], b4[j], acc[i][j], 0, 0, 0);
            __builtin_amdgcn_s_setprio(0);
            cur = (cur == 2) ? 0 : cur + 1;
        }
    }
    END_BAR();
    // ---- tail: K=256 over [acat | kcat], 3-deep (4 iters) ----
    {
        const size_t aoff = (size_t)(bm0 + srow) * 256 + sq * 8;
        const size_t boff = (size_t)(bn0 + srow) * 256 + sq * 8;
        const size_t r64  = (size_t)64 * 256;
        auto stage2 = [&](int b, int kt) {
            unsigned short* d = &lds[b * 16384 + (w << 9)];
            gl16(acat + aoff + kt,       d + 0);
            gl16(acat + aoff + kt + r64, d + 4096);
            gl16(kcat + boff + kt,       d + 8192);
            gl16(kcat + boff + kt + r64, d + 12288);
        };
        stage2(0, 0);
        stage2(1, 64);
        int cur = 0;
        for (int kt = 0; kt < 256; kt += 64) {
            if (kt + 64 < 256) { WAITV_BAR(4); } else { WAITV_BAR(0); }
            if (kt + 128 < 256) {
                int nb3 = (cur + 2 >= 3) ? cur - 1 : cur + 2;
                stage2(nb3, kt + 128);
            }
            const int cb = cur * 16384;
#pragma unroll
            for (int ks = 0; ks < 2; ks++) {
                const int qo = ks ? q1 : q0;
                bfrag a4[4], b4[2];
#pragma unroll
                for (int f = 0; f < 4; f++)
                    a4[f] = *(const bfrag*)&lds[cb + rowa + f * 1024 + qo];
#pragma unroll
                for (int f = 0; f < 2; f++)
                    b4[f] = *(const bfrag*)&lds[cb + 8192 + rowb + f * 1024 + qo];
#pragma unroll
                for (int i = 0; i < 4; i++)
#pragma unroll
                    for (int j = 0; j < 2; j++)
                        acc[i][j] = __builtin_amdgcn_mfma_f32_16x16x32_bf16(a4[i], b4[j], acc[i][j], 0, 0, 0);
            }
            cur = (cur == 2) ? 0 : cur + 1;
        }
    }

    const int crow0 = bm0 + wr * 64 + (l >> 4) * 4;
    const int ccol0 = bn0 + wc * 32 + (l & 15);
#pragma unroll
    for (int i = 0; i < 4; i++)
#pragma unroll
        for (int j = 0; j < 2; j++)
#pragma unroll
            for (int r = 0; r < 4; r++)
                out[(size_t)(crow0 + i * 16 + r) * Dq + ccol0 + j * 16] = acc[i][j][r];
}

// ---------------------------------------------------------------------------
// rln16b: reduce 16 bf16 aout-partials (p2b from gup) + LayerNorm. (Proven r22.)
// ---------------------------------------------------------------------------
__global__ __launch_bounds__(256)
void rln16b(const unsigned short* __restrict__ p2b, unsigned short* __restrict__ oh,
            const float* __restrict__ g, const float* __restrict__ b)
{
    int row  = blockIdx.x * 4 + (threadIdx.x >> 6);
    int lane = threadIdx.x & 63;
    long base = (long)row * Aq;
    const long PS = (long)Nq * Aq;
    float x0 = 0.f, x1 = 0.f;
#pragma unroll
    for (int z = 0; z < 16; z++) {
        x0 += bf2f(p2b[base + z * PS + lane]);
        x1 += bf2f(p2b[base + z * PS + lane + 64]);
    }
    float s  = x0 + x1;
    float ss = x0 * x0 + x1 * x1;
#pragma unroll
    for (int off = 32; off > 0; off >>= 1) {
        s  += __shfl_xor(s, off);
        ss += __shfl_xor(ss, off);
    }
    float m  = s * (1.0f / Aq);
    float v  = ss * (1.0f / Aq) - m * m;
    float rs = rsqrtf(v + 1e-5f);
    oh[base + lane]      = f2bf((x0 - m) * rs * g[lane]      + b[lane]);
    oh[base + lane + 64] = f2bf((x1 - m) * rs * g[lane + 64] + b[lane + 64]);
}

// ---------------------------------------------------------------------------
// rlnrbf: kcat reduce (blocks 0..1023) + ain LN/transpose (1024..2047).
// (Proven r21.)
// ---------------------------------------------------------------------------
__global__ __launch_bounds__(256)
void rlnrbf(const float* __restrict__ kdp, const float* __restrict__ p1,
            unsigned short* __restrict__ kcat,
            unsigned short* __restrict__ ainh, unsigned short* __restrict__ ainT,
            const float* __restrict__ g, const float* __restrict__ b)
{
    if (blockIdx.x < 1024) {
        int i = blockIdx.x * 256 + threadIdx.x;       // < 262144
        int n = i >> 7, a = i & 127;
        int bz = n >> 10, s = n & 1023;
        long base = (long)bz * 16 * Dq * Aq + (long)s * Aq + a;
        float acc = 0.f;
#pragma unroll
        for (int z = 0; z < 16; z++) acc += kdp[base + (long)z * Dq * Aq];
        kcat[(long)s * 256 + bz * 128 + a] = f2bf(acc);
        return;
    }
    int row  = (blockIdx.x - 1024) * 4 + (threadIdx.x >> 6);
    int lane = threadIdx.x & 63;
    long base = (long)row * Aq;
    float x0 = 0.f, x1 = 0.f;
#pragma unroll
    for (int z = 0; z < 8; z++) {
        x0 += p1[base + (long)z * Nq * Aq + lane];
        x1 += p1[base + (long)z * Nq * Aq + lane + 64];
    }
    float s  = x0 + x1;
    float ss = x0 * x0 + x1 * x1;
#pragma unroll
    for (int off = 32; off > 0; off >>= 1) {
        s  += __shfl_xor(s, off);
        ss += __shfl_xor(ss, off);
    }
    float m  = s * (1.0f / Aq);
    float v  = ss * (1.0f / Aq) - m * m;
    float rs = rsqrtf(v + 1e-5f);
    unsigned short h0 = f2bf((x0 - m) * rs * g[lane]      + b[lane]);
    unsigned short h1 = f2bf((x1 - m) * rs * g[lane + 64] + b[lane + 64]);
    ainh[base + lane]      = h0;
    ainh[base + lane + 64] = h1;
    int bb2 = row >> 11, sidx = row & 2047;
    unsigned short* t = ainT + (size_t)bb2 * Sq * Aq + sidx;
    t[(size_t)lane * Sq]        = h0;
    t[(size_t)(lane + 64) * Sq] = h1;
}

// ---------------------------------------------------------------------------
// Merged tail: blocks 0..2047 = reduce(p3) -> acat cols 0..127 (scale 0.1);
// blocks 2048..3071 = mix_ln(he bf16 -> acat cols 128..255).
// ---------------------------------------------------------------------------
__global__ __launch_bounds__(256)
void tailk(const float* __restrict__ p3, const unsigned short* __restrict__ he,
           const float* __restrict__ ew, const float* __restrict__ g,
           const float* __restrict__ bb, unsigned short* __restrict__ acat)
{
    if (blockIdx.x < 2048) {
        int i = blockIdx.x * 256 + threadIdx.x;       // < 524288
        int n = i >> 7, a = i & 127;
        int bz = n >> 11, s = n & 2047;
        long base = ((long)bz * 8) * Sq * Aq + (long)s * Aq + a;
        float acc = 0.f;
#pragma unroll
        for (int z = 0; z < 8; z++) acc += p3[base + (long)z * Sq * Aq];
        acat[(long)n * 256 + a] = f2bf(acc * 0.1f);
        return;
    }
    int n    = (blockIdx.x - 2048) * 4 + (threadIdx.x >> 6);
    int lane = threadIdx.x & 63;
    float a0 = 0.0f, a1 = 0.0f;
#pragma unroll
    for (int e = 0; e < Eq; e++) {
        const unsigned short* r = he + ((long)e * Nq + n) * Aq;
        float x0 = bf2f(r[lane]), x1 = bf2f(r[lane + 64]);
        float s  = x0 + x1;
        float ss = x0 * x0 + x1 * x1;
#pragma unroll
        for (int off = 32; off > 0; off >>= 1) {
            s  += __shfl_xor(s, off);
            ss += __shfl_xor(ss, off);
        }
        float m  = s * (1.0f / Aq);
        float v  = ss * (1.0f / Aq) - m * m;
        float rs = rsqrtf(v + 1e-5f);
        float wv = ew[(long)n * Eq + e];
        a0 += wv * ((x0 - m) * rs * g[e * Aq + lane]      + bb[e * Aq + lane]);
        a1 += wv * ((x1 - m) * rs * g[e * Aq + lane + 64] + bb[e * Aq + lane + 64]);
    }
    acat[(long)n * 256 + 128 + lane]      = f2bf(a0);
    acat[(long)n * 256 + 128 + lane + 64] = f2bf(a1);
}

extern "C" void kernel_launch(void* const* d_in, const int* in_sizes, int n_in,
                              void* d_out, int out_size, void* d_ws, size_t ws_size,
                              hipStream_t stream)
{
    const float* x             = (const float*)d_in[0];
    const float* ew            = (const float*)d_in[1];
    const float* up_w          = (const float*)d_in[2];
    const float* gate_w        = (const float*)d_in[3];
    const float* down_w        = (const float*)d_in[4];
    const float* pre_w         = (const float*)d_in[5];
    const float* post_w        = (const float*)d_in[6];
    const float* an_g          = (const float*)d_in[7];
    const float* an_b          = (const float*)d_in[8];
    const float* adapt_proj_w  = (const float*)d_in[9];
    const float* adapter_w     = (const float*)d_in[10];
    const float* adapter_g     = (const float*)d_in[11];
    const float* adapter_b     = (const float*)d_in[12];
    const float* expert_proj_w = (const float*)d_in[13];
    const float* output_proj_w = (const float*)d_in[14];
    float* out = (float*)d_out;

    // ---- workspace (KB offsets; peak ~96 MB) ----
#define OFF(kb) ((char*)d_ws + (size_t)(kb) * 1024)
    float* kdp  = (float*)OFF(0);        // [2][16][D][A] 16MB (phase 1)
    float* p1   = (float*)OFF(16384);    // [8][N][A] 16MB   (phase 1)
    float* p3   = (float*)OFF(0);        // [2][8][S][A] 16MB (after kdp dead)
    unsigned short* he = (unsigned short*)OFF(16384);    // [E][N][A] bf16 8MB (after p1 dead)
    unsigned short* hh   = (unsigned short*)OFF(32768);  // [N,H] 16MB
    unsigned short* xh   = (unsigned short*)OFF(49152);  // 8MB
    unsigned short* gwh  = (unsigned short*)OFF(57344);  // 4MB
    unsigned short* uwh  = (unsigned short*)OFF(61440);  // 4MB
    unsigned short* dwh  = (unsigned short*)OFF(65536);  // 4MB
    unsigned short* oph  = (unsigned short*)OFF(69632);  // 4MB
    unsigned short* pwh  = (unsigned short*)OFF(73728);  // .25MB
    unsigned short* powh = (unsigned short*)OFF(73984);  // .5MB
    unsigned short* apT  = (unsigned short*)OFF(74496);  // .5MB } contiguous pair
    unsigned short* epT  = (unsigned short*)OFF(75008);  // .5MB }
    unsigned short* ainh = (unsigned short*)OFF(75520);  // 1MB
    unsigned short* ainT = (unsigned short*)OFF(76544);  // [B][A][S] 1MB
    unsigned short* aouth= (unsigned short*)OFF(77568);  // 1MB
    unsigned short* adw  = (unsigned short*)OFF(78592);  // .25MB
    unsigned short* kcat = (unsigned short*)OFF(78848);  // [D][256] .5MB
    unsigned short* acat = (unsigned short*)OFF(79360);  // [N][256] 2MB -> 81408
    unsigned short* p2b  = (unsigned short*)OFF(81920);  // [16][N][A] bf16 16MB -> 98304
#undef OFF
    (void)epT;

    dim3 blk(256), blk512(512);

    // 1. conversions + BOTH fp32 transposes in one launch (2048 + 512 blocks)
    convert_all<<<dim3(2560), blk, 0, stream>>>(x, gate_w, up_w, down_w, pre_w,
        post_w, output_proj_w, adapter_w, adapt_proj_w, expert_proj_w,
        xh, gwh, uwh, dwh, pwh, powh, oph, adw, apT);

    // 2. MERGED: kcat partials (blocks 0..255) + p1 partials (blocks 256..511)
    mgpair<<<dim3(512), blk512, 0, stream>>>(dwh, apT, kdp, xh, pwh, p1);

    // 3. MERGED: kcat reduce (blocks 0..1023) + ain LN/transpose (1024..2047)
    rlnrbf<<<dim3(2048), blk, 0, stream>>>(kdp, p1, kcat, ainh, ainT, an_g, an_b);

    // 4. MERGED: fused SwiGLU + aout-partial epilogue (blocks 0..255) +
    //    he GEMM (blocks 256..511)
    guphe<<<dim3(512), blk512, 0, stream>>>(xh, gwh, uwh, powh, hh, p2b,
        ainh, adw, he);

    // 5. aout = LN(reduce16(p2b))
    rln16b<<<dim3(1024), blk, 0, stream>>>(p2b, aouth, an_g, an_b);

    // 6. FUSED score-combine: p3 partials (no wmat)
    gsc<<<dim3(8, 16, 2), blk512, 0, stream>>>(ainh, aouth, ainT, p3);

    // 7. merged tail: acat[:,0:128] = 0.1*reduce(p3); acat[:,128:256] = mix_ln(he)
    tailk<<<dim3(3072), blk, 0, stream>>>(p3, he, ew, adapter_g, adapter_b, acat);

    // 8. out = hh@dwh^T + acat@kcat^T   (2-phase main loop)
    gfinal<<<dim3(8, 32), blk512, 0, stream>>>(hh, dwh, acat, kcat, out);
}

// Round 24
// 134.057 us; speedup vs baseline: 1.2364x; 1.0452x over previous
//
#include <hip/hip_runtime.h>
#include <hip/hip_bf16.h>
#include <math.h>

// Problem constants (B,S,D,E = 2,2048,1024,8)
#define Bq 2
#define Sq 2048
#define Dq 1024
#define Eq 8
#define Hq 2048            // 2*D
#define Aq 128             // H/16
#define Nq (Bq*Sq)         // 4096 tokens

typedef __attribute__((ext_vector_type(4))) float f32x4;
typedef __attribute__((ext_vector_type(8))) short bfrag;   // 8 bf16 in 4 VGPRs

__device__ __forceinline__ float silu_f(float x) {
    return x / (1.0f + expf(-x));
}
__device__ __forceinline__ unsigned short f2bf(float x) {  // RNE fp32->bf16
    unsigned u = __float_as_uint(x);
    u += 0x7fffu + ((u >> 16) & 1u);
    return (unsigned short)(u >> 16);
}
__device__ __forceinline__ float bf2f(unsigned short h) {
    return __uint_as_float(((unsigned)h) << 16);
}
__device__ __forceinline__ void gl16(const unsigned short* g, unsigned short* l) {
    __builtin_amdgcn_global_load_lds(
        (const __attribute__((address_space(1))) void*)g,
        (__attribute__((address_space(3))) void*)(void*)l, 16, 0, 0);
}

// Counted-vmcnt wait-then-barrier (T4). vmcnt retires IN ORDER.
#define WAITV_BAR(N)                                            \
    asm volatile("s_waitcnt vmcnt(" #N ")" ::: "memory");       \
    __builtin_amdgcn_s_barrier();                               \
    asm volatile("" ::: "memory")
#define END_BAR()                                               \
    asm volatile("" ::: "memory");                              \
    __builtin_amdgcn_s_barrier();                               \
    asm volatile("" ::: "memory")
#define WAITV(N) asm volatile("s_waitcnt vmcnt(" #N ")" ::: "memory")
#define BARF()                                                  \
    asm volatile("" ::: "memory");                              \
    __builtin_amdgcn_s_barrier();                               \
    asm volatile("" ::: "memory")

// ---------------------------------------------------------------------------
// convert_all: fp32 -> bf16 for all inputs (blocks 0..2047, grid-stride)
// PLUS the two fp32 transposes (blocks 2048..2559).
// ---------------------------------------------------------------------------
__global__ __launch_bounds__(256)
void convert_all(const float* __restrict__ x,  const float* __restrict__ gw,
                 const float* __restrict__ uw, const float* __restrict__ dw,
                 const float* __restrict__ pw, const float* __restrict__ ow,
                 const float* __restrict__ opw, const float* __restrict__ aw,
                 const float* __restrict__ apw, const float* __restrict__ epw,
                 unsigned short* xh,  unsigned short* gwh, unsigned short* uwh,
                 unsigned short* dwh, unsigned short* pwh, unsigned short* powh,
                 unsigned short* oph, unsigned short* adw, unsigned short* apT)
{
    __shared__ float t[32][33];
    if (blockIdx.x >= 2048) {
        int bid = blockIdx.x - 2048;
        int z   = bid >> 8;
        int rem = bid & 255;
        int bx  = rem & 3, by = rem >> 2;
        const float* in = z ? epw : apw;
        unsigned short* out = apT + (size_t)z * Hq * Aq;
        int tx = threadIdx.x & 31, ty = threadIdx.x >> 5;
        int r0 = by * 32, c0 = bx * 32;
#pragma unroll
        for (int j = 0; j < 4; j++)
            t[ty + j * 8][tx] = in[(size_t)(r0 + ty + j * 8) * Aq + c0 + tx];
        __syncthreads();
#pragma unroll
        for (int j = 0; j < 4; j++)
            out[(size_t)(c0 + ty + j * 8) * Hq + r0 + tx] = f2bf(t[tx][ty + j * 8]);
        return;
    }
    const int T = 3276800;
    for (int i = blockIdx.x * 256 + threadIdx.x; i < T; i += 2048 * 256) {
        const float* in; unsigned short* hi; int j = i;
        if (j < 1048576)                 { in = x;   hi = xh;  }
        else if ((j -= 1048576) < 524288){ in = gw;  hi = gwh; }
        else if ((j -= 524288) < 524288) { in = uw;  hi = uwh; }
        else if ((j -= 524288) < 524288) { in = dw;  hi = dwh; }
        else if ((j -= 524288) < 32768)  { in = pw;  hi = pwh; }
        else if ((j -= 32768) < 65536)   { in = ow;  hi = powh; }
        else if ((j -= 65536) < 524288)  { in = opw; hi = oph; }
        else { j -= 524288;                in = aw;  hi = adw; }
        float4 v = ((const float4*)in)[j];
        ((ushort4*)hi)[j] = make_ushort4(f2bf(v.x), f2bf(v.y), f2bf(v.z), f2bf(v.w));
    }
}

// ---------------------------------------------------------------------------
// mgpair: kcat partials (blocks 0..255) + p1 partials (blocks 256..511).
// (Proven r21.)
// ---------------------------------------------------------------------------
__global__ __launch_bounds__(512)
void mgpair(const unsigned short* __restrict__ dwh, const unsigned short* __restrict__ apT,
            float* __restrict__ kdp,
            const unsigned short* __restrict__ xh, const unsigned short* __restrict__ pwh,
            float* __restrict__ p1)
{
    __shared__ __align__(16) unsigned short lds[32768];

    const int tid = threadIdx.x;
    const int l   = tid & 63;
    const int w   = tid >> 6;
    const int wr  = w >> 2, wc = w & 3;

    const unsigned short *Ah, *Bh; float* Cv;
    int K, kchunks, by, zidx;
    long zA, zB, zC, pz;
    int bid = blockIdx.x;
    if (bid < 256) {
        Ah = dwh; Bh = apT; Cv = kdp; K = Hq; kchunks = 16;
        zA = (long)Dq * Hq; zB = (long)Aq * Hq; zC = (long)16 * Dq * Aq; pz = (long)Dq * Aq;
        by = bid & 7; zidx = bid >> 3;
    } else {
        int r = bid - 256;
        Ah = xh; Bh = pwh; Cv = p1; K = Dq; kchunks = 8;
        zA = 0; zB = 0; zC = 0; pz = (long)Nq * Aq;
        by = r & 31; zidx = r >> 5;
    }
    const int N = Aq;
    const int bm0 = by * 128, bn0 = 0;
    const int bz  = zidx / kchunks;
    const int kz  = zidx - bz * kchunks;
    const int kcnt = K / kchunks;
    const int kbeg = kz * kcnt;
    const int kend = kbeg + kcnt;

    const unsigned short* A0 = Ah + (size_t)bz * zA;
    const unsigned short* B0 = Bh + (size_t)bz * zB;

    const int srow = tid >> 3;
    const int sq   = (tid & 7) ^ (srow & 7);
    const size_t aoff = (size_t)(bm0 + srow) * K + sq * 8;
    const size_t boff = (size_t)(bn0 + srow) * K + sq * 8;
    const size_t r64  = (size_t)64 * K;

    auto stage = [&](int b, int kt) {
        unsigned short* d = &lds[b * 16384 + (w << 9)];
        gl16(A0 + aoff + kt,       d + 0);
        gl16(A0 + aoff + kt + r64, d + 4096);
        gl16(B0 + boff + kt,       d + 8192);
        gl16(B0 + boff + kt + r64, d + 12288);
    };

    const int rowa = (wr * 64 + (l & 15)) * 64;
    const int rowb = (wc * 32 + (l & 15)) * 64;
    const int q0 = (((l >> 4)    ) ^ (l & 7)) << 3;
    const int q1 = (((l >> 4) + 4) ^ (l & 7)) << 3;

    f32x4 acc[4][2];
#pragma unroll
    for (int i = 0; i < 4; i++)
#pragma unroll
        for (int j = 0; j < 2; j++) acc[i][j] = (f32x4){0.f, 0.f, 0.f, 0.f};

    stage(0, kbeg);
    int cur = 0;
    for (int kt = kbeg; kt < kend; kt += 64) {
        if (kt + 64 < kend) {
            stage(cur ^ 1, kt + 64);
            WAITV_BAR(4);
        } else {
            WAITV_BAR(0);
        }
        const int cb = cur * 16384;
#pragma unroll
        for (int ks = 0; ks < 2; ks++) {
            const int qo = ks ? q1 : q0;
            bfrag a4[4], b4[2];
#pragma unroll
            for (int f = 0; f < 4; f++)
                a4[f] = *(const bfrag*)&lds[cb + rowa + f * 1024 + qo];
#pragma unroll
            for (int f = 0; f < 2; f++)
                b4[f] = *(const bfrag*)&lds[cb + 8192 + rowb + f * 1024 + qo];
#pragma unroll
            for (int i = 0; i < 4; i++)
#pragma unroll
                for (int j = 0; j < 2; j++)
                    acc[i][j] = __builtin_amdgcn_mfma_f32_16x16x32_bf16(a4[i], b4[j], acc[i][j], 0, 0, 0);
        }
        END_BAR();
        cur ^= 1;
    }

    const int crow0 = bm0 + wr * 64 + (l >> 4) * 4;
    const int ccol0 = bn0 + wc * 32 + (l & 15);
    float* C = Cv + (size_t)bz * zC + (size_t)kz * pz;
#pragma unroll
    for (int i = 0; i < 4; i++)
#pragma unroll
        for (int j = 0; j < 2; j++)
#pragma unroll
            for (int r = 0; r < 4; r++)
                C[(size_t)(crow0 + i * 16 + r) * N + (ccol0 + j * 16)] = acc[i][j][r];
}

// ---------------------------------------------------------------------------
// Fused score-combine (steps 6+7, no wmat). (Proven r17.)
// r24: partials stored as bf16 (p3b) — halves the p3 round-trip traffic.
// ---------------------------------------------------------------------------
__global__ __launch_bounds__(512)
void gsc(const unsigned short* __restrict__ ainh, const unsigned short* __restrict__ aouth,
         const unsigned short* __restrict__ ainT, unsigned short* __restrict__ p3b)
{
    __shared__ __align__(16) unsigned short lds[65536];  // 128 KB
    const int AIN = 0, AOUT = 16384, AINT = 32768, PB = 49152;

    const int tid = threadIdx.x;
    const int l   = tid & 63;
    const int w   = tid >> 6;
    const int wr  = w >> 2, wc = w & 3;
    const int tz  = blockIdx.x;        // 0..7
    const int ib  = blockIdx.y;        // 0..15
    const int b   = blockIdx.z;        // 0..1
    const long SA = (long)Sq * Aq;

    auto stage32 = [&](int base, const unsigned short* src, size_t kstride) {
#pragma unroll
        for (int rd = 0; rd < 4; rd++) {
            int grow = rd * 32 + (w << 2) + (l >> 4);
            int slot = (l & 15) ^ (grow & 15);
            gl16(src + (size_t)grow * kstride + slot * 8,
                 &lds[base + rd * 4096 + (w << 9)]);
        }
    };

    const unsigned short* ainI_src = ainh + (size_t)b * SA + (size_t)(ib * 128) * Aq;
    f32x4 acc2[4][2];
#pragma unroll
    for (int i = 0; i < 4; i++)
#pragma unroll
        for (int j = 0; j < 2; j++) acc2[i][j] = (f32x4){0.f, 0.f, 0.f, 0.f};

    {
        int tglob = tz * 2;
        stage32(AIN,  ainI_src, Aq);
        stage32(AOUT, aouth + (size_t)b * SA + (size_t)(tglob * 128) * Aq, Aq);
        stage32(AINT, ainT  + (size_t)b * SA + (size_t)(tglob * 128), Sq);
        WAITV_BAR(0);
    }

    const int rowa = (wr * 64 + (l & 15)) * 128;
    const int rowb = (wc * 32 + (l & 15)) * 128;

#pragma unroll 1
    for (int t = 0; t < 2; t++) {
        if (t == 1) {
            int tglob = tz * 2 + 1;
            stage32(AOUT, aouth + (size_t)b * SA + (size_t)(tglob * 128) * Aq, Aq);
            stage32(AINT, ainT  + (size_t)b * SA + (size_t)(tglob * 128), Sq);
            WAITV_BAR(0);
        }
        f32x4 acc1[4][2];
#pragma unroll
        for (int i = 0; i < 4; i++)
#pragma unroll
            for (int j = 0; j < 2; j++) acc1[i][j] = (f32x4){0.f, 0.f, 0.f, 0.f};
#pragma unroll
        for (int ks = 0; ks < 4; ks++) {
            const int qo = ((ks * 4 + (l >> 4)) ^ (l & 15)) << 3;
            bfrag a4[4], b4[2];
#pragma unroll
            for (int f = 0; f < 4; f++)
                a4[f] = *(const bfrag*)&lds[AIN + rowa + f * 2048 + qo];
#pragma unroll
            for (int f = 0; f < 2; f++)
                b4[f] = *(const bfrag*)&lds[AOUT + rowb + f * 2048 + qo];
#pragma unroll
            for (int i = 0; i < 4; i++)
#pragma unroll
                for (int j = 0; j < 2; j++)
                    acc1[i][j] = __builtin_amdgcn_mfma_f32_16x16x32_bf16(a4[i], b4[j], acc1[i][j], 0, 0, 0);
        }
        {
            const int prow0 = wr * 64 + (l >> 4) * 4;
            const int pcol0 = wc * 32 + (l & 15);
#pragma unroll
            for (int i = 0; i < 4; i++)
#pragma unroll
                for (int j = 0; j < 2; j++)
#pragma unroll
                    for (int r = 0; r < 4; r++) {
                        int pr = prow0 + i * 16 + r;
                        int pc = pcol0 + j * 16;
                        float v = silu_f(fminf(fmaxf(acc1[i][j][r], -5.f), 5.f));
                        lds[PB + pr * 128 + (((pc >> 3) ^ (pr & 15)) << 3) + (pc & 7)] = f2bf(v);
                    }
        }
        __syncthreads();
#pragma unroll
        for (int ks = 0; ks < 4; ks++) {
            const int qo = ((ks * 4 + (l >> 4)) ^ (l & 15)) << 3;
            bfrag a4[4], b4[2];
#pragma unroll
            for (int f = 0; f < 4; f++)
                a4[f] = *(const bfrag*)&lds[PB + rowa + f * 2048 + qo];
#pragma unroll
            for (int f = 0; f < 2; f++)
                b4[f] = *(const bfrag*)&lds[AINT + rowb + f * 2048 + qo];
#pragma unroll
            for (int i = 0; i < 4; i++)
#pragma unroll
                for (int j = 0; j < 2; j++)
                    acc2[i][j] = __builtin_amdgcn_mfma_f32_16x16x32_bf16(a4[i], b4[j], acc2[i][j], 0, 0, 0);
        }
        __syncthreads();
    }

    const int crow0 = wr * 64 + (l >> 4) * 4;
    const int ccol0 = wc * 32 + (l & 15);
    unsigned short* dst = p3b + ((size_t)(b * 8 + tz) * Sq + ib * 128) * Aq;
#pragma unroll
    for (int i = 0; i < 4; i++)
#pragma unroll
        for (int j = 0; j < 2; j++)
#pragma unroll
            for (int r = 0; r < 4; r++)
                dst[(size_t)(crow0 + i * 16 + r) * Aq + ccol0 + j * 16] = f2bf(acc2[i][j][r]);
}

// ---------------------------------------------------------------------------
// guphe: merged launch — gup (blocks 0..255, proven r22) + he GEMM
// (blocks 256..511, proven mg body). (Proven r23.)
// ---------------------------------------------------------------------------
__global__ __launch_bounds__(512)
void guphe(const unsigned short* __restrict__ xh, const unsigned short* __restrict__ gwh,
           const unsigned short* __restrict__ uwh, const unsigned short* __restrict__ powh,
           unsigned short* __restrict__ hh, unsigned short* __restrict__ p2b,
           const unsigned short* __restrict__ ainh, const unsigned short* __restrict__ adw,
           unsigned short* __restrict__ he)
{
    __shared__ __align__(16) unsigned short lds[65536];  // gup: all; he: first 32K
    const int tid = threadIdx.x;
    const int l   = tid & 63;
    const int w   = tid >> 6;

    if (blockIdx.x >= 256) {
        // ================== he path (mg<2> body) ==================
        int r   = blockIdx.x - 256;
        int by  = r & 31;
        int e   = r >> 5;
        const int wr  = w >> 2, wc = w & 3;
        const int bm0 = by * 128;
        const int K = Aq;                       // 128
        const unsigned short* A0 = ainh;
        const unsigned short* B0 = adw + (size_t)e * Aq * Aq;

        const int srow = tid >> 3;
        const int sq   = (tid & 7) ^ (srow & 7);
        const size_t aoff = (size_t)(bm0 + srow) * K + sq * 8;
        const size_t boff = (size_t)srow * K + sq * 8;
        const size_t r64  = (size_t)64 * K;

        auto stage = [&](int b, int kt) {
            unsigned short* d = &lds[b * 16384 + (w << 9)];
            gl16(A0 + aoff + kt,       d + 0);
            gl16(A0 + aoff + kt + r64, d + 4096);
            gl16(B0 + boff + kt,       d + 8192);
            gl16(B0 + boff + kt + r64, d + 12288);
        };

        const int rowa = (wr * 64 + (l & 15)) * 64;
        const int rowb = (wc * 32 + (l & 15)) * 64;
        const int q0 = (((l >> 4)    ) ^ (l & 7)) << 3;
        const int q1 = (((l >> 4) + 4) ^ (l & 7)) << 3;

        f32x4 acc[4][2];
#pragma unroll
        for (int i = 0; i < 4; i++)
#pragma unroll
            for (int j = 0; j < 2; j++) acc[i][j] = (f32x4){0.f, 0.f, 0.f, 0.f};

        stage(0, 0);
        int cur = 0;
        for (int kt = 0; kt < K; kt += 64) {
            if (kt + 64 < K) {
                stage(cur ^ 1, kt + 64);
                WAITV_BAR(4);
            } else {
                WAITV_BAR(0);
            }
            const int cb = cur * 16384;
#pragma unroll
            for (int ks = 0; ks < 2; ks++) {
                const int qo = ks ? q1 : q0;
                bfrag a4[4], b4[2];
#pragma unroll
                for (int f = 0; f < 4; f++)
                    a4[f] = *(const bfrag*)&lds[cb + rowa + f * 1024 + qo];
#pragma unroll
                for (int f = 0; f < 2; f++)
                    b4[f] = *(const bfrag*)&lds[cb + 8192 + rowb + f * 1024 + qo];
#pragma unroll
                for (int i = 0; i < 4; i++)
#pragma unroll
                    for (int j = 0; j < 2; j++)
                        acc[i][j] = __builtin_amdgcn_mfma_f32_16x16x32_bf16(a4[i], b4[j], acc[i][j], 0, 0, 0);
            }
            END_BAR();
            cur ^= 1;
        }

        const int crow0 = bm0 + wr * 64 + (l >> 4) * 4;
        const int ccol0 = wc * 32 + (l & 15);
        unsigned short* C = he + (size_t)e * Nq * Aq;
#pragma unroll
        for (int i = 0; i < 4; i++)
#pragma unroll
            for (int j = 0; j < 2; j++)
#pragma unroll
                for (int r2 = 0; r2 < 4; r2++)
                    C[(size_t)(crow0 + i * 16 + r2) * Aq + (ccol0 + j * 16)] =
                        f2bf(acc[i][j][r2]);
        return;
    }

    // ================== gup path (proven r22) ==================
    const int wr  = w >> 2;
    const int wc  = w & 3;
    int id  = blockIdx.x;                              // 0..255
    int xcd = id & 7, j0 = id >> 3;
    int bx  = (xcd & 3) * 4 + (j0 & 3);
    int by  = (xcd >> 2) * 8 + (j0 >> 2);
    const int bm0 = by * 256, bn0 = bx * 128;

    const int srw = tid >> 3;
    const int sq  = (tid & 7) ^ (srw & 7);
    auto stageU = [&](int b, int u, int kt) {
        unsigned short* d = &lds[b * 32768 + u * 8192 + (tid << 3)];
        const unsigned short* src = (u < 2) ? xh : (u == 2 ? gwh : uwh);
        int baserow = (u < 2) ? (bm0 + u * 128) : bn0;
        size_t o = (size_t)(baserow + srw) * Dq + kt + sq * 8;
        gl16(src + o,                   d);
        gl16(src + o + (size_t)64 * Dq, d + 4096);
    };

    const int rowa = (wr * 128 + (l & 15)) * 64;
    const int rowb = (wc * 32  + (l & 15)) * 64;
    const int q0 = (((l >> 4)    ) ^ (l & 7)) << 3;
    const int q1 = (((l >> 4) + 4) ^ (l & 7)) << 3;

    f32x4 accg[8][2], accu[8][2];
#pragma unroll
    for (int i = 0; i < 8; i++)
#pragma unroll
        for (int jj = 0; jj < 2; jj++) {
            accg[i][jj] = (f32x4){0.f, 0.f, 0.f, 0.f};
            accu[i][jj] = (f32x4){0.f, 0.f, 0.f, 0.f};
        }

    stageU(0, 0, 0); stageU(0, 1, 0); stageU(0, 2, 0); stageU(0, 3, 0);
    int cur = 0;
    for (int kt = 0; kt < Dq; kt += 64) {
        const int pf = (kt + 64 < Dq);
        const int cb = cur * 32768;
        const int nx = cur ^ 1;
        bfrag a4[8], b4[2];

        // ---- phase 0: ks0 gate ----
        WAITV(2);
        BARF();
#pragma unroll
        for (int f = 0; f < 8; f++)
            a4[f] = *(const bfrag*)&lds[cb + rowa + f * 1024 + q0];
#pragma unroll
        for (int f = 0; f < 2; f++)
            b4[f] = *(const bfrag*)&lds[cb + 16384 + rowb + f * 1024 + q0];
        if (pf) stageU(nx, 0, kt + 64);
        __builtin_amdgcn_s_setprio(1);
#pragma unroll
        for (int i = 0; i < 8; i++)
#pragma unroll
            for (int jj = 0; jj < 2; jj++)
                accg[i][jj] = __builtin_amdgcn_mfma_f32_16x16x32_bf16(a4[i], b4[jj], accg[i][jj], 0, 0, 0);
        __builtin_amdgcn_s_setprio(0);

        // ---- phase 1: ks0 up ----
        if (pf) { WAITV(2); } else { WAITV(0); }
        BARF();
#pragma unroll
        for (int f = 0; f < 2; f++)
            b4[f] = *(const bfrag*)&lds[cb + 24576 + rowb + f * 1024 + q0];
        if (pf) stageU(nx, 1, kt + 64);
        __builtin_amdgcn_s_setprio(1);
#pragma unroll
        for (int i = 0; i < 8; i++)
#pragma unroll
            for (int jj = 0; jj < 2; jj++)
                accu[i][jj] = __builtin_amdgcn_mfma_f32_16x16x32_bf16(a4[i], b4[jj], accu[i][jj], 0, 0, 0);
        __builtin_amdgcn_s_setprio(0);

        // ---- phase 2: ks1 gate ----
        BARF();
#pragma unroll
        for (int f = 0; f < 8; f++)
            a4[f] = *(const bfrag*)&lds[cb + rowa + f * 1024 + q1];
#pragma unroll
        for (int f = 0; f < 2; f++)
            b4[f] = *(const bfrag*)&lds[cb + 16384 + rowb + f * 1024 + q1];
        if (pf) stageU(nx, 2, kt + 64);
        __builtin_amdgcn_s_setprio(1);
#pragma unroll
        for (int i = 0; i < 8; i++)
#pragma unroll
            for (int jj = 0; jj < 2; jj++)
                accg[i][jj] = __builtin_amdgcn_mfma_f32_16x16x32_bf16(a4[i], b4[jj], accg[i][jj], 0, 0, 0);
        __builtin_amdgcn_s_setprio(0);

        // ---- phase 3: ks1 up ----
        BARF();
#pragma unroll
        for (int f = 0; f < 2; f++)
            b4[f] = *(const bfrag*)&lds[cb + 24576 + rowb + f * 1024 + q1];
        if (pf) stageU(nx, 3, kt + 64);
        __builtin_amdgcn_s_setprio(1);
#pragma unroll
        for (int i = 0; i < 8; i++)
#pragma unroll
            for (int jj = 0; jj < 2; jj++)
                accu[i][jj] = __builtin_amdgcn_mfma_f32_16x16x32_bf16(a4[i], b4[jj], accu[i][jj], 0, 0, 0);
        __builtin_amdgcn_s_setprio(0);

        cur = nx;
    }

    // ---- fused epilogue (proven r22) ----
    END_BAR();
#pragma unroll
    for (int rd = 0; rd < 4; rd++) {
        int grow = rd * 32 + (w << 2) + (l >> 4);
        int slot = (l & 15) ^ (grow & 15);
        gl16(powh + (size_t)grow * Hq + bn0 + slot * 8,
             &lds[32768 + rd * 4096 + (tid << 3)]);
    }
    const int crow0 = bm0 + wr * 128 + (l >> 4) * 4;
    const int ccol0 = bn0 + wc * 32 + (l & 15);
    const int lrow0 = wr * 128 + (l >> 4) * 4;
    const int lcol0 = wc * 32 + (l & 15);
#pragma unroll
    for (int i = 0; i < 8; i++)
#pragma unroll
        for (int jj = 0; jj < 2; jj++)
#pragma unroll
            for (int r2 = 0; r2 < 4; r2++) {
                float hv = silu_f(accg[i][jj][r2]) * accu[i][jj][r2];
                unsigned short hb = f2bf(hv);
                hh[(size_t)(crow0 + i * 16 + r2) * Hq + (ccol0 + jj * 16)] = hb;
                int pr = lrow0 + i * 16 + r2;
                int pc = lcol0 + jj * 16;
                lds[pr * 128 + (((pc >> 3) ^ (pr & 15)) << 3) + (pc & 7)] = hb;
            }
    __syncthreads();
    f32x4 acc2[8][2];
#pragma unroll
    for (int i = 0; i < 8; i++)
#pragma unroll
        for (int jj = 0; jj < 2; jj++) acc2[i][jj] = (f32x4){0.f, 0.f, 0.f, 0.f};
    const int rowa2 = (wr * 128 + (l & 15)) * 128;
    const int rowb2 = 32768 + (wc * 32 + (l & 15)) * 128;
#pragma unroll
    for (int ks = 0; ks < 4; ks++) {
        const int qo = ((ks * 4 + (l >> 4)) ^ (l & 15)) << 3;
        bfrag a4[8], b4[2];
#pragma unroll
        for (int f = 0; f < 8; f++)
            a4[f] = *(const bfrag*)&lds[rowa2 + f * 2048 + qo];
#pragma unroll
        for (int f = 0; f < 2; f++)
            b4[f] = *(const bfrag*)&lds[rowb2 + f * 2048 + qo];
#pragma unroll
        for (int i = 0; i < 8; i++)
#pragma unroll
            for (int jj = 0; jj < 2; jj++)
                acc2[i][jj] = __builtin_amdgcn_mfma_f32_16x16x32_bf16(a4[i], b4[jj], acc2[i][jj], 0, 0, 0);
    }
    unsigned short* dst = p2b + (size_t)bx * Nq * Aq;
#pragma unroll
    for (int i = 0; i < 8; i++)
#pragma unroll
        for (int jj = 0; jj < 2; jj++)
#pragma unroll
            for (int r2 = 0; r2 < 4; r2++)
                dst[(size_t)(crow0 + i * 16 + r2) * Aq + (wc * 32 + jj * 16 + (l & 15))] =
                    f2bf(acc2[i][jj][r2]);
}

// ---------------------------------------------------------------------------
// Final fused GEMM, BK=64, 8 waves (2Mx4N), 3-deep ring, 2-phase main loop.
// (Proven r21.)  out[4096][1024] = hh@dwh^T (K=2048) + acat@kcat^T (K=256)
// ---------------------------------------------------------------------------
__global__ __launch_bounds__(512)
void gfinal(const unsigned short* __restrict__ hh, const unsigned short* __restrict__ dwh,
            const unsigned short* __restrict__ acat, const unsigned short* __restrict__ kcat,
            float* __restrict__ out)
{
    __shared__ __align__(16) unsigned short lds[49152];  // 3 bufs x 16384
    const int tid = threadIdx.x;
    const int l   = tid & 63;
    const int w   = tid >> 6;
    const int wr  = w >> 2, wc = w & 3;

    int nb  = gridDim.x * gridDim.y;                      // 256
    int id  = blockIdx.y * gridDim.x + blockIdx.x;
    int id2 = (id & 7) * (nb >> 3) + (id >> 3);
    int bx  = id2 % gridDim.x, by = id2 / gridDim.x;
    const int bm0 = by * 128, bn0 = bx * 128;

    const int srow = tid >> 3;
    const int sq   = (tid & 7) ^ (srow & 7);
    const int rowa = (wr * 64 + (l & 15)) * 64;
    const int rowb = (wc * 32 + (l & 15)) * 64;
    const int q0 = (((l >> 4)    ) ^ (l & 7)) << 3;
    const int q1 = (((l >> 4) + 4) ^ (l & 7)) << 3;

    f32x4 acc[4][2];
#pragma unroll
    for (int i = 0; i < 4; i++)
#pragma unroll
        for (int j = 0; j < 2; j++) acc[i][j] = (f32x4){0.f, 0.f, 0.f, 0.f};

    // ---- main: K=2048, 3-deep ring, 2-phase ----
    {
        const size_t aoff = (size_t)(bm0 + srow) * Hq + sq * 8;
        const size_t boff = (size_t)(bn0 + srow) * Hq + sq * 8;
        const size_t r64  = (size_t)64 * Hq;
        auto stageA = [&](int b, int kt) {
            unsigned short* d = &lds[b * 16384 + (w << 9)];
            gl16(hh + aoff + kt,       d + 0);
            gl16(hh + aoff + kt + r64, d + 4096);
        };
        auto stageB = [&](int b, int kt) {
            unsigned short* d = &lds[b * 16384 + (w << 9)];
            gl16(dwh + boff + kt,       d + 8192);
            gl16(dwh + boff + kt + r64, d + 12288);
        };
        stageA(0, 0);  stageB(0, 0);
        stageA(1, 64); stageB(1, 64);
        int cur = 0;
        for (int kt = 0; kt < Hq; kt += 64) {
            if (kt + 64 < Hq) { WAITV_BAR(4); } else { WAITV_BAR(0); }
            const int pf  = (kt + 128 < Hq);
            const int nb3 = (cur + 2 >= 3) ? cur - 1 : cur + 2;
            const int cb  = cur * 16384;
            bfrag a4[4], b4[2];
            // ---- phase 0: ks0 ----
#pragma unroll
            for (int f = 0; f < 4; f++)
                a4[f] = *(const bfrag*)&lds[cb + rowa + f * 1024 + q0];
#pragma unroll
            for (int f = 0; f < 2; f++)
                b4[f] = *(const bfrag*)&lds[cb + 8192 + rowb + f * 1024 + q0];
            if (pf) stageA(nb3, kt + 128);
            __builtin_amdgcn_s_setprio(1);
#pragma unroll
            for (int i = 0; i < 4; i++)
#pragma unroll
                for (int j = 0; j < 2; j++)
                    acc[i][j] = __builtin_amdgcn_mfma_f32_16x16x32_bf16(a4[i], b4[j], acc[i][j], 0, 0, 0);
            __builtin_amdgcn_s_setprio(0);
            BARF();
            // ---- phase 1: ks1 ----
#pragma unroll
            for (int f = 0; f < 4; f++)
                a4[f] = *(const bfrag*)&lds[cb + rowa + f * 1024 + q1];
#pragma unroll
            for (int f = 0; f < 2; f++)
                b4[f] = *(const bfrag*)&lds[cb + 8192 + rowb + f * 1024 + q1];
            if (pf) stageB(nb3, kt + 128);
            __builtin_amdgcn_s_setprio(1);
#pragma unroll
            for (int i = 0; i < 4; i++)
#pragma unroll
                for (int j = 0; j < 2; j++)
                    acc[i][j] = __builtin_amdgcn_mfma_f32_16x16x32_bf16(a4[i], b4[j], acc[i][j], 0, 0, 0);
            __builtin_amdgcn_s_setprio(0);
            cur = (cur == 2) ? 0 : cur + 1;
        }
    }
    END_BAR();
    // ---- tail: K=256 over [acat | kcat], 3-deep (4 iters) ----
    {
        const size_t aoff = (size_t)(bm0 + srow) * 256 + sq * 8;
        const size_t boff = (size_t)(bn0 + srow) * 256 + sq * 8;
        const size_t r64  = (size_t)64 * 256;
        auto stage2 = [&](int b, int kt) {
            unsigned short* d = &lds[b * 16384 + (w << 9)];
            gl16(acat + aoff + kt,       d + 0);
            gl16(acat + aoff + kt + r64, d + 4096);
            gl16(kcat + boff + kt,       d + 8192);
            gl16(kcat + boff + kt + r64, d + 12288);
        };
        stage2(0, 0);
        stage2(1, 64);
        int cur = 0;
        for (int kt = 0; kt < 256; kt += 64) {
            if (kt + 64 < 256) { WAITV_BAR(4); } else { WAITV_BAR(0); }
            if (kt + 128 < 256) {
                int nb3 = (cur + 2 >= 3) ? cur - 1 : cur + 2;
                stage2(nb3, kt + 128);
            }
            const int cb = cur * 16384;
#pragma unroll
            for (int ks = 0; ks < 2; ks++) {
                const int qo = ks ? q1 : q0;
                bfrag a4[4], b4[2];
#pragma unroll
                for (int f = 0; f < 4; f++)
                    a4[f] = *(const bfrag*)&lds[cb + rowa + f * 1024 + qo];
#pragma unroll
                for (int f = 0; f < 2; f++)
                    b4[f] = *(const bfrag*)&lds[cb + 8192 + rowb + f * 1024 + qo];
#pragma unroll
                for (int i = 0; i < 4; i++)
#pragma unroll
                    for (int j = 0; j < 2; j++)
                        acc[i][j] = __builtin_amdgcn_mfma_f32_16x16x32_bf16(a4[i], b4[j], acc[i][j], 0, 0, 0);
            }
            cur = (cur == 2) ? 0 : cur + 1;
        }
    }

    const int crow0 = bm0 + wr * 64 + (l >> 4) * 4;
    const int ccol0 = bn0 + wc * 32 + (l & 15);
#pragma unroll
    for (int i = 0; i < 4; i++)
#pragma unroll
        for (int j = 0; j < 2; j++)
#pragma unroll
            for (int r = 0; r < 4; r++)
                out[(size_t)(crow0 + i * 16 + r) * Dq + ccol0 + j * 16] = acc[i][j][r];
}

// ---------------------------------------------------------------------------
// rlnmix (r24): blocks 0..1023 = aout LN over 16 bf16 partials (rln16b body);
// blocks 1024..2047 = mix_ln(he bf16 -> acat cols 128..255)  [moved out of
// tailk — depends only on he, so it runs two steps earlier].
// ---------------------------------------------------------------------------
__global__ __launch_bounds__(256)
void rlnmix(const unsigned short* __restrict__ p2b, unsigned short* __restrict__ oh,
            const unsigned short* __restrict__ he, const float* __restrict__ ew,
            const float* __restrict__ gm, const float* __restrict__ bm,
            const float* __restrict__ g, const float* __restrict__ b,
            unsigned short* __restrict__ acat)
{
    int lane = threadIdx.x & 63;
    if (blockIdx.x < 1024) {
        int row  = blockIdx.x * 4 + (threadIdx.x >> 6);
        long base = (long)row * Aq;
        const long PS = (long)Nq * Aq;
        float x0 = 0.f, x1 = 0.f;
#pragma unroll
        for (int z = 0; z < 16; z++) {
            x0 += bf2f(p2b[base + z * PS + lane]);
            x1 += bf2f(p2b[base + z * PS + lane + 64]);
        }
        float s  = x0 + x1;
        float ss = x0 * x0 + x1 * x1;
#pragma unroll
        for (int off = 32; off > 0; off >>= 1) {
            s  += __shfl_xor(s, off);
            ss += __shfl_xor(ss, off);
        }
        float m  = s * (1.0f / Aq);
        float v  = ss * (1.0f / Aq) - m * m;
        float rs = rsqrtf(v + 1e-5f);
        oh[base + lane]      = f2bf((x0 - m) * rs * g[lane]      + b[lane]);
        oh[base + lane + 64] = f2bf((x1 - m) * rs * g[lane + 64] + b[lane + 64]);
        return;
    }
    int n = (blockIdx.x - 1024) * 4 + (threadIdx.x >> 6);
    float a0 = 0.0f, a1 = 0.0f;
#pragma unroll
    for (int e = 0; e < Eq; e++) {
        const unsigned short* r = he + ((long)e * Nq + n) * Aq;
        float x0 = bf2f(r[lane]), x1 = bf2f(r[lane + 64]);
        float s  = x0 + x1;
        float ss = x0 * x0 + x1 * x1;
#pragma unroll
        for (int off = 32; off > 0; off >>= 1) {
            s  += __shfl_xor(s, off);
            ss += __shfl_xor(ss, off);
        }
        float m  = s * (1.0f / Aq);
        float v  = ss * (1.0f / Aq) - m * m;
        float rs = rsqrtf(v + 1e-5f);
        float wv = ew[(long)n * Eq + e];
        a0 += wv * ((x0 - m) * rs * gm[e * Aq + lane]      + bm[e * Aq + lane]);
        a1 += wv * ((x1 - m) * rs * gm[e * Aq + lane + 64] + bm[e * Aq + lane + 64]);
    }
    acat[(long)n * 256 + 128 + lane]      = f2bf(a0);
    acat[(long)n * 256 + 128 + lane + 64] = f2bf(a1);
}

// ---------------------------------------------------------------------------
// rlnrbf: kcat reduce (blocks 0..1023) + ain LN/transpose (1024..2047).
// (Proven r21.)
// ---------------------------------------------------------------------------
__global__ __launch_bounds__(256)
void rlnrbf(const float* __restrict__ kdp, const float* __restrict__ p1,
            unsigned short* __restrict__ kcat,
            unsigned short* __restrict__ ainh, unsigned short* __restrict__ ainT,
            const float* __restrict__ g, const float* __restrict__ b)
{
    if (blockIdx.x < 1024) {
        int i = blockIdx.x * 256 + threadIdx.x;       // < 262144
        int n = i >> 7, a = i & 127;
        int bz = n >> 10, s = n & 1023;
        long base = (long)bz * 16 * Dq * Aq + (long)s * Aq + a;
        float acc = 0.f;
#pragma unroll
        for (int z = 0; z < 16; z++) acc += kdp[base + (long)z * Dq * Aq];
        kcat[(long)s * 256 + bz * 128 + a] = f2bf(acc);
        return;
    }
    int row  = (blockIdx.x - 1024) * 4 + (threadIdx.x >> 6);
    int lane = threadIdx.x & 63;
    long base = (long)row * Aq;
    float x0 = 0.f, x1 = 0.f;
#pragma unroll
    for (int z = 0; z < 8; z++) {
        x0 += p1[base + (long)z * Nq * Aq + lane];
        x1 += p1[base + (long)z * Nq * Aq + lane + 64];
    }
    float s  = x0 + x1;
    float ss = x0 * x0 + x1 * x1;
#pragma unroll
    for (int off = 32; off > 0; off >>= 1) {
        s  += __shfl_xor(s, off);
        ss += __shfl_xor(ss, off);
    }
    float m  = s * (1.0f / Aq);
    float v  = ss * (1.0f / Aq) - m * m;
    float rs = rsqrtf(v + 1e-5f);
    unsigned short h0 = f2bf((x0 - m) * rs * g[lane]      + b[lane]);
    unsigned short h1 = f2bf((x1 - m) * rs * g[lane + 64] + b[lane + 64]);
    ainh[base + lane]      = h0;
    ainh[base + lane + 64] = h1;
    int bb2 = row >> 11, sidx = row & 2047;
    unsigned short* t = ainT + (size_t)bb2 * Sq * Aq + sidx;
    t[(size_t)lane * Sq]        = h0;
    t[(size_t)(lane + 64) * Sq] = h1;
}

// ---------------------------------------------------------------------------
// tailk (r24: reduce-only): acat[:,0:128] = 0.1 * sum_z p3b (8 bf16 partials).
// ---------------------------------------------------------------------------
__global__ __launch_bounds__(256)
void tailk(const unsigned short* __restrict__ p3b, unsigned short* __restrict__ acat)
{
    int i = blockIdx.x * 256 + threadIdx.x;       // < 524288
    int n = i >> 7, a = i & 127;
    int bz = n >> 11, s = n & 2047;
    long base = ((long)bz * 8) * Sq * Aq + (long)s * Aq + a;
    float acc = 0.f;
#pragma unroll
    for (int z = 0; z < 8; z++) acc += bf2f(p3b[base + (long)z * Sq * Aq]);
    acat[(long)n * 256 + a] = f2bf(acc * 0.1f);
}

extern "C" void kernel_launch(void* const* d_in, const int* in_sizes, int n_in,
                              void* d_out, int out_size, void* d_ws, size_t ws_size,
                              hipStream_t stream)
{
    const float* x             = (const float*)d_in[0];
    const float* ew            = (const float*)d_in[1];
    const float* up_w          = (const float*)d_in[2];
    const float* gate_w        = (const float*)d_in[3];
    const float* down_w        = (const float*)d_in[4];
    const float* pre_w         = (const float*)d_in[5];
    const float* post_w        = (const float*)d_in[6];
    const float* an_g          = (const float*)d_in[7];
    const float* an_b          = (const float*)d_in[8];
    const float* adapt_proj_w  = (const float*)d_in[9];
    const float* adapter_w     = (const float*)d_in[10];
    const float* adapter_g     = (const float*)d_in[11];
    const float* adapter_b     = (const float*)d_in[12];
    const float* expert_proj_w = (const float*)d_in[13];
    const float* output_proj_w = (const float*)d_in[14];
    float* out = (float*)d_out;

    // ---- workspace (KB offsets; peak ~96 MB) ----
#define OFF(kb) ((char*)d_ws + (size_t)(kb) * 1024)
    float* kdp  = (float*)OFF(0);        // [2][16][D][A] 16MB (phase 1)
    float* p1   = (float*)OFF(16384);    // [8][N][A] 16MB   (phase 1)
    unsigned short* p3b = (unsigned short*)OFF(0);       // [2][8][S][A] bf16 8MB (after kdp dead)
    unsigned short* he = (unsigned short*)OFF(16384);    // [E][N][A] bf16 8MB (after p1 dead)
    unsigned short* hh   = (unsigned short*)OFF(32768);  // [N,H] 16MB
    unsigned short* xh   = (unsigned short*)OFF(49152);  // 8MB
    unsigned short* gwh  = (unsigned short*)OFF(57344);  // 4MB
    unsigned short* uwh  = (unsigned short*)OFF(61440);  // 4MB
    unsigned short* dwh  = (unsigned short*)OFF(65536);  // 4MB
    unsigned short* oph  = (unsigned short*)OFF(69632);  // 4MB
    unsigned short* pwh  = (unsigned short*)OFF(73728);  // .25MB
    unsigned short* powh = (unsigned short*)OFF(73984);  // .5MB
    unsigned short* apT  = (unsigned short*)OFF(74496);  // .5MB } contiguous pair
    unsigned short* epT  = (unsigned short*)OFF(75008);  // .5MB }
    unsigned short* ainh = (unsigned short*)OFF(75520);  // 1MB
    unsigned short* ainT = (unsigned short*)OFF(76544);  // [B][A][S] 1MB
    unsigned short* aouth= (unsigned short*)OFF(77568);  // 1MB
    unsigned short* adw  = (unsigned short*)OFF(78592);  // .25MB
    unsigned short* kcat = (unsigned short*)OFF(78848);  // [D][256] .5MB
    unsigned short* acat = (unsigned short*)OFF(79360);  // [N][256] 2MB -> 81408
    unsigned short* p2b  = (unsigned short*)OFF(81920);  // [16][N][A] bf16 16MB -> 98304
#undef OFF
    (void)epT;

    dim3 blk(256), blk512(512);

    // 1. conversions + BOTH fp32 transposes in one launch (2048 + 512 blocks)
    convert_all<<<dim3(2560), blk, 0, stream>>>(x, gate_w, up_w, down_w, pre_w,
        post_w, output_proj_w, adapter_w, adapt_proj_w, expert_proj_w,
        xh, gwh, uwh, dwh, pwh, powh, oph, adw, apT);

    // 2. MERGED: kcat partials (blocks 0..255) + p1 partials (blocks 256..511)
    mgpair<<<dim3(512), blk512, 0, stream>>>(dwh, apT, kdp, xh, pwh, p1);

    // 3. MERGED: kcat reduce (blocks 0..1023) + ain LN/transpose (1024..2047)
    rlnrbf<<<dim3(2048), blk, 0, stream>>>(kdp, p1, kcat, ainh, ainT, an_g, an_b);

    // 4. MERGED: fused SwiGLU + aout-partial epilogue (blocks 0..255) +
    //    he GEMM (blocks 256..511)
    guphe<<<dim3(512), blk512, 0, stream>>>(xh, gwh, uwh, powh, hh, p2b,
        ainh, adw, he);

    // 5. MERGED: aout = LN(reduce16(p2b)) (blocks 0..1023) +
    //    acat[:,128:256] = mix_ln(he) (blocks 1024..2047)
    rlnmix<<<dim3(2048), blk, 0, stream>>>(p2b, aouth, he, ew,
        adapter_g, adapter_b, an_g, an_b, acat);

    // 6. FUSED score-combine: p3b bf16 partials (no wmat)
    gsc<<<dim3(8, 16, 2), blk512, 0, stream>>>(ainh, aouth, ainT, p3b);

    // 7. tail reduce: acat[:,0:128] = 0.1 * reduce8(p3b)
    tailk<<<dim3(2048), blk, 0, stream>>>(p3b, acat);

    // 8. out = hh@dwh^T + acat@kcat^T   (2-phase main loop)
    gfinal<<<dim3(8, 32), blk512, 0, stream>>>(hh, dwh, acat, kcat, out);
}